// Round 1
// baseline (4030.435 us; speedup 1.0000x reference)
//
#include <hip/hip_runtime.h>
#include <math.h>

#define LRELU(v) ((v) > 0.0f ? (v) : 0.01f*(v))

static __device__ __forceinline__ float lrelu(float v){ return v > 0.0f ? v : 0.01f*v; }

#define ENC_INV  2.5253813613805277f
#define ENC_NORM 1.4247939f

// ---------------- conv1: fused magnitude-encoding + conv 20->32, k3 s2, lrelu ----------------
__global__ __launch_bounds__(256) void k_conv1(
    const float* __restrict__ batch, const float* __restrict__ w,
    const float* __restrict__ bias, float* __restrict__ y)
{
  __shared__ float enc[20][17][80];   // 108.8 KB
  __shared__ float wsm[5760];         // 23 KB
  __shared__ float bsm[32];
  int n = blockIdx.x;
  int orow0 = blockIdx.y * 8;
  int nrows = min(8, 39 - orow0);
  int irow0 = orow0 * 2;
  int nirows = nrows*2 + 1;
  int tid = threadIdx.x;
  for (int i = tid; i < 5760; i += 256) wsm[i] = w[i];
  if (tid < 32) bsm[tid] = bias[tid];
  const float* img = batch + (size_t)n * 6400;
  int npix = nirows * 79;
  for (int p = tid; p < npix; p += 256) {
    int r = p / 79, col = p % 79;
    float x = img[(irow0 + r)*80 + col];
    float t = tanhf(x * (2.0f/255.0f) - 1.0f);
    #pragma unroll
    for (int c = 0; c < 20; ++c) {
      float mg = -1.0f + (2.0f/19.0f)*(float)c;
      float u = (t + mg) * ENC_INV;
      enc[c][r][col] = ENC_NORM * expf(-u*u);
    }
  }
  __syncthreads();
  int totpix = nrows * 39;
  for (int p = tid; p < totpix; p += 256) {
    int rs = p / 39, ow = p % 39;
    float acc[32];
    #pragma unroll
    for (int o = 0; o < 32; ++o) acc[o] = bsm[o];
    for (int c = 0; c < 20; ++c) {
      #pragma unroll
      for (int kh = 0; kh < 3; ++kh) {
        float e0 = enc[c][rs*2+kh][ow*2];
        float e1 = enc[c][rs*2+kh][ow*2+1];
        float e2 = enc[c][rs*2+kh][ow*2+2];
        int wb = (c*3+kh)*3;
        #pragma unroll
        for (int o = 0; o < 32; ++o) {
          const float* wp = &wsm[o*180 + wb];
          acc[o] += e0*wp[0] + e1*wp[1] + e2*wp[2];
        }
      }
    }
    int orow = orow0 + rs;
    #pragma unroll
    for (int o = 0; o < 32; ++o)
      y[(((size_t)n*32 + o)*39 + orow)*39 + ow] = lrelu(acc[o]);
  }
}

// ---------------- generic 32->32 conv, k3 s2, lrelu ----------------
__global__ __launch_bounds__(256) void k_conv(
    const float* __restrict__ in, const float* __restrict__ w,
    const float* __restrict__ bias, float* __restrict__ out,
    int H, int W, int OH, int OW, int tile_oh)
{
  __shared__ float wsm[9216];
  __shared__ float bsm[32];
  __shared__ float xs[26208];   // max: 32*21*39 (conv2 tile)
  int n = blockIdx.x;
  int orow0 = blockIdx.y * tile_oh;
  int nrows = min(tile_oh, OH - orow0);
  int irow0 = orow0*2, nirows = nrows*2 + 1;
  int tid = threadIdx.x;
  for (int i = tid; i < 9216; i += 256) wsm[i] = w[i];
  if (tid < 32) bsm[tid] = bias[tid];
  const float* ip = in + (size_t)n * 32 * H * W;
  int rw = nirows * W;
  int tot = 32 * rw;
  for (int i = tid; i < tot; i += 256) {
    int c = i / rw, rem = i % rw;
    xs[c*rw + rem] = ip[c*H*W + irow0*W + rem];
  }
  __syncthreads();
  int totpix = nrows * OW;
  for (int p = tid; p < totpix; p += 256) {
    int rs = p / OW, ow = p % OW;
    float acc[32];
    #pragma unroll
    for (int o = 0; o < 32; ++o) acc[o] = bsm[o];
    for (int c = 0; c < 32; ++c) {
      const float* xc = &xs[c*rw + (rs*2)*W + ow*2];
      #pragma unroll
      for (int kh = 0; kh < 3; ++kh) {
        float e0 = xc[kh*W], e1 = xc[kh*W+1], e2 = xc[kh*W+2];
        int wb = (c*3+kh)*3;
        #pragma unroll
        for (int o = 0; o < 32; ++o) {
          const float* wp = &wsm[o*288 + wb];
          acc[o] += e0*wp[0] + e1*wp[1] + e2*wp[2];
        }
      }
    }
    int orow = orow0 + rs;
    #pragma unroll
    for (int o = 0; o < 32; ++o)
      out[(((size_t)n*32 + o)*OH + orow)*OW + ow] = lrelu(acc[o]);
  }
}

// ---------------- tiled fp32 GEMM: C = act(A(MxK) @ W(KxN, ld=ldw) + bias) ----------------
// BM=128, BN=64, BK=16; 256 threads; 8x4 per thread. M must be a multiple of 128.
__global__ __launch_bounds__(256) void k_gemm(
    const float* __restrict__ A, const float* __restrict__ W,
    const float* __restrict__ bias, float* __restrict__ C,
    int M, int N, int K, int ldw, int act)
{
  __shared__ float As[16][132];   // [k][r], padded -> conflict-free
  __shared__ float Bs[16][68];    // [k][c]
  int bm = blockIdx.x * 128;
  int bn = blockIdx.y * 64;
  int tid = threadIdx.x;
  int tr = tid >> 4, tc = tid & 15;
  float acc[8][4];
  #pragma unroll
  for (int i = 0; i < 8; ++i)
    #pragma unroll
    for (int j = 0; j < 4; ++j) acc[i][j] = 0.f;

  for (int k0 = 0; k0 < K; k0 += 16) {
    #pragma unroll
    for (int i = 0; i < 8; ++i) {
      int idx = tid + (i << 8);
      int r = idx >> 4, kk = idx & 15;
      As[kk][r] = A[(size_t)(bm + r)*K + (k0 + kk)];
    }
    #pragma unroll
    for (int i = 0; i < 4; ++i) {
      int idx = tid + (i << 8);
      int kk = idx >> 6, c = idx & 63;
      int nn = bn + c;
      Bs[kk][c] = (nn < N) ? W[(size_t)(k0 + kk)*ldw + nn] : 0.f;
    }
    __syncthreads();
    #pragma unroll
    for (int kk = 0; kk < 16; ++kk) {
      float4 a0 = *(const float4*)&As[kk][tr*8];
      float4 a1 = *(const float4*)&As[kk][tr*8 + 4];
      float4 bv = *(const float4*)&Bs[kk][tc*4];
      float a[8] = {a0.x,a0.y,a0.z,a0.w,a1.x,a1.y,a1.z,a1.w};
      float b[4] = {bv.x,bv.y,bv.z,bv.w};
      #pragma unroll
      for (int i = 0; i < 8; ++i)
        #pragma unroll
        for (int j = 0; j < 4; ++j)
          acc[i][j] += a[i]*b[j];
    }
    __syncthreads();
  }
  #pragma unroll
  for (int i = 0; i < 8; ++i) {
    int row = bm + tr*8 + i;
    #pragma unroll
    for (int j = 0; j < 4; ++j) {
      int col = bn + tc*4 + j;
      if (col < N) {
        float v = acc[i][j];
        if (bias) v += bias[col];
        if (act) v = lrelu(v);
        C[(size_t)row*N + col] = v;
      }
    }
  }
}

// ---------------- build objects (2304 x 256): [panel slice | one-hot tag] ----------------
__global__ void k_objects(const float* __restrict__ panel, float* __restrict__ obj)
{
  int idx = blockIdx.x*256 + threadIdx.x;   // 2304*256 total
  int row = idx >> 8;
  int k = idx & 255;
  int slot = row % 9;
  int n = row / 9;
  int b = n >> 3, opt = n & 7;
  float v;
  if (k < 247) {
    int src = (slot < 8) ? (b*16 + slot) : (b*16 + 8 + opt);
    v = panel[src*247 + k];
  } else {
    v = ((k - 247) == slot) ? 1.0f : 0.0f;
  }
  obj[idx] = v;
}

// ---------------- expand: Z[n,i,j,k] = lrelu(U[n*9+i,k] + V[n*9+j,k] + b[k]) ----------------
__global__ void k_expand(const float* __restrict__ U, const float* __restrict__ V,
                         const float* __restrict__ bias, float* __restrict__ Z, int N)
{
  int idx = blockIdx.x*256 + threadIdx.x;   // 20736*N total
  int m = idx / N, k = idx % N;
  int n = m / 81, r = m % 81;
  int i = r / 9, j = r % 9;
  float v = U[(size_t)(n*9 + i)*N + k] + V[(size_t)(n*9 + j)*N + k] + bias[k];
  Z[idx] = lrelu(v);
}

// ---------------- sum over j: (256,9,9,C) -> (256,9,C) ----------------
__global__ void k_sumj(const float* __restrict__ Z, float* __restrict__ SJ, int C)
{
  int idx = blockIdx.x*256 + threadIdx.x;   // 2304*C total
  int orow = idx / C, k = idx % C;
  int n = orow / 9, i = orow % 9;
  const float* base = Z + (size_t)(n*81 + i*9)*C + k;
  float s = 0.f;
  #pragma unroll
  for (int j = 0; j < 9; ++j) s += base[(size_t)j*C];
  SJ[idx] = s;
}

// ---------------- sum over i: (256,9,256) -> (256,256) ----------------
__global__ void k_hsum(const float* __restrict__ SJ, float* __restrict__ HS)
{
  int idx = blockIdx.x*256 + threadIdx.x;   // 65536
  int n = idx >> 8, k = idx & 255;
  const float* base = SJ + (size_t)n*9*256 + k;
  float s = 0.f;
  #pragma unroll
  for (int i = 0; i < 9; ++i) s += base[i*256];
  HS[idx] = s;
}

// ---------------- final small matvec: RES[m] = F2[m,:] . ffw + ffb ----------------
__global__ void k_result(const float* __restrict__ F2, const float* __restrict__ ffw,
                         const float* __restrict__ ffb, float* __restrict__ RES)
{
  int m = threadIdx.x;
  float s = ffb[0];
  for (int k = 0; k < 256; ++k) s += F2[m*256 + k]*ffw[k];
  RES[m] = s;
}

// ---------------- loss partials: sum of HS^2 ----------------
__global__ void k_losspart(const float* __restrict__ HS, float* __restrict__ part)
{
  __shared__ float red[256];
  int tid = threadIdx.x;
  float s = 0.f;
  for (int i = blockIdx.x*256 + tid; i < 65536; i += 64*256) { float v = HS[i]; s += v*v; }
  red[tid] = s; __syncthreads();
  for (int off = 128; off > 0; off >>= 1) { if (tid < off) red[tid] += red[tid + off]; __syncthreads(); }
  if (tid == 0) part[blockIdx.x] = red[0];
}

// ---------------- finalize: write answer + loss ----------------
__global__ void k_final(const float* __restrict__ part, const float* __restrict__ RES,
                        float* __restrict__ out)
{
  __shared__ float red[256];
  int tid = threadIdx.x;
  red[tid] = (tid < 64) ? part[tid] : 0.f;
  __syncthreads();
  for (int off = 128; off > 0; off >>= 1) { if (tid < off) red[tid] += red[tid + off]; __syncthreads(); }
  float hsq = red[0];
  __syncthreads();
  float r = RES[tid];
  red[tid] = r*r;
  __syncthreads();
  for (int off = 128; off > 0; off >>= 1) { if (tid < off) red[tid] += red[tid + off]; __syncthreads(); }
  out[tid] = r;
  if (tid == 0) out[256] = hsq/65536.0f + red[0]/256.0f;
}

extern "C" void kernel_launch(void* const* d_in, const int* in_sizes, int n_in,
                              void* d_out, int out_size, void* d_ws, size_t ws_size,
                              hipStream_t stream)
{
  const float* batch   = (const float*)d_in[0];
  const float* conv_w1 = (const float*)d_in[1];
  const float* conv_b1 = (const float*)d_in[2];
  const float* conv_w2 = (const float*)d_in[3];
  const float* conv_b2 = (const float*)d_in[4];
  const float* conv_w3 = (const float*)d_in[5];
  const float* conv_b3 = (const float*)d_in[6];
  const float* conv_w4 = (const float*)d_in[7];
  const float* conv_b4 = (const float*)d_in[8];
  const float* post_w  = (const float*)d_in[9];
  const float* post_b  = (const float*)d_in[10];
  const float* g_w1    = (const float*)d_in[11];
  const float* g_b1    = (const float*)d_in[12];
  const float* g_w2    = (const float*)d_in[13];
  const float* g_b2    = (const float*)d_in[14];
  const float* g_w3    = (const float*)d_in[15];
  const float* g_b3    = (const float*)d_in[16];
  const float* g_w4    = (const float*)d_in[17];
  const float* g_b4    = (const float*)d_in[18];
  const float* h_w1    = (const float*)d_in[19];
  const float* h_b1    = (const float*)d_in[20];
  const float* h_w2    = (const float*)d_in[21];
  const float* h_b2    = (const float*)d_in[22];
  const float* h_w3    = (const float*)d_in[23];
  const float* h_b3    = (const float*)d_in[24];
  const float* f_w1    = (const float*)d_in[25];
  const float* f_b1    = (const float*)d_in[26];
  const float* f_w2    = (const float*)d_in[27];
  const float* f_b2    = (const float*)d_in[28];
  const float* ff_w    = (const float*)d_in[29];
  const float* ff_b    = (const float*)d_in[30];

  float* ws = (float*)d_ws;
  // layout (floats). Y1 aliases the P/Q ping-pong region (dead before MLP starts).
  const size_t off_P    = 0;           // 20736*512 = 10,616,832
  const size_t off_Q    = 12000000;    // 10,616,832
  const size_t off_Y1   = 0;           // 512*32*39*39 = 24,920,064
  const size_t off_Y2   = 25000000;    // 5,914,624
  const size_t off_Y3   = 31000000;    // 1,327,104 (later reused as PANEL 512*247)
  const size_t off_Y4   = 32400000;    // 262,144
  const size_t off_OBJ  = 32700000;    // 589,824
  const size_t off_SJ   = 33300000;    // 589,824
  const size_t off_U    = 33900000;    // up to 2304*512 = 1,179,648
  const size_t off_V    = 35100000;    // 1,179,648
  const size_t off_HS   = 36300000;    // 65,536
  const size_t off_F1   = 36400000;    // 65,536
  const size_t off_F2   = 36500000;    // 65,536
  const size_t off_RES  = 36600000;    // 256
  const size_t off_PART = 36601000;    // 64
  const size_t off_PANEL = off_Y3;

  dim3 b256(256);

  // conv stack
  k_conv1<<<dim3(512,5), b256, 0, stream>>>(batch, conv_w1, conv_b1, ws + off_Y1);
  k_conv <<<dim3(512,2), b256, 0, stream>>>(ws + off_Y1, conv_w2, conv_b2, ws + off_Y2, 39,39,19,19,10);
  k_conv <<<dim3(512,1), b256, 0, stream>>>(ws + off_Y2, conv_w3, conv_b3, ws + off_Y3, 19,19, 9, 9, 9);
  k_conv <<<dim3(512,1), b256, 0, stream>>>(ws + off_Y3, conv_w4, conv_b4, ws + off_Y4,  9, 9, 4, 4, 4);

  // post: (512x512) @ (512x247) + b   -> panel
  k_gemm<<<dim3(4,4), b256, 0, stream>>>(ws + off_Y4, post_w, post_b, ws + off_PANEL, 512,247,512, 247, 0);

  // objects (2304 x 256)
  k_objects<<<dim3(2304*256/256), b256, 0, stream>>>(ws + off_PANEL, ws + off_OBJ);

  // g layer 1 via combos decomposition: U = OBJ @ g_w1[:256], V = OBJ @ g_w1[256:]
  k_gemm<<<dim3(18,8), b256, 0, stream>>>(ws + off_OBJ, g_w1,            nullptr, ws + off_U, 2304,512,256, 512, 0);
  k_gemm<<<dim3(18,8), b256, 0, stream>>>(ws + off_OBJ, g_w1 + 256*512,  nullptr, ws + off_V, 2304,512,256, 512, 0);
  k_expand<<<dim3(20736*512/256), b256, 0, stream>>>(ws + off_U, ws + off_V, g_b1, ws + off_P, 512);
  // g2..g4
  k_gemm<<<dim3(162,8), b256, 0, stream>>>(ws + off_P, g_w2, g_b2, ws + off_Q, 20736,512,512, 512, 1);
  k_gemm<<<dim3(162,8), b256, 0, stream>>>(ws + off_Q, g_w3, g_b3, ws + off_P, 20736,512,512, 512, 1);
  k_gemm<<<dim3(162,4), b256, 0, stream>>>(ws + off_P, g_w4, g_b4, ws + off_Q, 20736,256,512, 256, 1);
  k_sumj<<<dim3(2304*256/256), b256, 0, stream>>>(ws + off_Q, ws + off_SJ, 256);

  // h loop
  for (int i = 0; i < 3; ++i) {
    const float* hw1 = h_w1 + (size_t)i*512*256;
    k_gemm<<<dim3(18,4), b256, 0, stream>>>(ws + off_SJ, hw1,            nullptr, ws + off_U, 2304,256,256, 256, 0);
    k_gemm<<<dim3(18,4), b256, 0, stream>>>(ws + off_SJ, hw1 + 256*256,  nullptr, ws + off_V, 2304,256,256, 256, 0);
    k_expand<<<dim3(20736*256/256), b256, 0, stream>>>(ws + off_U, ws + off_V, h_b1 + i*256, ws + off_P, 256);
    k_gemm<<<dim3(162,4), b256, 0, stream>>>(ws + off_P, h_w2 + (size_t)i*256*256, h_b2 + i*256, ws + off_Q, 20736,256,256, 256, 1);
    k_gemm<<<dim3(162,4), b256, 0, stream>>>(ws + off_Q, h_w3 + (size_t)i*256*256, h_b3 + i*256, ws + off_P, 20736,256,256, 256, 1);
    k_sumj<<<dim3(2304*256/256), b256, 0, stream>>>(ws + off_P, ws + off_SJ, 256);
  }

  // head
  k_hsum<<<dim3(256), b256, 0, stream>>>(ws + off_SJ, ws + off_HS);
  k_gemm<<<dim3(2,4), b256, 0, stream>>>(ws + off_HS, f_w1, f_b1, ws + off_F1, 256,256,256, 256, 1);
  k_gemm<<<dim3(2,4), b256, 0, stream>>>(ws + off_F1, f_w2, f_b2, ws + off_F2, 256,256,256, 256, 1);
  k_result<<<dim3(1), b256, 0, stream>>>(ws + off_F2, ff_w, ff_b, ws + off_RES);
  k_losspart<<<dim3(64), b256, 0, stream>>>(ws + off_HS, ws + off_PART);
  k_final<<<dim3(1), b256, 0, stream>>>(ws + off_PART, ws + off_RES, (float*)d_out);
}

// Round 2
// 2513.522 us; speedup vs baseline: 1.6035x; 1.6035x over previous
//
#include <hip/hip_runtime.h>
#include <math.h>

static __device__ __forceinline__ float lrelu(float v){ return v > 0.0f ? v : 0.01f*v; }

static __device__ __forceinline__ unsigned short f2bf(float f){
  unsigned int u = __float_as_uint(f);
  unsigned int r = (u + 0x7fffu + ((u >> 16) & 1u)) >> 16;
  return (unsigned short)r;
}
static __device__ __forceinline__ float bf2f(unsigned short u){
  return __uint_as_float(((unsigned int)u) << 16);
}

#define ENC_INV  2.5253813613805277f
#define ENC_NORM 1.4247939f

typedef __attribute__((ext_vector_type(4))) float f32x4;
typedef __attribute__((ext_vector_type(8))) short bf16x8;

// ---------------- conv1: fused encoding + conv 20->32, k3 s2, lrelu ----------------
// 2-phase over channel halves (enc LDS 10ch) + 8x5 register tile per thread.
__global__ __launch_bounds__(256,2) void k_conv1(
    const float* __restrict__ batch, const float* __restrict__ w,
    const float* __restrict__ bias, float* __restrict__ y)
{
  __shared__ float enc[10][17][79];
  __shared__ float wsm[32][91];
  __shared__ float bsm[32];
  int n = blockIdx.x;
  int orow0 = blockIdx.y * 8;
  int nrows = min(8, 39 - orow0);
  int irow0 = orow0 * 2;
  int nirows = nrows*2 + 1;
  int tid = threadIdx.x;
  int q = tid & 3;          // o-chunk (8 channels)
  int pg = tid >> 2;        // pixel group 0..63
  if (tid < 32) bsm[tid] = bias[tid];
  const float* img = batch + (size_t)n * 6400;

  int totpix = nrows * 39;
  int rs[5], ow[5], valid[5];
  #pragma unroll
  for (int m = 0; m < 5; ++m) {
    int p = pg + 64*m;
    valid[m] = (p < totpix);
    int pc = valid[m] ? p : 0;
    rs[m] = pc / 39; ow[m] = pc % 39;
  }
  float acc[8][5];
  #pragma unroll
  for (int j = 0; j < 8; ++j)
    #pragma unroll
    for (int m = 0; m < 5; ++m) acc[j][m] = 0.f;

  for (int phase = 0; phase < 2; ++phase) {
    int c0 = phase * 10;
    // stage weights for this phase: wsm[o][cc*9 + t]
    for (int i = tid; i < 2880; i += 256) {
      int o = i / 90, r = i % 90;
      wsm[o][r] = w[o*180 + c0*9 + r];
    }
    // stage enc for this phase
    int npix = nirows * 79;
    for (int p = tid; p < npix; p += 256) {
      int r = p / 79, col = p % 79;
      float x = img[(irow0 + r)*80 + col];
      float t = tanhf(x * (2.0f/255.0f) - 1.0f);
      #pragma unroll
      for (int c = 0; c < 10; ++c) {
        float mg = -1.0f + (2.0f/19.0f)*(float)(c0 + c);
        float u = (t + mg) * ENC_INV;
        enc[c][r][col] = ENC_NORM * __expf(-u*u);
      }
    }
    __syncthreads();
    #pragma unroll
    for (int cc = 0; cc < 10; ++cc) {
      #pragma unroll
      for (int kh = 0; kh < 3; ++kh) {
        float wreg[8][3];
        #pragma unroll
        for (int j = 0; j < 8; ++j)
          #pragma unroll
          for (int kw = 0; kw < 3; ++kw)
            wreg[j][kw] = wsm[q*8 + j][cc*9 + kh*3 + kw];
        #pragma unroll
        for (int m = 0; m < 5; ++m) {
          int row = rs[m]*2 + kh;
          float e0 = enc[cc][row][ow[m]*2];
          float e1 = enc[cc][row][ow[m]*2 + 1];
          float e2 = enc[cc][row][ow[m]*2 + 2];
          #pragma unroll
          for (int j = 0; j < 8; ++j)
            acc[j][m] += e0*wreg[j][0] + e1*wreg[j][1] + e2*wreg[j][2];
        }
      }
    }
    __syncthreads();
  }
  #pragma unroll
  for (int m = 0; m < 5; ++m) {
    if (!valid[m]) continue;
    int orow = orow0 + rs[m];
    #pragma unroll
    for (int j = 0; j < 8; ++j) {
      int o = q*8 + j;
      y[(((size_t)n*32 + o)*39 + orow)*39 + ow[m]] = lrelu(acc[j][m] + bsm[o]);
    }
  }
}

// NOTE: enc declared [10][17][79]: col index max is ow*2+2 = 78 -> 79 cols. Stage covers cols 0..78.

// ---------------- generic 32->32 conv, k3 s2, lrelu ----------------
__global__ __launch_bounds__(256) void k_conv(
    const float* __restrict__ in, const float* __restrict__ w,
    const float* __restrict__ bias, float* __restrict__ out,
    int H, int W, int OH, int OW, int tile_oh)
{
  __shared__ float wsm[9216];
  __shared__ float bsm[32];
  __shared__ float xs[26208];
  int n = blockIdx.x;
  int orow0 = blockIdx.y * tile_oh;
  int nrows = min(tile_oh, OH - orow0);
  int irow0 = orow0*2, nirows = nrows*2 + 1;
  int tid = threadIdx.x;
  for (int i = tid; i < 9216; i += 256) wsm[i] = w[i];
  if (tid < 32) bsm[tid] = bias[tid];
  const float* ip = in + (size_t)n * 32 * H * W;
  int rw = nirows * W;
  int tot = 32 * rw;
  for (int i = tid; i < tot; i += 256) {
    int c = i / rw, rem = i % rw;
    xs[c*rw + rem] = ip[c*H*W + irow0*W + rem];
  }
  __syncthreads();
  int totpix = nrows * OW;
  for (int p = tid; p < totpix; p += 256) {
    int rsv = p / OW, owv = p % OW;
    float acc[32];
    #pragma unroll
    for (int o = 0; o < 32; ++o) acc[o] = bsm[o];
    for (int c = 0; c < 32; ++c) {
      const float* xc = &xs[c*rw + (rsv*2)*W + owv*2];
      #pragma unroll
      for (int kh = 0; kh < 3; ++kh) {
        float e0 = xc[kh*W], e1 = xc[kh*W+1], e2 = xc[kh*W+2];
        int wb = (c*3+kh)*3;
        #pragma unroll
        for (int o = 0; o < 32; ++o) {
          const float* wp = &wsm[o*288 + wb];
          acc[o] += e0*wp[0] + e1*wp[1] + e2*wp[2];
        }
      }
    }
    int orow = orow0 + rsv;
    #pragma unroll
    for (int o = 0; o < 32; ++o)
      out[(((size_t)n*32 + o)*OH + orow)*OW + owv] = lrelu(acc[o]);
  }
}

// ---------------- fp32 tiled GEMM (small matrices: post, f-head) ----------------
__global__ __launch_bounds__(256) void k_gemm(
    const float* __restrict__ A, const float* __restrict__ W,
    const float* __restrict__ bias, float* __restrict__ C,
    int M, int N, int K, int ldw, int act)
{
  __shared__ float As[16][132];
  __shared__ float Bs[16][68];
  int bm = blockIdx.x * 128;
  int bn = blockIdx.y * 64;
  int tid = threadIdx.x;
  int tr = tid >> 4, tc = tid & 15;
  float acc[8][4];
  #pragma unroll
  for (int i = 0; i < 8; ++i)
    #pragma unroll
    for (int j = 0; j < 4; ++j) acc[i][j] = 0.f;

  for (int k0 = 0; k0 < K; k0 += 16) {
    #pragma unroll
    for (int i = 0; i < 8; ++i) {
      int idx = tid + (i << 8);
      int r = idx >> 4, kk = idx & 15;
      As[kk][r] = A[(size_t)(bm + r)*K + (k0 + kk)];
    }
    #pragma unroll
    for (int i = 0; i < 4; ++i) {
      int idx = tid + (i << 8);
      int kk = idx >> 6, c = idx & 63;
      int nn = bn + c;
      Bs[kk][c] = (nn < N) ? W[(size_t)(k0 + kk)*ldw + nn] : 0.f;
    }
    __syncthreads();
    #pragma unroll
    for (int kk = 0; kk < 16; ++kk) {
      float4 a0 = *(const float4*)&As[kk][tr*8];
      float4 a1 = *(const float4*)&As[kk][tr*8 + 4];
      float4 bv = *(const float4*)&Bs[kk][tc*4];
      float a[8] = {a0.x,a0.y,a0.z,a0.w,a1.x,a1.y,a1.z,a1.w};
      float b[4] = {bv.x,bv.y,bv.z,bv.w};
      #pragma unroll
      for (int i = 0; i < 8; ++i)
        #pragma unroll
        for (int j = 0; j < 4; ++j)
          acc[i][j] += a[i]*b[j];
    }
    __syncthreads();
  }
  #pragma unroll
  for (int i = 0; i < 8; ++i) {
    int row = bm + tr*8 + i;
    #pragma unroll
    for (int j = 0; j < 4; ++j) {
      int col = bn + tc*4 + j;
      if (col < N) {
        float v = acc[i][j];
        if (bias) v += bias[col];
        if (act) v = lrelu(v);
        C[(size_t)row*N + col] = v;
      }
    }
  }
}

// ---------------- bf16 MFMA GEMM: C = act(A(MxK,bf16) @ Wt(NxK,bf16)^T + bias) ----------------
// 128x128 tile, BK=64, 4 waves (2x2), each wave 4x4 frags of 16x16x32.
template<int OUT_BF16, int ACT>
__global__ __launch_bounds__(256) void k_mgemm(
    const unsigned short* __restrict__ A, const unsigned short* __restrict__ Wt,
    const float* __restrict__ bias, void* __restrict__ Cv,
    int M, int N, int K)
{
  __shared__ unsigned short As[128][72];
  __shared__ unsigned short Bs[128][72];
  int bm = blockIdx.x * 128;
  int bn = blockIdx.y * 128;
  int tid = threadIdx.x;
  int wid = tid >> 6, lane = tid & 63;
  int wr = (wid >> 1) * 64, wc = (wid & 1) * 64;
  int lr = lane & 15, lk = (lane >> 4) * 8;

  f32x4 acc[4][4];
  #pragma unroll
  for (int i = 0; i < 4; ++i)
    #pragma unroll
    for (int j = 0; j < 4; ++j)
      acc[i][j] = (f32x4){0.f,0.f,0.f,0.f};

  for (int k0 = 0; k0 < K; k0 += 64) {
    #pragma unroll
    for (int i = 0; i < 4; ++i) {
      int ch = tid + (i << 8);
      int r = ch >> 3, kc = (ch & 7) * 8;
      *(uint4*)&As[r][kc] = *(const uint4*)&A[(size_t)(bm + r)*K + k0 + kc];
      *(uint4*)&Bs[r][kc] = *(const uint4*)&Wt[(size_t)(bn + r)*K + k0 + kc];
    }
    __syncthreads();
    #pragma unroll
    for (int ks = 0; ks < 2; ++ks) {
      bf16x8 a[4], b[4];
      #pragma unroll
      for (int i = 0; i < 4; ++i)
        a[i] = *(const bf16x8*)&As[wr + i*16 + lr][ks*32 + lk];
      #pragma unroll
      for (int i = 0; i < 4; ++i)
        b[i] = *(const bf16x8*)&Bs[wc + i*16 + lr][ks*32 + lk];
      #pragma unroll
      for (int i = 0; i < 4; ++i)
        #pragma unroll
        for (int j = 0; j < 4; ++j)
          acc[i][j] = __builtin_amdgcn_mfma_f32_16x16x32_bf16(a[i], b[j], acc[i][j], 0, 0, 0);
    }
    __syncthreads();
  }
  int r0 = (lane >> 4) * 4;
  #pragma unroll
  for (int i = 0; i < 4; ++i) {
    #pragma unroll
    for (int j = 0; j < 4; ++j) {
      int col = bn + wc + j*16 + lr;
      float bv = bias ? bias[col] : 0.f;
      #pragma unroll
      for (int rr = 0; rr < 4; ++rr) {
        int row = bm + wr + i*16 + r0 + rr;
        float v = acc[i][j][rr] + bv;
        if (ACT) v = lrelu(v);
        if (OUT_BF16) ((unsigned short*)Cv)[(size_t)row*N + col] = f2bf(v);
        else          ((float*)Cv)[(size_t)row*N + col] = v;
      }
    }
  }
}

// ---------------- transpose+convert: out[n*K+k] = bf16(in[k*ldin+n]) ----------------
__global__ __launch_bounds__(256) void k_tr(
    const float* __restrict__ in, unsigned short* __restrict__ out,
    int K, int N, int ldin)
{
  __shared__ float t[32][33];
  int n0 = blockIdx.x * 32, k0 = blockIdx.y * 32;
  int tx = threadIdx.x & 31, ty = threadIdx.x >> 5;
  #pragma unroll
  for (int r = 0; r < 4; ++r)
    t[ty + r*8][tx] = in[(size_t)(k0 + ty + r*8)*ldin + n0 + tx];
  __syncthreads();
  #pragma unroll
  for (int r = 0; r < 4; ++r)
    out[(size_t)(n0 + ty + r*8)*K + k0 + tx] = f2bf(t[tx][ty + r*8]);
}

// batched 256x256 transposes for h weights: z<6: h_w1[i] halves; 6-8: h_w2; 9-11: h_w3
__global__ __launch_bounds__(256) void k_tr_h(
    const float* __restrict__ hw1, const float* __restrict__ hw2,
    const float* __restrict__ hw3, unsigned short* __restrict__ out)
{
  __shared__ float t[32][33];
  int z = blockIdx.z;
  const float* in;
  if (z < 6)      in = hw1 + (size_t)(z >> 1)*512*256 + (size_t)(z & 1)*256*256;
  else if (z < 9) in = hw2 + (size_t)(z - 6)*65536;
  else            in = hw3 + (size_t)(z - 9)*65536;
  unsigned short* op = out + (size_t)z*65536;
  int n0 = blockIdx.x * 32, k0 = blockIdx.y * 32;
  int tx = threadIdx.x & 31, ty = threadIdx.x >> 5;
  #pragma unroll
  for (int r = 0; r < 4; ++r)
    t[ty + r*8][tx] = in[(size_t)(k0 + ty + r*8)*256 + n0 + tx];
  __syncthreads();
  #pragma unroll
  for (int r = 0; r < 4; ++r)
    op[(size_t)(n0 + ty + r*8)*256 + k0 + tx] = f2bf(t[tx][ty + r*8]);
}

// ---------------- build objects (2304 x 256) bf16 ----------------
__global__ void k_objects(const float* __restrict__ panel, unsigned short* __restrict__ obj)
{
  int idx = blockIdx.x*256 + threadIdx.x;
  int row = idx >> 8;
  int k = idx & 255;
  int slot = row % 9;
  int nn = row / 9;
  int b = nn >> 3, opt = nn & 7;
  float v;
  if (k < 247) {
    int src = (slot < 8) ? (b*16 + slot) : (b*16 + 8 + opt);
    v = panel[src*247 + k];
  } else {
    v = ((k - 247) == slot) ? 1.0f : 0.0f;
  }
  obj[idx] = f2bf(v);
}

// ---------------- expand: Z[n,i,j,k] = bf16(lrelu(U + V + b)) ----------------
__global__ void k_expand(const float* __restrict__ U, const float* __restrict__ V,
                         const float* __restrict__ bias, unsigned short* __restrict__ Z, int N)
{
  int idx = blockIdx.x*256 + threadIdx.x;
  int m = idx / N, k = idx % N;
  int n = m / 81, r = m % 81;
  int i = r / 9, j = r % 9;
  float v = U[(size_t)(n*9 + i)*N + k] + V[(size_t)(n*9 + j)*N + k] + bias[k];
  Z[idx] = f2bf(lrelu(v));
}

// ---------------- sum over j: bf16 (256,9,9,C) -> fp32+bf16 (256,9,C) ----------------
__global__ void k_sumj(const unsigned short* __restrict__ Z, float* __restrict__ SJ,
                       unsigned short* __restrict__ SJb, int C)
{
  int idx = blockIdx.x*256 + threadIdx.x;
  int orow = idx / C, k = idx % C;
  int n = orow / 9, i = orow % 9;
  const unsigned short* base = Z + (size_t)(n*81 + i*9)*C + k;
  float s = 0.f;
  #pragma unroll
  for (int j = 0; j < 9; ++j) s += bf2f(base[(size_t)j*C]);
  SJ[idx] = s;
  SJb[idx] = f2bf(s);
}

// ---------------- sum over i: (256,9,256) -> (256,256) ----------------
__global__ void k_hsum(const float* __restrict__ SJ, float* __restrict__ HS)
{
  int idx = blockIdx.x*256 + threadIdx.x;
  int n = idx >> 8, k = idx & 255;
  const float* base = SJ + (size_t)n*9*256 + k;
  float s = 0.f;
  #pragma unroll
  for (int i = 0; i < 9; ++i) s += base[i*256];
  HS[idx] = s;
}

__global__ void k_result(const float* __restrict__ F2, const float* __restrict__ ffw,
                         const float* __restrict__ ffb, float* __restrict__ RES)
{
  int m = threadIdx.x;
  float s = ffb[0];
  for (int k = 0; k < 256; ++k) s += F2[m*256 + k]*ffw[k];
  RES[m] = s;
}

__global__ void k_losspart(const float* __restrict__ HS, float* __restrict__ part)
{
  __shared__ float red[256];
  int tid = threadIdx.x;
  float s = 0.f;
  for (int i = blockIdx.x*256 + tid; i < 65536; i += 64*256) { float v = HS[i]; s += v*v; }
  red[tid] = s; __syncthreads();
  for (int off = 128; off > 0; off >>= 1) { if (tid < off) red[tid] += red[tid + off]; __syncthreads(); }
  if (tid == 0) part[blockIdx.x] = red[0];
}

__global__ void k_final(const float* __restrict__ part, const float* __restrict__ RES,
                        float* __restrict__ out)
{
  __shared__ float red[256];
  int tid = threadIdx.x;
  red[tid] = (tid < 64) ? part[tid] : 0.f;
  __syncthreads();
  for (int off = 128; off > 0; off >>= 1) { if (tid < off) red[tid] += red[tid + off]; __syncthreads(); }
  float hsq = red[0];
  __syncthreads();
  float r = RES[tid];
  red[tid] = r*r;
  __syncthreads();
  for (int off = 128; off > 0; off >>= 1) { if (tid < off) red[tid] += red[tid + off]; __syncthreads(); }
  out[tid] = r;
  if (tid == 0) out[256] = hsq/65536.0f + red[0]/256.0f;
}

extern "C" void kernel_launch(void* const* d_in, const int* in_sizes, int n_in,
                              void* d_out, int out_size, void* d_ws, size_t ws_size,
                              hipStream_t stream)
{
  const float* batch   = (const float*)d_in[0];
  const float* conv_w1 = (const float*)d_in[1];
  const float* conv_b1 = (const float*)d_in[2];
  const float* conv_w2 = (const float*)d_in[3];
  const float* conv_b2 = (const float*)d_in[4];
  const float* conv_w3 = (const float*)d_in[5];
  const float* conv_b3 = (const float*)d_in[6];
  const float* conv_w4 = (const float*)d_in[7];
  const float* conv_b4 = (const float*)d_in[8];
  const float* post_w  = (const float*)d_in[9];
  const float* post_b  = (const float*)d_in[10];
  const float* g_w1    = (const float*)d_in[11];
  const float* g_b1    = (const float*)d_in[12];
  const float* g_w2    = (const float*)d_in[13];
  const float* g_b2    = (const float*)d_in[14];
  const float* g_w3    = (const float*)d_in[15];
  const float* g_b3    = (const float*)d_in[16];
  const float* g_w4    = (const float*)d_in[17];
  const float* g_b4    = (const float*)d_in[18];
  const float* h_w1    = (const float*)d_in[19];
  const float* h_b1    = (const float*)d_in[20];
  const float* h_w2    = (const float*)d_in[21];
  const float* h_b2    = (const float*)d_in[22];
  const float* h_w3    = (const float*)d_in[23];
  const float* h_b3    = (const float*)d_in[24];
  const float* f_w1    = (const float*)d_in[25];
  const float* f_b1    = (const float*)d_in[26];
  const float* f_w2    = (const float*)d_in[27];
  const float* f_b2    = (const float*)d_in[28];
  const float* ff_w    = (const float*)d_in[29];
  const float* ff_b    = (const float*)d_in[30];

  char* wsb = (char*)d_ws;
  // byte offsets
  const size_t off_Y1    = 0;             // 99.7 MB (convs only)
  const size_t off_Y2    = 100000000;     // 23.7 MB
  const size_t off_Y3    = 124000000;     // 5.3 MB
  const size_t off_Y4    = 130000000;     // 1.05 MB
  const size_t off_PANEL = 131200000;     // 0.51 MB
  const size_t off_WT    = 132000000;     // 3.4 MB (bf16 transposed weights, persistent)
  // MLP phase reuses [0, 99.7MB)
  const size_t off_Pb    = 0;             // 21.2 MB bf16
  const size_t off_Qb    = 22000000;      // 21.2 MB bf16
  const size_t off_U     = 44000000;      // 4.72 MB f32
  const size_t off_V     = 49000000;      // 4.72 MB f32
  const size_t off_OBJb  = 54000000;      // 1.18 MB bf16
  const size_t off_SJ    = 56000000;      // 2.36 MB f32
  const size_t off_SJb   = 59000000;      // 1.18 MB bf16
  const size_t off_HS    = 61000000;
  const size_t off_F1    = 62000000;
  const size_t off_F2    = 63000000;
  const size_t off_RES   = 64000000;
  const size_t off_PART  = 64100000;

  unsigned short* WT = (unsigned short*)(wsb + off_WT);
  // WT element offsets
  const size_t wt_g1u = 0;        // N=512,K=256
  const size_t wt_g1v = 131072;   // N=512,K=256
  const size_t wt_g2  = 262144;   // 512x512
  const size_t wt_g3  = 524288;   // 512x512
  const size_t wt_g4  = 786432;   // N=256,K=512
  const size_t wt_h   = 917504;   // 12 x 65536

  dim3 b256(256);

  // weight transposes (bf16)
  k_tr<<<dim3(16,8),  b256, 0, stream>>>(g_w1,             WT + wt_g1u, 256, 512, 512);
  k_tr<<<dim3(16,8),  b256, 0, stream>>>(g_w1 + 256*512,   WT + wt_g1v, 256, 512, 512);
  k_tr<<<dim3(16,16), b256, 0, stream>>>(g_w2,             WT + wt_g2,  512, 512, 512);
  k_tr<<<dim3(16,16), b256, 0, stream>>>(g_w3,             WT + wt_g3,  512, 512, 512);
  k_tr<<<dim3(8,16),  b256, 0, stream>>>(g_w4,             WT + wt_g4,  512, 256, 256);
  k_tr_h<<<dim3(8,8,12), b256, 0, stream>>>(h_w1, h_w2, h_w3, WT + wt_h);

  float* Y1 = (float*)(wsb + off_Y1);
  float* Y2 = (float*)(wsb + off_Y2);
  float* Y3 = (float*)(wsb + off_Y3);
  float* Y4 = (float*)(wsb + off_Y4);
  float* PANEL = (float*)(wsb + off_PANEL);

  // conv stack
  k_conv1<<<dim3(512,5), b256, 0, stream>>>(batch, conv_w1, conv_b1, Y1);
  k_conv <<<dim3(512,2), b256, 0, stream>>>(Y1, conv_w2, conv_b2, Y2, 39,39,19,19,10);
  k_conv <<<dim3(512,1), b256, 0, stream>>>(Y2, conv_w3, conv_b3, Y3, 19,19, 9, 9, 9);
  k_conv <<<dim3(512,1), b256, 0, stream>>>(Y3, conv_w4, conv_b4, Y4,  9, 9, 4, 4, 4);

  // post GEMM (fp32): (512x512)@(512x247)
  k_gemm<<<dim3(4,4), b256, 0, stream>>>(Y4, post_w, post_b, PANEL, 512,247,512, 247, 0);

  unsigned short* OBJb = (unsigned short*)(wsb + off_OBJb);
  unsigned short* Pb   = (unsigned short*)(wsb + off_Pb);
  unsigned short* Qb   = (unsigned short*)(wsb + off_Qb);
  unsigned short* SJb  = (unsigned short*)(wsb + off_SJb);
  float* U  = (float*)(wsb + off_U);
  float* V  = (float*)(wsb + off_V);
  float* SJ = (float*)(wsb + off_SJ);
  float* HS = (float*)(wsb + off_HS);
  float* F1 = (float*)(wsb + off_F1);
  float* F2 = (float*)(wsb + off_F2);
  float* RES = (float*)(wsb + off_RES);
  float* PART = (float*)(wsb + off_PART);

  k_objects<<<dim3(2304), b256, 0, stream>>>(PANEL, OBJb);

  // g1 via combos decomposition
  k_mgemm<0,0><<<dim3(18,4), b256, 0, stream>>>(OBJb, WT + wt_g1u, nullptr, U, 2304,512,256);
  k_mgemm<0,0><<<dim3(18,4), b256, 0, stream>>>(OBJb, WT + wt_g1v, nullptr, V, 2304,512,256);
  k_expand<<<dim3(20736*512/256), b256, 0, stream>>>(U, V, g_b1, Pb, 512);
  // g2..g4
  k_mgemm<1,1><<<dim3(162,4), b256, 0, stream>>>(Pb, WT + wt_g2, g_b2, Qb, 20736,512,512);
  k_mgemm<1,1><<<dim3(162,4), b256, 0, stream>>>(Qb, WT + wt_g3, g_b3, Pb, 20736,512,512);
  k_mgemm<1,1><<<dim3(162,2), b256, 0, stream>>>(Pb, WT + wt_g4, g_b4, Qb, 20736,256,512);
  k_sumj<<<dim3(2304), b256, 0, stream>>>(Qb, SJ, SJb, 256);

  // h loop
  for (int i = 0; i < 3; ++i) {
    unsigned short* h1u = WT + wt_h + (size_t)(2*i)*65536;
    unsigned short* h1v = WT + wt_h + (size_t)(2*i+1)*65536;
    unsigned short* h2t = WT + wt_h + (size_t)(6+i)*65536;
    unsigned short* h3t = WT + wt_h + (size_t)(9+i)*65536;
    k_mgemm<0,0><<<dim3(18,2), b256, 0, stream>>>(SJb, h1u, nullptr, U, 2304,256,256);
    k_mgemm<0,0><<<dim3(18,2), b256, 0, stream>>>(SJb, h1v, nullptr, V, 2304,256,256);
    k_expand<<<dim3(20736*256/256), b256, 0, stream>>>(U, V, h_b1 + i*256, Pb, 256);
    k_mgemm<1,1><<<dim3(162,2), b256, 0, stream>>>(Pb, h2t, h_b2 + i*256, Qb, 20736,256,256);
    k_mgemm<1,1><<<dim3(162,2), b256, 0, stream>>>(Qb, h3t, h_b3 + i*256, Pb, 20736,256,256);
    k_sumj<<<dim3(2304), b256, 0, stream>>>(Pb, SJ, SJb, 256);
  }

  // head (fp32)
  k_hsum<<<dim3(256), b256, 0, stream>>>(SJ, HS);
  k_gemm<<<dim3(2,4), b256, 0, stream>>>(HS, f_w1, f_b1, F1, 256,256,256, 256, 1);
  k_gemm<<<dim3(2,4), b256, 0, stream>>>(F1, f_w2, f_b2, F2, 256,256,256, 256, 1);
  k_result<<<dim3(1), b256, 0, stream>>>(F2, ff_w, ff_b, RES);
  k_losspart<<<dim3(64), b256, 0, stream>>>(HS, PART);
  k_final<<<dim3(1), b256, 0, stream>>>(PART, RES, (float*)d_out);
}

// Round 3
// 887.752 us; speedup vs baseline: 4.5400x; 2.8313x over previous
//
#include <hip/hip_runtime.h>
#include <math.h>

static __device__ __forceinline__ float lrelu(float v){ return v > 0.0f ? v : 0.01f*v; }

static __device__ __forceinline__ unsigned short f2bf(float f){
  unsigned int u = __float_as_uint(f);
  unsigned int r = (u + 0x7fffu + ((u >> 16) & 1u)) >> 16;
  return (unsigned short)r;
}
static __device__ __forceinline__ float bf2f(unsigned short u){
  return __uint_as_float(((unsigned int)u) << 16);
}

#define ENC_INV  2.5253813613805277f
#define ENC_NORM 1.4247939f

typedef __attribute__((ext_vector_type(4))) float f32x4;
typedef __attribute__((ext_vector_type(8))) short bf16x8;

// ---------------- conv1: fused encoding + conv 20->32, k3 s2, lrelu ----------------
// 3 output rows per block (39 = 13*3). 256 thr = 4 chunks(8 oc) x 64 slots x 2 px.
// Weights via wave-uniform scalar loads (no LDS); enc in LDS (44.8 KB -> 3 blk/CU).
__global__ __launch_bounds__(256) void k_conv1(
    const float* __restrict__ batch, const float* __restrict__ w,
    const float* __restrict__ bias, float* __restrict__ y)
{
  __shared__ float enc[20][7][80];
  int n = blockIdx.x;
  int orow0 = blockIdx.y * 3;          // nrows always 3 (39 = 13*3)
  int irow0 = orow0 * 2;
  int tid = threadIdx.x;
  int chunk = __builtin_amdgcn_readfirstlane(tid >> 6);
  int slot = tid & 63;
  const float* img = batch + (size_t)n * 6400;

  // stage encoding: 7 input rows x 79 cols x 20 mag channels
  for (int p = tid; p < 7*79; p += 256) {
    int r = p / 79, col = p % 79;
    float x = img[(irow0 + r)*80 + col];
    float t = tanhf(x * (2.0f/255.0f) - 1.0f);
    #pragma unroll
    for (int c = 0; c < 20; ++c) {
      float mg = -1.0f + (2.0f/19.0f)*(float)c;
      float u = (t + mg) * ENC_INV;
      enc[c][r][col] = ENC_NORM * __expf(-u*u);
    }
  }
  __syncthreads();

  const int totpix = 3*39;  // 117
  int rs[2], ov[2]; bool val[2];
  #pragma unroll
  for (int m = 0; m < 2; ++m) {
    int p = slot + 64*m;
    val[m] = (p < totpix);
    int pc = val[m] ? p : 0;
    rs[m] = pc / 39; ov[m] = pc % 39;
  }
  float acc[8][2];
  #pragma unroll
  for (int j = 0; j < 8; ++j){ acc[j][0] = 0.f; acc[j][1] = 0.f; }

  const float* wp = w + (size_t)chunk*8*180;
  for (int c = 0; c < 20; ++c) {
    #pragma unroll
    for (int kh = 0; kh < 3; ++kh) {
      float wr[8][3];
      #pragma unroll
      for (int j = 0; j < 8; ++j)
        #pragma unroll
        for (int kw = 0; kw < 3; ++kw)
          wr[j][kw] = wp[j*180 + c*9 + kh*3 + kw];   // uniform -> s_load
      #pragma unroll
      for (int m = 0; m < 2; ++m) {
        int row = rs[m]*2 + kh;
        float2 e01 = *(const float2*)&enc[c][row][ov[m]*2];
        float e2   = enc[c][row][ov[m]*2 + 2];
        #pragma unroll
        for (int j = 0; j < 8; ++j)
          acc[j][m] += e01.x*wr[j][0] + e01.y*wr[j][1] + e2*wr[j][2];
      }
    }
  }
  #pragma unroll
  for (int m = 0; m < 2; ++m) {
    if (!val[m]) continue;
    int orow = orow0 + rs[m];
    #pragma unroll
    for (int j = 0; j < 8; ++j) {
      int o = chunk*8 + j;
      y[(((size_t)n*32 + o)*39 + orow)*39 + ov[m]] = lrelu(acc[j][m] + bias[o]);
    }
  }
}

// ---------------- unified 32->32 conv, k3 s2, lrelu (conv2/3/4) ----------------
// Input tile (all 32 ch) in LDS; weights via wave-uniform scalar loads.
template<int H, int W, int OH, int OW, int ROWS, int PX, int WP>
__global__ __launch_bounds__(256) void k_convT(
    const float* __restrict__ in, const float* __restrict__ w,
    const float* __restrict__ bias, float* __restrict__ out)
{
  __shared__ float xs[32][2*ROWS+1][WP];
  int n = blockIdx.x;
  int orow0 = blockIdx.y * ROWS;
  int nrows = min(ROWS, OH - orow0);
  int irow0 = orow0*2;
  int IH = nrows*2 + 1;
  int tid = threadIdx.x;
  int chunk = __builtin_amdgcn_readfirstlane(tid >> 6);
  int slot = tid & 63;
  const float* ip = in + (size_t)n * 32 * H * W;
  int rw = IH * W;
  for (int i = tid; i < 32*rw; i += 256) {
    int c = i / rw, rem = i % rw;
    int r = rem / W, col = rem % W;
    xs[c][r][col] = ip[(size_t)c*H*W + (irow0 + r)*W + col];
  }
  __syncthreads();

  int totpix = nrows * OW;
  int rs[PX], ov[PX]; bool val[PX];
  #pragma unroll
  for (int m = 0; m < PX; ++m) {
    int p = slot + 64*m;
    val[m] = (p < totpix);
    int pc = val[m] ? p : 0;
    rs[m] = pc / OW; ov[m] = pc % OW;
  }
  float acc[8][PX];
  #pragma unroll
  for (int j = 0; j < 8; ++j)
    #pragma unroll
    for (int m = 0; m < PX; ++m) acc[j][m] = 0.f;

  const float* wp = w + (size_t)chunk*8*288;
  for (int c = 0; c < 32; ++c) {
    #pragma unroll
    for (int kh = 0; kh < 3; ++kh) {
      float wr[8][3];
      #pragma unroll
      for (int j = 0; j < 8; ++j)
        #pragma unroll
        for (int kw = 0; kw < 3; ++kw)
          wr[j][kw] = wp[j*288 + c*9 + kh*3 + kw];   // uniform -> s_load
      #pragma unroll
      for (int m = 0; m < PX; ++m) {
        int row = rs[m]*2 + kh;
        float2 e01 = *(const float2*)&xs[c][row][ov[m]*2];
        float e2   = xs[c][row][ov[m]*2 + 2];
        #pragma unroll
        for (int j = 0; j < 8; ++j)
          acc[j][m] += e01.x*wr[j][0] + e01.y*wr[j][1] + e2*wr[j][2];
      }
    }
  }
  #pragma unroll
  for (int m = 0; m < PX; ++m) {
    if (!val[m]) continue;
    int orow = orow0 + rs[m];
    #pragma unroll
    for (int j = 0; j < 8; ++j) {
      int o = chunk*8 + j;
      out[(((size_t)n*32 + o)*OH + orow)*OW + ov[m]] = lrelu(acc[j][m] + bias[o]);
    }
  }
}

// ---------------- fp32 tiled GEMM (small matrices: post, f-head) ----------------
__global__ __launch_bounds__(256) void k_gemm(
    const float* __restrict__ A, const float* __restrict__ W,
    const float* __restrict__ bias, float* __restrict__ C,
    int M, int N, int K, int ldw, int act)
{
  __shared__ float As[16][132];
  __shared__ float Bs[16][68];
  int bm = blockIdx.x * 128;
  int bn = blockIdx.y * 64;
  int tid = threadIdx.x;
  int tr = tid >> 4, tc = tid & 15;
  float acc[8][4];
  #pragma unroll
  for (int i = 0; i < 8; ++i)
    #pragma unroll
    for (int j = 0; j < 4; ++j) acc[i][j] = 0.f;

  for (int k0 = 0; k0 < K; k0 += 16) {
    #pragma unroll
    for (int i = 0; i < 8; ++i) {
      int idx = tid + (i << 8);
      int r = idx >> 4, kk = idx & 15;
      As[kk][r] = A[(size_t)(bm + r)*K + (k0 + kk)];
    }
    #pragma unroll
    for (int i = 0; i < 4; ++i) {
      int idx = tid + (i << 8);
      int kk = idx >> 6, c = idx & 63;
      int nn = bn + c;
      Bs[kk][c] = (nn < N) ? W[(size_t)(k0 + kk)*ldw + nn] : 0.f;
    }
    __syncthreads();
    #pragma unroll
    for (int kk = 0; kk < 16; ++kk) {
      float4 a0 = *(const float4*)&As[kk][tr*8];
      float4 a1 = *(const float4*)&As[kk][tr*8 + 4];
      float4 bv = *(const float4*)&Bs[kk][tc*4];
      float a[8] = {a0.x,a0.y,a0.z,a0.w,a1.x,a1.y,a1.z,a1.w};
      float b[4] = {bv.x,bv.y,bv.z,bv.w};
      #pragma unroll
      for (int i = 0; i < 8; ++i)
        #pragma unroll
        for (int j = 0; j < 4; ++j)
          acc[i][j] += a[i]*b[j];
    }
    __syncthreads();
  }
  #pragma unroll
  for (int i = 0; i < 8; ++i) {
    int row = bm + tr*8 + i;
    #pragma unroll
    for (int j = 0; j < 4; ++j) {
      int col = bn + tc*4 + j;
      if (col < N) {
        float v = acc[i][j];
        if (bias) v += bias[col];
        if (act) v = lrelu(v);
        C[(size_t)row*N + col] = v;
      }
    }
  }
}

// ---------------- bf16 MFMA GEMM: C = act(A(MxK,bf16) @ Wt(NxK,bf16)^T + bias) ----------------
template<int OUT_BF16, int ACT>
__global__ __launch_bounds__(256) void k_mgemm(
    const unsigned short* __restrict__ A, const unsigned short* __restrict__ Wt,
    const float* __restrict__ bias, void* __restrict__ Cv,
    int M, int N, int K)
{
  __shared__ unsigned short As[128][72];
  __shared__ unsigned short Bs[128][72];
  int bm = blockIdx.x * 128;
  int bn = blockIdx.y * 128;
  int tid = threadIdx.x;
  int wid = tid >> 6, lane = tid & 63;
  int wr = (wid >> 1) * 64, wc = (wid & 1) * 64;
  int lr = lane & 15, lk = (lane >> 4) * 8;

  f32x4 acc[4][4];
  #pragma unroll
  for (int i = 0; i < 4; ++i)
    #pragma unroll
    for (int j = 0; j < 4; ++j)
      acc[i][j] = (f32x4){0.f,0.f,0.f,0.f};

  for (int k0 = 0; k0 < K; k0 += 64) {
    #pragma unroll
    for (int i = 0; i < 4; ++i) {
      int ch = tid + (i << 8);
      int r = ch >> 3, kc = (ch & 7) * 8;
      *(uint4*)&As[r][kc] = *(const uint4*)&A[(size_t)(bm + r)*K + k0 + kc];
      *(uint4*)&Bs[r][kc] = *(const uint4*)&Wt[(size_t)(bn + r)*K + k0 + kc];
    }
    __syncthreads();
    #pragma unroll
    for (int ks = 0; ks < 2; ++ks) {
      bf16x8 a[4], b[4];
      #pragma unroll
      for (int i = 0; i < 4; ++i)
        a[i] = *(const bf16x8*)&As[wr + i*16 + lr][ks*32 + lk];
      #pragma unroll
      for (int i = 0; i < 4; ++i)
        b[i] = *(const bf16x8*)&Bs[wc + i*16 + lr][ks*32 + lk];
      #pragma unroll
      for (int i = 0; i < 4; ++i)
        #pragma unroll
        for (int j = 0; j < 4; ++j)
          acc[i][j] = __builtin_amdgcn_mfma_f32_16x16x32_bf16(a[i], b[j], acc[i][j], 0, 0, 0);
    }
    __syncthreads();
  }
  int r0 = (lane >> 4) * 4;
  #pragma unroll
  for (int i = 0; i < 4; ++i) {
    #pragma unroll
    for (int j = 0; j < 4; ++j) {
      int col = bn + wc + j*16 + lr;
      float bv = bias ? bias[col] : 0.f;
      #pragma unroll
      for (int rr = 0; rr < 4; ++rr) {
        int row = bm + wr + i*16 + r0 + rr;
        float v = acc[i][j][rr] + bv;
        if (ACT) v = lrelu(v);
        if (OUT_BF16) ((unsigned short*)Cv)[(size_t)row*N + col] = f2bf(v);
        else          ((float*)Cv)[(size_t)row*N + col] = v;
      }
    }
  }
}

// ---------------- transpose+convert: out[n*K+k] = bf16(in[k*ldin+n]) ----------------
__global__ __launch_bounds__(256) void k_tr(
    const float* __restrict__ in, unsigned short* __restrict__ out,
    int K, int N, int ldin)
{
  __shared__ float t[32][33];
  int n0 = blockIdx.x * 32, k0 = blockIdx.y * 32;
  int tx = threadIdx.x & 31, ty = threadIdx.x >> 5;
  #pragma unroll
  for (int r = 0; r < 4; ++r)
    t[ty + r*8][tx] = in[(size_t)(k0 + ty + r*8)*ldin + n0 + tx];
  __syncthreads();
  #pragma unroll
  for (int r = 0; r < 4; ++r)
    out[(size_t)(n0 + ty + r*8)*K + k0 + tx] = f2bf(t[tx][ty + r*8]);
}

__global__ __launch_bounds__(256) void k_tr_h(
    const float* __restrict__ hw1, const float* __restrict__ hw2,
    const float* __restrict__ hw3, unsigned short* __restrict__ out)
{
  __shared__ float t[32][33];
  int z = blockIdx.z;
  const float* in;
  if (z < 6)      in = hw1 + (size_t)(z >> 1)*512*256 + (size_t)(z & 1)*256*256;
  else if (z < 9) in = hw2 + (size_t)(z - 6)*65536;
  else            in = hw3 + (size_t)(z - 9)*65536;
  unsigned short* op = out + (size_t)z*65536;
  int n0 = blockIdx.x * 32, k0 = blockIdx.y * 32;
  int tx = threadIdx.x & 31, ty = threadIdx.x >> 5;
  #pragma unroll
  for (int r = 0; r < 4; ++r)
    t[ty + r*8][tx] = in[(size_t)(k0 + ty + r*8)*256 + n0 + tx];
  __syncthreads();
  #pragma unroll
  for (int r = 0; r < 4; ++r)
    op[(size_t)(n0 + ty + r*8)*256 + k0 + tx] = f2bf(t[tx][ty + r*8]);
}

// ---------------- build objects (2304 x 256) bf16 ----------------
__global__ void k_objects(const float* __restrict__ panel, unsigned short* __restrict__ obj)
{
  int idx = blockIdx.x*256 + threadIdx.x;
  int row = idx >> 8;
  int k = idx & 255;
  int slot = row % 9;
  int nn = row / 9;
  int b = nn >> 3, opt = nn & 7;
  float v;
  if (k < 247) {
    int src = (slot < 8) ? (b*16 + slot) : (b*16 + 8 + opt);
    v = panel[src*247 + k];
  } else {
    v = ((k - 247) == slot) ? 1.0f : 0.0f;
  }
  obj[idx] = f2bf(v);
}

// ---------------- expand: Z[n,i,j,k] = bf16(lrelu(U + V + b)) ----------------
__global__ void k_expand(const float* __restrict__ U, const float* __restrict__ V,
                         const float* __restrict__ bias, unsigned short* __restrict__ Z, int N)
{
  int idx = blockIdx.x*256 + threadIdx.x;
  int m = idx / N, k = idx % N;
  int n = m / 81, r = m % 81;
  int i = r / 9, j = r % 9;
  float v = U[(size_t)(n*9 + i)*N + k] + V[(size_t)(n*9 + j)*N + k] + bias[k];
  Z[idx] = f2bf(lrelu(v));
}

// ---------------- sum over j: bf16 (256,9,9,C) -> fp32+bf16 (256,9,C) ----------------
__global__ void k_sumj(const unsigned short* __restrict__ Z, float* __restrict__ SJ,
                       unsigned short* __restrict__ SJb, int C)
{
  int idx = blockIdx.x*256 + threadIdx.x;
  int orow = idx / C, k = idx % C;
  int n = orow / 9, i = orow % 9;
  const unsigned short* base = Z + (size_t)(n*81 + i*9)*C + k;
  float s = 0.f;
  #pragma unroll
  for (int j = 0; j < 9; ++j) s += bf2f(base[(size_t)j*C]);
  SJ[idx] = s;
  SJb[idx] = f2bf(s);
}

__global__ void k_hsum(const float* __restrict__ SJ, float* __restrict__ HS)
{
  int idx = blockIdx.x*256 + threadIdx.x;
  int n = idx >> 8, k = idx & 255;
  const float* base = SJ + (size_t)n*9*256 + k;
  float s = 0.f;
  #pragma unroll
  for (int i = 0; i < 9; ++i) s += base[i*256];
  HS[idx] = s;
}

__global__ void k_result(const float* __restrict__ F2, const float* __restrict__ ffw,
                         const float* __restrict__ ffb, float* __restrict__ RES)
{
  int m = threadIdx.x;
  float s = ffb[0];
  for (int k = 0; k < 256; ++k) s += F2[m*256 + k]*ffw[k];
  RES[m] = s;
}

__global__ void k_losspart(const float* __restrict__ HS, float* __restrict__ part)
{
  __shared__ float red[256];
  int tid = threadIdx.x;
  float s = 0.f;
  for (int i = blockIdx.x*256 + tid; i < 65536; i += 64*256) { float v = HS[i]; s += v*v; }
  red[tid] = s; __syncthreads();
  for (int off = 128; off > 0; off >>= 1) { if (tid < off) red[tid] += red[tid + off]; __syncthreads(); }
  if (tid == 0) part[blockIdx.x] = red[0];
}

__global__ void k_final(const float* __restrict__ part, const float* __restrict__ RES,
                        float* __restrict__ out)
{
  __shared__ float red[256];
  int tid = threadIdx.x;
  red[tid] = (tid < 64) ? part[tid] : 0.f;
  __syncthreads();
  for (int off = 128; off > 0; off >>= 1) { if (tid < off) red[tid] += red[tid + off]; __syncthreads(); }
  float hsq = red[0];
  __syncthreads();
  float r = RES[tid];
  red[tid] = r*r;
  __syncthreads();
  for (int off = 128; off > 0; off >>= 1) { if (tid < off) red[tid] += red[tid + off]; __syncthreads(); }
  out[tid] = r;
  if (tid == 0) out[256] = hsq/65536.0f + red[0]/256.0f;
}

extern "C" void kernel_launch(void* const* d_in, const int* in_sizes, int n_in,
                              void* d_out, int out_size, void* d_ws, size_t ws_size,
                              hipStream_t stream)
{
  const float* batch   = (const float*)d_in[0];
  const float* conv_w1 = (const float*)d_in[1];
  const float* conv_b1 = (const float*)d_in[2];
  const float* conv_w2 = (const float*)d_in[3];
  const float* conv_b2 = (const float*)d_in[4];
  const float* conv_w3 = (const float*)d_in[5];
  const float* conv_b3 = (const float*)d_in[6];
  const float* conv_w4 = (const float*)d_in[7];
  const float* conv_b4 = (const float*)d_in[8];
  const float* post_w  = (const float*)d_in[9];
  const float* post_b  = (const float*)d_in[10];
  const float* g_w1    = (const float*)d_in[11];
  const float* g_b1    = (const float*)d_in[12];
  const float* g_w2    = (const float*)d_in[13];
  const float* g_b2    = (const float*)d_in[14];
  const float* g_w3    = (const float*)d_in[15];
  const float* g_b3    = (const float*)d_in[16];
  const float* g_w4    = (const float*)d_in[17];
  const float* g_b4    = (const float*)d_in[18];
  const float* h_w1    = (const float*)d_in[19];
  const float* h_b1    = (const float*)d_in[20];
  const float* h_w2    = (const float*)d_in[21];
  const float* h_b2    = (const float*)d_in[22];
  const float* h_w3    = (const float*)d_in[23];
  const float* h_b3    = (const float*)d_in[24];
  const float* f_w1    = (const float*)d_in[25];
  const float* f_b1    = (const float*)d_in[26];
  const float* f_w2    = (const float*)d_in[27];
  const float* f_b2    = (const float*)d_in[28];
  const float* ff_w    = (const float*)d_in[29];
  const float* ff_b    = (const float*)d_in[30];

  char* wsb = (char*)d_ws;
  const size_t off_Y1    = 0;
  const size_t off_Y2    = 100000000;
  const size_t off_Y3    = 124000000;
  const size_t off_Y4    = 130000000;
  const size_t off_PANEL = 131200000;
  const size_t off_WT    = 132000000;
  const size_t off_Pb    = 0;
  const size_t off_Qb    = 22000000;
  const size_t off_U     = 44000000;
  const size_t off_V     = 49000000;
  const size_t off_OBJb  = 54000000;
  const size_t off_SJ    = 56000000;
  const size_t off_SJb   = 59000000;
  const size_t off_HS    = 61000000;
  const size_t off_F1    = 62000000;
  const size_t off_F2    = 63000000;
  const size_t off_RES   = 64000000;
  const size_t off_PART  = 64100000;

  unsigned short* WT = (unsigned short*)(wsb + off_WT);
  const size_t wt_g1u = 0;
  const size_t wt_g1v = 131072;
  const size_t wt_g2  = 262144;
  const size_t wt_g3  = 524288;
  const size_t wt_g4  = 786432;
  const size_t wt_h   = 917504;

  dim3 b256(256);

  k_tr<<<dim3(16,8),  b256, 0, stream>>>(g_w1,             WT + wt_g1u, 256, 512, 512);
  k_tr<<<dim3(16,8),  b256, 0, stream>>>(g_w1 + 256*512,   WT + wt_g1v, 256, 512, 512);
  k_tr<<<dim3(16,16), b256, 0, stream>>>(g_w2,             WT + wt_g2,  512, 512, 512);
  k_tr<<<dim3(16,16), b256, 0, stream>>>(g_w3,             WT + wt_g3,  512, 512, 512);
  k_tr<<<dim3(8,16),  b256, 0, stream>>>(g_w4,             WT + wt_g4,  512, 256, 256);
  k_tr_h<<<dim3(8,8,12), b256, 0, stream>>>(h_w1, h_w2, h_w3, WT + wt_h);

  float* Y1 = (float*)(wsb + off_Y1);
  float* Y2 = (float*)(wsb + off_Y2);
  float* Y3 = (float*)(wsb + off_Y3);
  float* Y4 = (float*)(wsb + off_Y4);
  float* PANEL = (float*)(wsb + off_PANEL);

  // conv stack
  k_conv1<<<dim3(512,13), b256, 0, stream>>>(batch, conv_w1, conv_b1, Y1);
  k_convT<39,39,19,19,5,2,40><<<dim3(512,4), b256, 0, stream>>>(Y1, conv_w2, conv_b2, Y2);
  k_convT<19,19, 9, 9,9,2,20><<<dim3(512,1), b256, 0, stream>>>(Y2, conv_w3, conv_b3, Y3);
  k_convT< 9, 9, 4, 4,4,1,10><<<dim3(512,1), b256, 0, stream>>>(Y3, conv_w4, conv_b4, Y4);

  // post GEMM (fp32): (512x512)@(512x247)
  k_gemm<<<dim3(4,4), b256, 0, stream>>>(Y4, post_w, post_b, PANEL, 512,247,512, 247, 0);

  unsigned short* OBJb = (unsigned short*)(wsb + off_OBJb);
  unsigned short* Pb   = (unsigned short*)(wsb + off_Pb);
  unsigned short* Qb   = (unsigned short*)(wsb + off_Qb);
  unsigned short* SJb  = (unsigned short*)(wsb + off_SJb);
  float* U  = (float*)(wsb + off_U);
  float* V  = (float*)(wsb + off_V);
  float* SJ = (float*)(wsb + off_SJ);
  float* HS = (float*)(wsb + off_HS);
  float* F1 = (float*)(wsb + off_F1);
  float* F2 = (float*)(wsb + off_F2);
  float* RES = (float*)(wsb + off_RES);
  float* PART = (float*)(wsb + off_PART);

  k_objects<<<dim3(2304), b256, 0, stream>>>(PANEL, OBJb);

  k_mgemm<0,0><<<dim3(18,4), b256, 0, stream>>>(OBJb, WT + wt_g1u, nullptr, U, 2304,512,256);
  k_mgemm<0,0><<<dim3(18,4), b256, 0, stream>>>(OBJb, WT + wt_g1v, nullptr, V, 2304,512,256);
  k_expand<<<dim3(20736*512/256), b256, 0, stream>>>(U, V, g_b1, Pb, 512);
  k_mgemm<1,1><<<dim3(162,4), b256, 0, stream>>>(Pb, WT + wt_g2, g_b2, Qb, 20736,512,512);
  k_mgemm<1,1><<<dim3(162,4), b256, 0, stream>>>(Qb, WT + wt_g3, g_b3, Pb, 20736,512,512);
  k_mgemm<1,1><<<dim3(162,2), b256, 0, stream>>>(Pb, WT + wt_g4, g_b4, Qb, 20736,256,512);
  k_sumj<<<dim3(2304), b256, 0, stream>>>(Qb, SJ, SJb, 256);

  for (int i = 0; i < 3; ++i) {
    unsigned short* h1u = WT + wt_h + (size_t)(2*i)*65536;
    unsigned short* h1v = WT + wt_h + (size_t)(2*i+1)*65536;
    unsigned short* h2t = WT + wt_h + (size_t)(6+i)*65536;
    unsigned short* h3t = WT + wt_h + (size_t)(9+i)*65536;
    k_mgemm<0,0><<<dim3(18,2), b256, 0, stream>>>(SJb, h1u, nullptr, U, 2304,256,256);
    k_mgemm<0,0><<<dim3(18,2), b256, 0, stream>>>(SJb, h1v, nullptr, V, 2304,256,256);
    k_expand<<<dim3(20736*256/256), b256, 0, stream>>>(U, V, h_b1 + i*256, Pb, 256);
    k_mgemm<1,1><<<dim3(162,2), b256, 0, stream>>>(Pb, h2t, h_b2 + i*256, Qb, 20736,256,256);
    k_mgemm<1,1><<<dim3(162,2), b256, 0, stream>>>(Qb, h3t, h_b3 + i*256, Pb, 20736,256,256);
    k_sumj<<<dim3(2304), b256, 0, stream>>>(Pb, SJ, SJb, 256);
  }

  k_hsum<<<dim3(256), b256, 0, stream>>>(SJ, HS);
  k_gemm<<<dim3(2,4), b256, 0, stream>>>(HS, f_w1, f_b1, F1, 256,256,256, 256, 1);
  k_gemm<<<dim3(2,4), b256, 0, stream>>>(F1, f_w2, f_b2, F2, 256,256,256, 256, 1);
  k_result<<<dim3(1), b256, 0, stream>>>(F2, ff_w, ff_b, RES);
  k_losspart<<<dim3(64), b256, 0, stream>>>(HS, PART);
  k_final<<<dim3(1), b256, 0, stream>>>(PART, RES, (float*)d_out);
}

// Round 4
// 654.003 us; speedup vs baseline: 6.1627x; 1.3574x over previous
//
#include <hip/hip_runtime.h>
#include <math.h>

static __device__ __forceinline__ float lrelu(float v){ return v > 0.0f ? v : 0.01f*v; }

static __device__ __forceinline__ unsigned short f2bf(float f){
  unsigned int u = __float_as_uint(f);
  unsigned int r = (u + 0x7fffu + ((u >> 16) & 1u)) >> 16;
  return (unsigned short)r;
}
static __device__ __forceinline__ float bf2f(unsigned short u){
  return __uint_as_float(((unsigned int)u) << 16);
}

#define ENC_INV  2.5253813613805277f
#define ENC_NORM 1.4247939f

typedef __attribute__((ext_vector_type(4))) float f32x4;
typedef __attribute__((ext_vector_type(8))) short bf16x8;

// ---------------- conv1: fused encoding + conv 20->32, k3 s2, lrelu ----------------
// fp32 compute; LDS even/odd de-interleaved (kills stride-2 bank aliasing);
// weights via wave-uniform scalar loads; output bf16 channel-last [n][39][39][32].
__global__ __launch_bounds__(256) void k_conv1(
    const float* __restrict__ batch, const float* __restrict__ w,
    const float* __restrict__ bias, unsigned short* __restrict__ y)
{
  __shared__ float ee[20][7][40];   // even input cols
  __shared__ float eo[20][7][40];   // odd input cols
  int n = blockIdx.x;
  int orow0 = blockIdx.y * 3;          // 39 = 13*3 exact
  int irow0 = orow0 * 2;
  int tid = threadIdx.x;
  int chunk = __builtin_amdgcn_readfirstlane(tid >> 6);
  int slot = tid & 63;
  const float* img = batch + (size_t)n * 6400;

  for (int p = tid; p < 7*79; p += 256) {
    int r = p / 79, col = p % 79;
    float x = img[(irow0 + r)*80 + col];
    float t = tanhf(x * (2.0f/255.0f) - 1.0f);
    int half = col >> 1;
    #pragma unroll
    for (int c = 0; c < 20; ++c) {
      float mg = -1.0f + (2.0f/19.0f)*(float)c;
      float u = (t + mg) * ENC_INV;
      float e = ENC_NORM * __expf(-u*u);
      if (col & 1) eo[c][r][half] = e; else ee[c][r][half] = e;
    }
  }
  __syncthreads();

  const int totpix = 3*39;  // 117
  int rs[2], ov[2]; bool val[2];
  #pragma unroll
  for (int m = 0; m < 2; ++m) {
    int p = slot + 64*m;
    val[m] = (p < totpix);
    int pc = val[m] ? p : 0;
    rs[m] = pc / 39; ov[m] = pc % 39;
  }
  float acc[8][2];
  #pragma unroll
  for (int j = 0; j < 8; ++j){ acc[j][0] = 0.f; acc[j][1] = 0.f; }

  const float* wp = w + (size_t)chunk*8*180;
  for (int c = 0; c < 20; ++c) {
    #pragma unroll
    for (int kh = 0; kh < 3; ++kh) {
      float wr[8][3];
      #pragma unroll
      for (int j = 0; j < 8; ++j)
        #pragma unroll
        for (int kw = 0; kw < 3; ++kw)
          wr[j][kw] = wp[j*180 + c*9 + kh*3 + kw];   // uniform -> s_load
      #pragma unroll
      for (int m = 0; m < 2; ++m) {
        int row = rs[m]*2 + kh;
        float e0 = ee[c][row][ov[m]];
        float e1 = eo[c][row][ov[m]];
        float e2 = ee[c][row][ov[m] + 1];
        #pragma unroll
        for (int j = 0; j < 8; ++j)
          acc[j][m] += e0*wr[j][0] + e1*wr[j][1] + e2*wr[j][2];
      }
    }
  }
  #pragma unroll
  for (int m = 0; m < 2; ++m) {
    if (!val[m]) continue;
    int orow = orow0 + rs[m];
    unsigned int pk[4];
    #pragma unroll
    for (int j = 0; j < 4; ++j) {
      unsigned int lo = f2bf(lrelu(acc[2*j][m]   + bias[chunk*8 + 2*j]));
      unsigned int hi = f2bf(lrelu(acc[2*j+1][m] + bias[chunk*8 + 2*j+1]));
      pk[j] = lo | (hi << 16);
    }
    unsigned short* op = y + (((size_t)n*39 + orow)*39 + ov[m])*32 + chunk*8;
    *(uint4*)op = *(uint4*)pk;
  }
}

// ---------------- conv2/3/4: bf16 MFMA implicit GEMM (32->32, k3 s2, lrelu) ----------------
// in  [n][H][W][32] bf16, out [n][OH][OW][32] bf16, wc [9][32][32] bf16 (tap,o,c).
template<int H, int W, int OH, int OW, int ROWS>
__global__ __launch_bounds__(256) void k_cmfma(
    const unsigned short* __restrict__ in, const unsigned short* __restrict__ wc,
    const float* __restrict__ bias, unsigned short* __restrict__ out)
{
  constexpr int IR = 2*ROWS + 1;
  __shared__ unsigned short xs[IR][W][40];   // pad px stride to 80B: 16B-aligned, bank-uniform
  int n = blockIdx.x;
  int orow0 = blockIdx.y * ROWS;
  int nrows = min(ROWS, OH - orow0);
  int irow0 = orow0 * 2;
  int ir = min(2*nrows + 1, H - irow0);
  int tid = threadIdx.x;
  int lane = tid & 63, wid = tid >> 6;
  int lr = lane & 15, kg = lane >> 4;

  // weight B-fragments -> registers (global, L2-hot)
  bf16x8 bf0[9], bf1[9];
  #pragma unroll
  for (int tap = 0; tap < 9; ++tap) {
    bf0[tap] = *(const bf16x8*)&wc[(tap*32 + lr)*32      + kg*8];
    bf1[tap] = *(const bf16x8*)&wc[(tap*32 + 16 + lr)*32 + kg*8];
  }

  // stage input tile
  const unsigned short* ip = in + ((size_t)n*H + irow0)*W*32;
  int npx = ir * W;
  for (int p = tid; p < npx; p += 256) {
    const uint4* src = (const uint4*)(ip + (size_t)p*32);
    uint4 v0 = src[0], v1 = src[1], v2 = src[2], v3 = src[3];
    int r = p / W, col = p % W;
    unsigned short* dst = &xs[r][col][0];
    *(uint4*)(dst)      = v0;
    *(uint4*)(dst + 8)  = v1;
    *(uint4*)(dst + 16) = v2;
    *(uint4*)(dst + 24) = v3;
  }
  __syncthreads();

  int totpx = nrows * OW;
  int ntiles = (totpx + 15) >> 4;
  float b0 = bias[lr], b1 = bias[16 + lr];
  for (int t = wid; t < ntiles; t += 4) {
    int pa = t*16 + lr;
    int pc = (pa < totpx) ? pa : 0;
    int oh = pc / OW, ow = pc % OW;
    f32x4 acc0 = {0.f,0.f,0.f,0.f}, acc1 = {0.f,0.f,0.f,0.f};
    #pragma unroll
    for (int kh = 0; kh < 3; ++kh)
      #pragma unroll
      for (int kw = 0; kw < 3; ++kw) {
        bf16x8 a = *(const bf16x8*)&xs[oh*2 + kh][ow*2 + kw][kg*8];
        acc0 = __builtin_amdgcn_mfma_f32_16x16x32_bf16(a, bf0[kh*3+kw], acc0, 0, 0, 0);
        acc1 = __builtin_amdgcn_mfma_f32_16x16x32_bf16(a, bf1[kh*3+kw], acc1, 0, 0, 0);
      }
    #pragma unroll
    for (int rr = 0; rr < 4; ++rr) {
      int ps = t*16 + kg*4 + rr;
      if (ps < totpx) {
        int soh = orow0 + ps / OW, sow = ps % OW;
        unsigned short* op = out + (((size_t)n*OH + soh)*OW + sow)*32;
        op[lr]      = f2bf(lrelu(acc0[rr] + b0));
        op[16 + lr] = f2bf(lrelu(acc1[rr] + b1));
      }
    }
  }
}

// conv weights: [32o][32c][3][3] fp32 -> [9 tap][32 o][32 c] bf16
__global__ void k_cw(const float* __restrict__ w, unsigned short* __restrict__ out)
{
  int idx = blockIdx.x*256 + threadIdx.x;    // 9216
  int tap = idx >> 10, r = idx & 1023;
  int o = r >> 5, c = r & 31;
  out[idx] = f2bf(w[(o*32 + c)*9 + tap]);
}

// post_w [512=c*16+px][247] fp32 -> padded transposed [256][512=px*32+c] bf16
__global__ void k_tr_post(const float* __restrict__ pw, unsigned short* __restrict__ out)
{
  int idx = blockIdx.x*256 + threadIdx.x;    // 131072
  int np = idx >> 9, kp = idx & 511;
  int px = kp >> 5, c = kp & 31;
  float v = (np < 247) ? pw[(size_t)(c*16 + px)*247 + np] : 0.f;
  out[idx] = f2bf(v);
}

// ---------------- fp32 tiled GEMM (f-head only) ----------------
__global__ __launch_bounds__(256) void k_gemm(
    const float* __restrict__ A, const float* __restrict__ W,
    const float* __restrict__ bias, float* __restrict__ C,
    int M, int N, int K, int ldw, int act)
{
  __shared__ float As[16][132];
  __shared__ float Bs[16][68];
  int bm = blockIdx.x * 128;
  int bn = blockIdx.y * 64;
  int tid = threadIdx.x;
  int tr = tid >> 4, tc = tid & 15;
  float acc[8][4];
  #pragma unroll
  for (int i = 0; i < 8; ++i)
    #pragma unroll
    for (int j = 0; j < 4; ++j) acc[i][j] = 0.f;

  for (int k0 = 0; k0 < K; k0 += 16) {
    #pragma unroll
    for (int i = 0; i < 8; ++i) {
      int idx = tid + (i << 8);
      int r = idx >> 4, kk = idx & 15;
      As[kk][r] = A[(size_t)(bm + r)*K + (k0 + kk)];
    }
    #pragma unroll
    for (int i = 0; i < 4; ++i) {
      int idx = tid + (i << 8);
      int kk = idx >> 6, c = idx & 63;
      int nn = bn + c;
      Bs[kk][c] = (nn < N) ? W[(size_t)(k0 + kk)*ldw + nn] : 0.f;
    }
    __syncthreads();
    #pragma unroll
    for (int kk = 0; kk < 16; ++kk) {
      float4 a0 = *(const float4*)&As[kk][tr*8];
      float4 a1 = *(const float4*)&As[kk][tr*8 + 4];
      float4 bv = *(const float4*)&Bs[kk][tc*4];
      float a[8] = {a0.x,a0.y,a0.z,a0.w,a1.x,a1.y,a1.z,a1.w};
      float b[4] = {bv.x,bv.y,bv.z,bv.w};
      #pragma unroll
      for (int i = 0; i < 8; ++i)
        #pragma unroll
        for (int j = 0; j < 4; ++j)
          acc[i][j] += a[i]*b[j];
    }
    __syncthreads();
  }
  #pragma unroll
  for (int i = 0; i < 8; ++i) {
    int row = bm + tr*8 + i;
    #pragma unroll
    for (int j = 0; j < 4; ++j) {
      int col = bn + tc*4 + j;
      if (col < N) {
        float v = acc[i][j];
        if (bias) v += bias[col];
        if (act) v = lrelu(v);
        C[(size_t)row*N + col] = v;
      }
    }
  }
}

// ---------------- bf16 MFMA GEMM: C = act(A(MxK,bf16) @ Wt(NxK,bf16)^T + bias) ----------------
template<int OUT_BF16, int ACT>
__global__ __launch_bounds__(256) void k_mgemm(
    const unsigned short* __restrict__ A, const unsigned short* __restrict__ Wt,
    const float* __restrict__ bias, void* __restrict__ Cv,
    int M, int N, int K)
{
  __shared__ unsigned short As[128][72];
  __shared__ unsigned short Bs[128][72];
  int bm = blockIdx.x * 128;
  int bn = blockIdx.y * 128;
  int tid = threadIdx.x;
  int wid = tid >> 6, lane = tid & 63;
  int wr = (wid >> 1) * 64, wc = (wid & 1) * 64;
  int lr = lane & 15, lk = (lane >> 4) * 8;

  f32x4 acc[4][4];
  #pragma unroll
  for (int i = 0; i < 4; ++i)
    #pragma unroll
    for (int j = 0; j < 4; ++j)
      acc[i][j] = (f32x4){0.f,0.f,0.f,0.f};

  for (int k0 = 0; k0 < K; k0 += 64) {
    #pragma unroll
    for (int i = 0; i < 4; ++i) {
      int ch = tid + (i << 8);
      int r = ch >> 3, kc = (ch & 7) * 8;
      *(uint4*)&As[r][kc] = *(const uint4*)&A[(size_t)(bm + r)*K + k0 + kc];
      *(uint4*)&Bs[r][kc] = *(const uint4*)&Wt[(size_t)(bn + r)*K + k0 + kc];
    }
    __syncthreads();
    #pragma unroll
    for (int ks = 0; ks < 2; ++ks) {
      bf16x8 a[4], b[4];
      #pragma unroll
      for (int i = 0; i < 4; ++i)
        a[i] = *(const bf16x8*)&As[wr + i*16 + lr][ks*32 + lk];
      #pragma unroll
      for (int i = 0; i < 4; ++i)
        b[i] = *(const bf16x8*)&Bs[wc + i*16 + lr][ks*32 + lk];
      #pragma unroll
      for (int i = 0; i < 4; ++i)
        #pragma unroll
        for (int j = 0; j < 4; ++j)
          acc[i][j] = __builtin_amdgcn_mfma_f32_16x16x32_bf16(a[i], b[j], acc[i][j], 0, 0, 0);
    }
    __syncthreads();
  }
  int r0 = (lane >> 4) * 4;
  #pragma unroll
  for (int i = 0; i < 4; ++i) {
    #pragma unroll
    for (int j = 0; j < 4; ++j) {
      int col = bn + wc + j*16 + lr;
      float bv = bias ? bias[col] : 0.f;
      #pragma unroll
      for (int rr = 0; rr < 4; ++rr) {
        int row = bm + wr + i*16 + r0 + rr;
        float v = acc[i][j][rr] + bv;
        if (ACT) v = lrelu(v);
        if (OUT_BF16) ((unsigned short*)Cv)[(size_t)row*N + col] = f2bf(v);
        else          ((float*)Cv)[(size_t)row*N + col] = v;
      }
    }
  }
}

// ---------------- transpose+convert: out[n*K+k] = bf16(in[k*ldin+n]) ----------------
__global__ __launch_bounds__(256) void k_tr(
    const float* __restrict__ in, unsigned short* __restrict__ out,
    int K, int N, int ldin)
{
  __shared__ float t[32][33];
  int n0 = blockIdx.x * 32, k0 = blockIdx.y * 32;
  int tx = threadIdx.x & 31, ty = threadIdx.x >> 5;
  #pragma unroll
  for (int r = 0; r < 4; ++r)
    t[ty + r*8][tx] = in[(size_t)(k0 + ty + r*8)*ldin + n0 + tx];
  __syncthreads();
  #pragma unroll
  for (int r = 0; r < 4; ++r)
    out[(size_t)(n0 + ty + r*8)*K + k0 + tx] = f2bf(t[tx][ty + r*8]);
}

__global__ __launch_bounds__(256) void k_tr_h(
    const float* __restrict__ hw1, const float* __restrict__ hw2,
    const float* __restrict__ hw3, unsigned short* __restrict__ out)
{
  __shared__ float t[32][33];
  int z = blockIdx.z;
  const float* in;
  if (z < 6)      in = hw1 + (size_t)(z >> 1)*512*256 + (size_t)(z & 1)*256*256;
  else if (z < 9) in = hw2 + (size_t)(z - 6)*65536;
  else            in = hw3 + (size_t)(z - 9)*65536;
  unsigned short* op = out + (size_t)z*65536;
  int n0 = blockIdx.x * 32, k0 = blockIdx.y * 32;
  int tx = threadIdx.x & 31, ty = threadIdx.x >> 5;
  #pragma unroll
  for (int r = 0; r < 4; ++r)
    t[ty + r*8][tx] = in[(size_t)(k0 + ty + r*8)*256 + n0 + tx];
  __syncthreads();
  #pragma unroll
  for (int r = 0; r < 4; ++r)
    op[(size_t)(n0 + ty + r*8)*256 + k0 + tx] = f2bf(t[tx][ty + r*8]);
}

// ---------------- build objects (2304 x 256) bf16; panel ld=256, +post_b ----------------
__global__ void k_objects(const float* __restrict__ panel, const float* __restrict__ post_b,
                          unsigned short* __restrict__ obj)
{
  int idx = blockIdx.x*256 + threadIdx.x;
  int row = idx >> 8;
  int k = idx & 255;
  int slot = row % 9;
  int nn = row / 9;
  int b = nn >> 3, opt = nn & 7;
  float v;
  if (k < 247) {
    int src = (slot < 8) ? (b*16 + slot) : (b*16 + 8 + opt);
    v = panel[(size_t)src*256 + k] + post_b[k];
  } else {
    v = ((k - 247) == slot) ? 1.0f : 0.0f;
  }
  obj[idx] = f2bf(v);
}

// ---------------- expand: Z[n,i,j,k] = bf16(lrelu(U + V + b)) ----------------
__global__ void k_expand(const float* __restrict__ U, const float* __restrict__ V,
                         const float* __restrict__ bias, unsigned short* __restrict__ Z, int N)
{
  int idx = blockIdx.x*256 + threadIdx.x;
  int m = idx / N, k = idx % N;
  int n = m / 81, r = m % 81;
  int i = r / 9, j = r % 9;
  float v = U[(size_t)(n*9 + i)*N + k] + V[(size_t)(n*9 + j)*N + k] + bias[k];
  Z[idx] = f2bf(lrelu(v));
}

// ---------------- sum over j: bf16 (256,9,9,C) -> fp32+bf16 (256,9,C) ----------------
__global__ void k_sumj(const unsigned short* __restrict__ Z, float* __restrict__ SJ,
                       unsigned short* __restrict__ SJb, int C)
{
  int idx = blockIdx.x*256 + threadIdx.x;
  int orow = idx / C, k = idx % C;
  int n = orow / 9, i = orow % 9;
  const unsigned short* base = Z + (size_t)(n*81 + i*9)*C + k;
  float s = 0.f;
  #pragma unroll
  for (int j = 0; j < 9; ++j) s += bf2f(base[(size_t)j*C]);
  SJ[idx] = s;
  SJb[idx] = f2bf(s);
}

__global__ void k_hsum(const float* __restrict__ SJ, float* __restrict__ HS)
{
  int idx = blockIdx.x*256 + threadIdx.x;
  int n = idx >> 8, k = idx & 255;
  const float* base = SJ + (size_t)n*9*256 + k;
  float s = 0.f;
  #pragma unroll
  for (int i = 0; i < 9; ++i) s += base[i*256];
  HS[idx] = s;
}

// ---------------- fused tail: result + loss ----------------
__global__ __launch_bounds__(256) void k_tailfin(
    const float* __restrict__ HS, const float* __restrict__ F2,
    const float* __restrict__ ffw, const float* __restrict__ ffb,
    float* __restrict__ out)
{
  __shared__ float red[256];
  __shared__ float wsm[256];
  int tid = threadIdx.x;
  wsm[tid] = ffw[tid];
  float s = 0.f;
  for (int j = 0; j < 256; ++j) { float v = HS[j*256 + tid]; s += v*v; }
  red[tid] = s; __syncthreads();
  for (int off = 128; off > 0; off >>= 1) { if (tid < off) red[tid] += red[tid + off]; __syncthreads(); }
  float hsq = red[0];
  __syncthreads();
  float r = ffb[0];
  for (int k = 0; k < 256; ++k) r += F2[(size_t)tid*256 + k]*wsm[k];
  red[tid] = r*r; __syncthreads();
  for (int off = 128; off > 0; off >>= 1) { if (tid < off) red[tid] += red[tid + off]; __syncthreads(); }
  out[tid] = r;
  if (tid == 0) out[256] = hsq/65536.0f + red[0]/256.0f;
}

extern "C" void kernel_launch(void* const* d_in, const int* in_sizes, int n_in,
                              void* d_out, int out_size, void* d_ws, size_t ws_size,
                              hipStream_t stream)
{
  const float* batch   = (const float*)d_in[0];
  const float* conv_w1 = (const float*)d_in[1];
  const float* conv_b1 = (const float*)d_in[2];
  const float* conv_w2 = (const float*)d_in[3];
  const float* conv_b2 = (const float*)d_in[4];
  const float* conv_w3 = (const float*)d_in[5];
  const float* conv_b3 = (const float*)d_in[6];
  const float* conv_w4 = (const float*)d_in[7];
  const float* conv_b4 = (const float*)d_in[8];
  const float* post_w  = (const float*)d_in[9];
  const float* post_b  = (const float*)d_in[10];
  const float* g_w1    = (const float*)d_in[11];
  const float* g_b1    = (const float*)d_in[12];
  const float* g_w2    = (const float*)d_in[13];
  const float* g_b2    = (const float*)d_in[14];
  const float* g_w3    = (const float*)d_in[15];
  const float* g_b3    = (const float*)d_in[16];
  const float* g_w4    = (const float*)d_in[17];
  const float* g_b4    = (const float*)d_in[18];
  const float* h_w1    = (const float*)d_in[19];
  const float* h_b1    = (const float*)d_in[20];
  const float* h_w2    = (const float*)d_in[21];
  const float* h_b2    = (const float*)d_in[22];
  const float* h_w3    = (const float*)d_in[23];
  const float* h_b3    = (const float*)d_in[24];
  const float* f_w1    = (const float*)d_in[25];
  const float* f_b1    = (const float*)d_in[26];
  const float* f_w2    = (const float*)d_in[27];
  const float* f_b2    = (const float*)d_in[28];
  const float* ff_w    = (const float*)d_in[29];
  const float* ff_b    = (const float*)d_in[30];

  char* wsb = (char*)d_ws;
  const size_t off_Y1    = 0;             // 49.9 MB bf16 NHWC
  const size_t off_Y2    = 52000000;      // 11.8 MB
  const size_t off_Y3    = 64000000;      // 2.66 MB
  const size_t off_Y4    = 67000000;      // 0.52 MB
  const size_t off_PANEL = 68000000;      // 0.52 MB fp32 [512][256]
  const size_t off_WT    = 132000000;     // bf16 weights (persistent)
  const size_t off_Pb    = 0;             // MLP ping-pong (convs dead by then)
  const size_t off_Qb    = 22000000;
  const size_t off_U     = 44000000;
  const size_t off_V     = 49000000;
  const size_t off_OBJb  = 54000000;
  const size_t off_SJ    = 56000000;
  const size_t off_SJb   = 59000000;
  const size_t off_HS    = 61000000;
  const size_t off_F1    = 62000000;
  const size_t off_F2    = 63000000;

  unsigned short* WT = (unsigned short*)(wsb + off_WT);
  const size_t wt_g1u  = 0;
  const size_t wt_g1v  = 131072;
  const size_t wt_g2   = 262144;
  const size_t wt_g3   = 524288;
  const size_t wt_g4   = 786432;
  const size_t wt_h    = 917504;          // 12 x 65536
  const size_t wt_post = 1703936;         // 256x512
  const size_t wt_cw2  = 1835008;         // 3 x 9216 (conv2/3/4 [9][32][32])
  const size_t wt_cw3  = 1844224;
  const size_t wt_cw4  = 1853440;

  dim3 b256(256);

  // weight prep
  k_tr<<<dim3(16,8),  b256, 0, stream>>>(g_w1,             WT + wt_g1u, 256, 512, 512);
  k_tr<<<dim3(16,8),  b256, 0, stream>>>(g_w1 + 256*512,   WT + wt_g1v, 256, 512, 512);
  k_tr<<<dim3(16,16), b256, 0, stream>>>(g_w2,             WT + wt_g2,  512, 512, 512);
  k_tr<<<dim3(16,16), b256, 0, stream>>>(g_w3,             WT + wt_g3,  512, 512, 512);
  k_tr<<<dim3(8,16),  b256, 0, stream>>>(g_w4,             WT + wt_g4,  512, 256, 256);
  k_tr_h<<<dim3(8,8,12), b256, 0, stream>>>(h_w1, h_w2, h_w3, WT + wt_h);
  k_tr_post<<<dim3(512), b256, 0, stream>>>(post_w, WT + wt_post);
  k_cw<<<dim3(36), b256, 0, stream>>>(conv_w2, WT + wt_cw2);
  k_cw<<<dim3(36), b256, 0, stream>>>(conv_w3, WT + wt_cw3);
  k_cw<<<dim3(36), b256, 0, stream>>>(conv_w4, WT + wt_cw4);

  unsigned short* Y1 = (unsigned short*)(wsb + off_Y1);
  unsigned short* Y2 = (unsigned short*)(wsb + off_Y2);
  unsigned short* Y3 = (unsigned short*)(wsb + off_Y3);
  unsigned short* Y4 = (unsigned short*)(wsb + off_Y4);
  float* PANEL = (float*)(wsb + off_PANEL);

  // conv stack
  k_conv1<<<dim3(512,13), b256, 0, stream>>>(batch, conv_w1, conv_b1, Y1);
  k_cmfma<39,39,19,19,10><<<dim3(512,2), b256, 0, stream>>>(Y1, WT + wt_cw2, conv_b2, Y2);
  k_cmfma<19,19, 9, 9, 9><<<dim3(512,1), b256, 0, stream>>>(Y2, WT + wt_cw3, conv_b3, Y3);
  k_cmfma< 9, 9, 4, 4, 4><<<dim3(512,1), b256, 0, stream>>>(Y3, WT + wt_cw4, conv_b4, Y4);

  // post: Y4(512x512 bf16) @ post (MFMA), PANEL fp32 ld 256
  k_mgemm<0,0><<<dim3(4,2), b256, 0, stream>>>(Y4, WT + wt_post, nullptr, PANEL, 512,256,512);

  unsigned short* OBJb = (unsigned short*)(wsb + off_OBJb);
  unsigned short* Pb   = (unsigned short*)(wsb + off_Pb);
  unsigned short* Qb   = (unsigned short*)(wsb + off_Qb);
  unsigned short* SJb  = (unsigned short*)(wsb + off_SJb);
  float* U  = (float*)(wsb + off_U);
  float* V  = (float*)(wsb + off_V);
  float* SJ = (float*)(wsb + off_SJ);
  float* HS = (float*)(wsb + off_HS);
  float* F1 = (float*)(wsb + off_F1);
  float* F2 = (float*)(wsb + off_F2);

  k_objects<<<dim3(2304), b256, 0, stream>>>(PANEL, post_b, OBJb);

  // g1 via combos decomposition
  k_mgemm<0,0><<<dim3(18,4), b256, 0, stream>>>(OBJb, WT + wt_g1u, nullptr, U, 2304,512,256);
  k_mgemm<0,0><<<dim3(18,4), b256, 0, stream>>>(OBJb, WT + wt_g1v, nullptr, V, 2304,512,256);
  k_expand<<<dim3(20736*512/256), b256, 0, stream>>>(U, V, g_b1, Pb, 512);
  k_mgemm<1,1><<<dim3(162,4), b256, 0, stream>>>(Pb, WT + wt_g2, g_b2, Qb, 20736,512,512);
  k_mgemm<1,1><<<dim3(162,4), b256, 0, stream>>>(Qb, WT + wt_g3, g_b3, Pb, 20736,512,512);
  k_mgemm<1,1><<<dim3(162,2), b256, 0, stream>>>(Pb, WT + wt_g4, g_b4, Qb, 20736,256,512);
  k_sumj<<<dim3(2304), b256, 0, stream>>>(Qb, SJ, SJb, 256);

  for (int i = 0; i < 3; ++i) {
    unsigned short* h1u = WT + wt_h + (size_t)(2*i)*65536;
    unsigned short* h1v = WT + wt_h + (size_t)(2*i+1)*65536;
    unsigned short* h2t = WT + wt_h + (size_t)(6+i)*65536;
    unsigned short* h3t = WT + wt_h + (size_t)(9+i)*65536;
    k_mgemm<0,0><<<dim3(18,2), b256, 0, stream>>>(SJb, h1u, nullptr, U, 2304,256,256);
    k_mgemm<0,0><<<dim3(18,2), b256, 0, stream>>>(SJb, h1v, nullptr, V, 2304,256,256);
    k_expand<<<dim3(20736*256/256), b256, 0, stream>>>(U, V, h_b1 + i*256, Pb, 256);
    k_mgemm<1,1><<<dim3(162,2), b256, 0, stream>>>(Pb, h2t, h_b2 + i*256, Qb, 20736,256,256);
    k_mgemm<1,1><<<dim3(162,2), b256, 0, stream>>>(Qb, h3t, h_b3 + i*256, Pb, 20736,256,256);
    k_sumj<<<dim3(2304), b256, 0, stream>>>(Pb, SJ, SJb, 256);
  }

  // head
  k_hsum<<<dim3(256), b256, 0, stream>>>(SJ, HS);
  k_gemm<<<dim3(2,4), b256, 0, stream>>>(HS, f_w1, f_b1, F1, 256,256,256, 256, 1);
  k_gemm<<<dim3(2,4), b256, 0, stream>>>(F1, f_w2, f_b2, F2, 256,256,256, 256, 1);
  k_tailfin<<<dim3(1), b256, 0, stream>>>(HS, F2, ff_w, ff_b, (float*)d_out);
}

// Round 5
// 512.133 us; speedup vs baseline: 7.8699x; 1.2770x over previous
//
#include <hip/hip_runtime.h>
#include <math.h>

static __device__ __forceinline__ float lrelu(float v){ return v > 0.0f ? v : 0.01f*v; }

static __device__ __forceinline__ unsigned short f2bf(float f){
  unsigned int u = __float_as_uint(f);
  unsigned int r = (u + 0x7fffu + ((u >> 16) & 1u)) >> 16;
  return (unsigned short)r;
}
static __device__ __forceinline__ float bf2f(unsigned short u){
  return __uint_as_float(((unsigned int)u) << 16);
}

#define ENC_INV  2.5253813613805277f
#define ENC_NORM 1.4247939f

typedef __attribute__((ext_vector_type(4))) float f32x4;
typedef __attribute__((ext_vector_type(8))) short bf16x8;

// ================= unified weight prep: all transposes/conversions in ONE kernel =================
// WT element offsets:
//   wt_g1   = 0        [1024][256]  (U|V combined)
//   wt_g2   = 262144   [512][512]
//   wt_g3   = 524288   [512][512]
//   wt_g4   = 786432   [256][512]
//   wt_h1   = 917504   3 x [512][256] (U|V combined)
//   wt_h2   = 1310720  3 x [256][256]
//   wt_h3   = 1507328  3 x [256][256]
//   wt_post = 1703936  [256][512]  (padded 247->256, K remap px*32+c)
//   wt_cw2  = 1835008  [9][32][32]; cw3 = 1844224; cw4 = 1853440
//   wt_cw1  = 1862656  [9][32][32] (c<20 valid, rest 0)
// total 1871872 elems -> grid 7312 blocks
__global__ __launch_bounds__(256) void k_prep(
    const float* __restrict__ g_w1, const float* __restrict__ g_w2,
    const float* __restrict__ g_w3, const float* __restrict__ g_w4,
    const float* __restrict__ h_w1, const float* __restrict__ h_w2,
    const float* __restrict__ h_w3, const float* __restrict__ post_w,
    const float* __restrict__ conv_w2, const float* __restrict__ conv_w3,
    const float* __restrict__ conv_w4, const float* __restrict__ conv_w1,
    unsigned short* __restrict__ WT)
{
  int e = blockIdx.x*256 + threadIdx.x;
  float v;
  if (e < 262144) {                     // g1 combined
    int nn = e >> 8, kk = e & 255;
    v = (nn < 512) ? g_w1[kk*512 + nn] : g_w1[(256+kk)*512 + (nn-512)];
  } else if (e < 524288) {              // g2
    int r = e - 262144; int nn = r >> 9, kk = r & 511;
    v = g_w2[kk*512 + nn];
  } else if (e < 786432) {              // g3
    int r = e - 524288; int nn = r >> 9, kk = r & 511;
    v = g_w3[kk*512 + nn];
  } else if (e < 917504) {              // g4
    int r = e - 786432; int nn = r >> 9, kk = r & 511;
    v = g_w4[kk*256 + nn];
  } else if (e < 1310720) {             // h1 combined x3
    int r = e - 917504; int i = r >> 17; int q = r & 131071;
    int nn = q >> 8, kk = q & 255;
    v = (nn < 256) ? h_w1[i*131072 + kk*256 + nn]
                   : h_w1[i*131072 + (256+kk)*256 + (nn-256)];
  } else if (e < 1507328) {             // h2 x3
    int r = e - 1310720; int i = r >> 16; int q = r & 65535;
    int nn = q >> 8, kk = q & 255;
    v = h_w2[i*65536 + kk*256 + nn];
  } else if (e < 1703936) {             // h3 x3
    int r = e - 1507328; int i = r >> 16; int q = r & 65535;
    int nn = q >> 8, kk = q & 255;
    v = h_w3[i*65536 + kk*256 + nn];
  } else if (e < 1835008) {             // post (pad 247->256)
    int r = e - 1703936; int np = r >> 9, kp = r & 511;
    int px = kp >> 5, c = kp & 31;
    v = (np < 247) ? post_w[(c*16+px)*247 + np] : 0.f;
  } else if (e < 1862656) {             // cw2/3/4
    int r = e - 1835008; int which = r / 9216; int q = r % 9216;
    int tap = q >> 10, o = (q >> 5) & 31, c = q & 31;
    const float* w = which==0 ? conv_w2 : (which==1 ? conv_w3 : conv_w4);
    v = w[(o*32+c)*9 + tap];
  } else {                              // cw1 (20ch zero-padded to 32)
    int r = e - 1862656; int tap = r >> 10, o = (r >> 5) & 31, c = r & 31;
    v = (c < 20) ? conv_w1[(o*20+c)*9 + tap] : 0.f;
  }
  WT[e] = f2bf(v);
}

// ================= conv1: fused encoding + MFMA implicit GEMM (20->32, k3 s2) =================
// enc in LDS channel-last bf16 [7 rows][80 half-cols: 0-39 even,40-79 odd][40 pad]
// K=32 (20ch + 12 zero) -> one 16x16x32 MFMA K-step per tap; 9 taps.
__global__ __launch_bounds__(256) void k_conv1m(
    const float* __restrict__ batch, const unsigned short* __restrict__ wc1,
    const float* __restrict__ bias, unsigned short* __restrict__ y)
{
  __shared__ unsigned short ench[7][80][40];   // 44.8 KB -> 3 blk/CU
  int n = blockIdx.x;
  int orow0 = blockIdx.y * 3;        // 39 = 13*3
  int irow0 = orow0 * 2;
  int tid = threadIdx.x;
  int lane = tid & 63, wid = tid >> 6;
  int lr = lane & 15, kg = lane >> 4;

  // weight B-fragments -> registers
  bf16x8 bf0[9], bf1[9];
  #pragma unroll
  for (int tap = 0; tap < 9; ++tap) {
    bf0[tap] = *(const bf16x8*)&wc1[tap*1024 + lr*32 + kg*8];
    bf1[tap] = *(const bf16x8*)&wc1[tap*1024 + (16+lr)*32 + kg*8];
  }

  // stage encoding: 7 rows x 79 cols, channel-last, even/odd col de-interleave
  const float* img = batch + (size_t)n*6400 + irow0*80;
  for (int p = tid; p < 7*79; p += 256) {
    int r = p / 79, col = p % 79;
    float x = img[r*80 + col];
    float t = tanhf(x * (2.0f/255.0f) - 1.0f);
    unsigned int pk[16];
    #pragma unroll
    for (int cp = 0; cp < 10; ++cp) {
      float mg0 = -1.0f + (2.0f/19.0f)*(float)(2*cp);
      float mg1 = -1.0f + (2.0f/19.0f)*(float)(2*cp+1);
      float u0 = (t + mg0)*ENC_INV, u1 = (t + mg1)*ENC_INV;
      unsigned int lo = f2bf(ENC_NORM*__expf(-u0*u0));
      unsigned int hi = f2bf(ENC_NORM*__expf(-u1*u1));
      pk[cp] = lo | (hi << 16);
    }
    #pragma unroll
    for (int cp = 10; cp < 16; ++cp) pk[cp] = 0u;
    int hidx = (col & 1) ? 40 + (col >> 1) : (col >> 1);
    unsigned short* dst = &ench[r][hidx][0];
    *(uint4*)(dst)      = *(uint4*)&pk[0];
    *(uint4*)(dst + 8)  = *(uint4*)&pk[4];
    *(uint4*)(dst + 16) = *(uint4*)&pk[8];
    *(uint4*)(dst + 24) = *(uint4*)&pk[12];
  }
  __syncthreads();

  const int totpx = 117;   // 3*39
  float b0 = bias[lr], b1 = bias[16 + lr];
  for (int t = wid; t < 8; t += 4) {
    int pa = t*16 + lr;
    int pc = (pa < totpx) ? pa : (totpx - 1);
    int oh = pc / 39, ow = pc % 39;
    f32x4 acc0 = {0.f,0.f,0.f,0.f}, acc1 = {0.f,0.f,0.f,0.f};
    #pragma unroll
    for (int kh = 0; kh < 3; ++kh) {
      int r = oh*2 + kh;
      #pragma unroll
      for (int kw = 0; kw < 3; ++kw) {
        int hidx = (kw == 1) ? (40 + ow) : (ow + (kw >> 1));
        bf16x8 a = *(const bf16x8*)&ench[r][hidx][kg*8];
        int tap = kh*3 + kw;
        acc0 = __builtin_amdgcn_mfma_f32_16x16x32_bf16(a, bf0[tap], acc0, 0, 0, 0);
        acc1 = __builtin_amdgcn_mfma_f32_16x16x32_bf16(a, bf1[tap], acc1, 0, 0, 0);
      }
    }
    #pragma unroll
    for (int rr = 0; rr < 4; ++rr) {
      int ps = t*16 + kg*4 + rr;
      if (ps < totpx) {
        int soh = orow0 + ps / 39, sow = ps % 39;
        unsigned short* op = y + (((size_t)n*39 + soh)*39 + sow)*32;
        op[lr]      = f2bf(lrelu(acc0[rr] + b0));
        op[16 + lr] = f2bf(lrelu(acc1[rr] + b1));
      }
    }
  }
}

// ---------------- conv2/3/4: bf16 MFMA implicit GEMM (32->32, k3 s2, lrelu) ----------------
template<int H, int W, int OH, int OW, int ROWS>
__global__ __launch_bounds__(256) void k_cmfma(
    const unsigned short* __restrict__ in, const unsigned short* __restrict__ wc,
    const float* __restrict__ bias, unsigned short* __restrict__ out)
{
  constexpr int IR = 2*ROWS + 1;
  __shared__ unsigned short xs[IR][W][40];
  int n = blockIdx.x;
  int orow0 = blockIdx.y * ROWS;
  int nrows = min(ROWS, OH - orow0);
  int irow0 = orow0 * 2;
  int ir = min(2*nrows + 1, H - irow0);
  int tid = threadIdx.x;
  int lane = tid & 63, wid = tid >> 6;
  int lr = lane & 15, kg = lane >> 4;

  bf16x8 bf0[9], bf1[9];
  #pragma unroll
  for (int tap = 0; tap < 9; ++tap) {
    bf0[tap] = *(const bf16x8*)&wc[(tap*32 + lr)*32      + kg*8];
    bf1[tap] = *(const bf16x8*)&wc[(tap*32 + 16 + lr)*32 + kg*8];
  }

  const unsigned short* ip = in + ((size_t)n*H + irow0)*W*32;
  int npx = ir * W;
  for (int p = tid; p < npx; p += 256) {
    const uint4* src = (const uint4*)(ip + (size_t)p*32);
    uint4 v0 = src[0], v1 = src[1], v2 = src[2], v3 = src[3];
    int r = p / W, col = p % W;
    unsigned short* dst = &xs[r][col][0];
    *(uint4*)(dst)      = v0;
    *(uint4*)(dst + 8)  = v1;
    *(uint4*)(dst + 16) = v2;
    *(uint4*)(dst + 24) = v3;
  }
  __syncthreads();

  int totpx = nrows * OW;
  int ntiles = (totpx + 15) >> 4;
  float b0 = bias[lr], b1 = bias[16 + lr];
  for (int t = wid; t < ntiles; t += 4) {
    int pa = t*16 + lr;
    int pc = (pa < totpx) ? pa : 0;
    int oh = pc / OW, ow = pc % OW;
    f32x4 acc0 = {0.f,0.f,0.f,0.f}, acc1 = {0.f,0.f,0.f,0.f};
    #pragma unroll
    for (int kh = 0; kh < 3; ++kh)
      #pragma unroll
      for (int kw = 0; kw < 3; ++kw) {
        bf16x8 a = *(const bf16x8*)&xs[oh*2 + kh][ow*2 + kw][kg*8];
        acc0 = __builtin_amdgcn_mfma_f32_16x16x32_bf16(a, bf0[kh*3+kw], acc0, 0, 0, 0);
        acc1 = __builtin_amdgcn_mfma_f32_16x16x32_bf16(a, bf1[kh*3+kw], acc1, 0, 0, 0);
      }
    #pragma unroll
    for (int rr = 0; rr < 4; ++rr) {
      int ps = t*16 + kg*4 + rr;
      if (ps < totpx) {
        int soh = orow0 + ps / OW, sow = ps % OW;
        unsigned short* op = out + (((size_t)n*OH + soh)*OW + sow)*32;
        op[lr]      = f2bf(lrelu(acc0[rr] + b0));
        op[16 + lr] = f2bf(lrelu(acc1[rr] + b1));
      }
    }
  }
}

// ---------------- fp32 tiled GEMM (f-head only) ----------------
__global__ __launch_bounds__(256) void k_gemm(
    const float* __restrict__ A, const float* __restrict__ W,
    const float* __restrict__ bias, float* __restrict__ C,
    int M, int N, int K, int ldw, int act)
{
  __shared__ float As[16][132];
  __shared__ float Bs[16][68];
  int bm = blockIdx.x * 128;
  int bn = blockIdx.y * 64;
  int tid = threadIdx.x;
  int tr = tid >> 4, tc = tid & 15;
  float acc[8][4];
  #pragma unroll
  for (int i = 0; i < 8; ++i)
    #pragma unroll
    for (int j = 0; j < 4; ++j) acc[i][j] = 0.f;

  for (int k0 = 0; k0 < K; k0 += 16) {
    #pragma unroll
    for (int i = 0; i < 8; ++i) {
      int idx = tid + (i << 8);
      int r = idx >> 4, kk = idx & 15;
      As[kk][r] = A[(size_t)(bm + r)*K + (k0 + kk)];
    }
    #pragma unroll
    for (int i = 0; i < 4; ++i) {
      int idx = tid + (i << 8);
      int kk = idx >> 6, c = idx & 63;
      int nn = bn + c;
      Bs[kk][c] = (nn < N) ? W[(size_t)(k0 + kk)*ldw + nn] : 0.f;
    }
    __syncthreads();
    #pragma unroll
    for (int kk = 0; kk < 16; ++kk) {
      float4 a0 = *(const float4*)&As[kk][tr*8];
      float4 a1 = *(const float4*)&As[kk][tr*8 + 4];
      float4 bv = *(const float4*)&Bs[kk][tc*4];
      float a[8] = {a0.x,a0.y,a0.z,a0.w,a1.x,a1.y,a1.z,a1.w};
      float b[4] = {bv.x,bv.y,bv.z,bv.w};
      #pragma unroll
      for (int i = 0; i < 8; ++i)
        #pragma unroll
        for (int j = 0; j < 4; ++j)
          acc[i][j] += a[i]*b[j];
    }
    __syncthreads();
  }
  #pragma unroll
  for (int i = 0; i < 8; ++i) {
    int row = bm + tr*8 + i;
    #pragma unroll
    for (int j = 0; j < 4; ++j) {
      int col = bn + tc*4 + j;
      if (col < N) {
        float v = acc[i][j];
        if (bias) v += bias[col];
        if (act) v = lrelu(v);
        C[(size_t)row*N + col] = v;
      }
    }
  }
}

// ---------------- bf16 MFMA GEMM: C = act(A(MxK,bf16) @ Wt(NxK,bf16)^T + bias) ----------------
template<int OUT_BF16, int ACT>
__global__ __launch_bounds__(256) void k_mgemm(
    const unsigned short* __restrict__ A, const unsigned short* __restrict__ Wt,
    const float* __restrict__ bias, void* __restrict__ Cv,
    int M, int N, int K)
{
  __shared__ unsigned short As[128][72];
  __shared__ unsigned short Bs[128][72];
  int bm = blockIdx.x * 128;
  int bn = blockIdx.y * 128;
  int tid = threadIdx.x;
  int wid = tid >> 6, lane = tid & 63;
  int wr = (wid >> 1) * 64, wc = (wid & 1) * 64;
  int lr = lane & 15, lk = (lane >> 4) * 8;

  f32x4 acc[4][4];
  #pragma unroll
  for (int i = 0; i < 4; ++i)
    #pragma unroll
    for (int j = 0; j < 4; ++j)
      acc[i][j] = (f32x4){0.f,0.f,0.f,0.f};

  for (int k0 = 0; k0 < K; k0 += 64) {
    #pragma unroll
    for (int i = 0; i < 4; ++i) {
      int ch = tid + (i << 8);
      int r = ch >> 3, kc = (ch & 7) * 8;
      *(uint4*)&As[r][kc] = *(const uint4*)&A[(size_t)(bm + r)*K + k0 + kc];
      *(uint4*)&Bs[r][kc] = *(const uint4*)&Wt[(size_t)(bn + r)*K + k0 + kc];
    }
    __syncthreads();
    #pragma unroll
    for (int ks = 0; ks < 2; ++ks) {
      bf16x8 a[4], b[4];
      #pragma unroll
      for (int i = 0; i < 4; ++i)
        a[i] = *(const bf16x8*)&As[wr + i*16 + lr][ks*32 + lk];
      #pragma unroll
      for (int i = 0; i < 4; ++i)
        b[i] = *(const bf16x8*)&Bs[wc + i*16 + lr][ks*32 + lk];
      #pragma unroll
      for (int i = 0; i < 4; ++i)
        #pragma unroll
        for (int j = 0; j < 4; ++j)
          acc[i][j] = __builtin_amdgcn_mfma_f32_16x16x32_bf16(a[i], b[j], acc[i][j], 0, 0, 0);
    }
    __syncthreads();
  }
  int r0 = (lane >> 4) * 4;
  #pragma unroll
  for (int i = 0; i < 4; ++i) {
    #pragma unroll
    for (int j = 0; j < 4; ++j) {
      int col = bn + wc + j*16 + lr;
      float bv = bias ? bias[col] : 0.f;
      #pragma unroll
      for (int rr = 0; rr < 4; ++rr) {
        int row = bm + wr + i*16 + r0 + rr;
        float v = acc[i][j][rr] + bv;
        if (ACT) v = lrelu(v);
        if (OUT_BF16) ((unsigned short*)Cv)[(size_t)row*N + col] = f2bf(v);
        else          ((float*)Cv)[(size_t)row*N + col] = v;
      }
    }
  }
}

// ---------------- build objects (2304 x 256) bf16; panel ld=256, +post_b ----------------
__global__ void k_objects(const float* __restrict__ panel, const float* __restrict__ post_b,
                          unsigned short* __restrict__ obj)
{
  int idx = blockIdx.x*256 + threadIdx.x;
  int row = idx >> 8;
  int k = idx & 255;
  int slot = row % 9;
  int nn = row / 9;
  int b = nn >> 3, opt = nn & 7;
  float v;
  if (k < 247) {
    int src = (slot < 8) ? (b*16 + slot) : (b*16 + 8 + opt);
    v = panel[(size_t)src*256 + k] + post_b[k];
  } else {
    v = ((k - 247) == slot) ? 1.0f : 0.0f;
  }
  obj[idx] = f2bf(v);
}

// ---------------- expand: Z[n,i,j,k] = bf16(lrelu(UV[n*9+i][k] + UV[n*9+j][N+k] + b[k])) ----------------
__global__ void k_expand(const float* __restrict__ UV, const float* __restrict__ bias,
                         unsigned short* __restrict__ Z, int N)
{
  int idx = blockIdx.x*256 + threadIdx.x;
  int m = idx / N, k = idx % N;
  int n = m / 81, r = m % 81;
  int i = r / 9, j = r % 9;
  int ld = 2*N;
  float v = UV[(size_t)(n*9 + i)*ld + k] + UV[(size_t)(n*9 + j)*ld + N + k] + bias[k];
  Z[idx] = f2bf(lrelu(v));
}

// ---------------- sum over j: bf16 (256,9,9,C) -> fp32+bf16 (256,9,C) ----------------
__global__ void k_sumj(const unsigned short* __restrict__ Z, float* __restrict__ SJ,
                       unsigned short* __restrict__ SJb, int C)
{
  int idx = blockIdx.x*256 + threadIdx.x;
  int orow = idx / C, k = idx % C;
  int n = orow / 9, i = orow % 9;
  const unsigned short* base = Z + (size_t)(n*81 + i*9)*C + k;
  float s = 0.f;
  #pragma unroll
  for (int j = 0; j < 9; ++j) s += bf2f(base[(size_t)j*C]);
  SJ[idx] = s;
  SJb[idx] = f2bf(s);
}

__global__ void k_hsum(const float* __restrict__ SJ, float* __restrict__ HS)
{
  int idx = blockIdx.x*256 + threadIdx.x;
  int n = idx >> 8, k = idx & 255;
  const float* base = SJ + (size_t)n*9*256 + k;
  float s = 0.f;
  #pragma unroll
  for (int i = 0; i < 9; ++i) s += base[i*256];
  HS[idx] = s;
}

// ---------------- fused tail: result + loss ----------------
__global__ __launch_bounds__(256) void k_tailfin(
    const float* __restrict__ HS, const float* __restrict__ F2,
    const float* __restrict__ ffw, const float* __restrict__ ffb,
    float* __restrict__ out)
{
  __shared__ float red[256];
  __shared__ float wsm[256];
  int tid = threadIdx.x;
  wsm[tid] = ffw[tid];
  float s = 0.f;
  for (int j = 0; j < 256; ++j) { float v = HS[j*256 + tid]; s += v*v; }
  red[tid] = s; __syncthreads();
  for (int off = 128; off > 0; off >>= 1) { if (tid < off) red[tid] += red[tid + off]; __syncthreads(); }
  float hsq = red[0];
  __syncthreads();
  float r = ffb[0];
  for (int k = 0; k < 256; ++k) r += F2[(size_t)tid*256 + k]*wsm[k];
  red[tid] = r*r; __syncthreads();
  for (int off = 128; off > 0; off >>= 1) { if (tid < off) red[tid] += red[tid + off]; __syncthreads(); }
  out[tid] = r;
  if (tid == 0) out[256] = hsq/65536.0f + red[0]/256.0f;
}

extern "C" void kernel_launch(void* const* d_in, const int* in_sizes, int n_in,
                              void* d_out, int out_size, void* d_ws, size_t ws_size,
                              hipStream_t stream)
{
  const float* batch   = (const float*)d_in[0];
  const float* conv_w1 = (const float*)d_in[1];
  const float* conv_b1 = (const float*)d_in[2];
  const float* conv_w2 = (const float*)d_in[3];
  const float* conv_b2 = (const float*)d_in[4];
  const float* conv_w3 = (const float*)d_in[5];
  const float* conv_b3 = (const float*)d_in[6];
  const float* conv_w4 = (const float*)d_in[7];
  const float* conv_b4 = (const float*)d_in[8];
  const float* post_w  = (const float*)d_in[9];
  const float* post_b  = (const float*)d_in[10];
  const float* g_w1    = (const float*)d_in[11];
  const float* g_b1    = (const float*)d_in[12];
  const float* g_w2    = (const float*)d_in[13];
  const float* g_b2    = (const float*)d_in[14];
  const float* g_w3    = (const float*)d_in[15];
  const float* g_b3    = (const float*)d_in[16];
  const float* g_w4    = (const float*)d_in[17];
  const float* g_b4    = (const float*)d_in[18];
  const float* h_w1    = (const float*)d_in[19];
  const float* h_b1    = (const float*)d_in[20];
  const float* h_w2    = (const float*)d_in[21];
  const float* h_b2    = (const float*)d_in[22];
  const float* h_w3    = (const float*)d_in[23];
  const float* h_b3    = (const float*)d_in[24];
  const float* f_w1    = (const float*)d_in[25];
  const float* f_b1    = (const float*)d_in[26];
  const float* f_w2    = (const float*)d_in[27];
  const float* f_b2    = (const float*)d_in[28];
  const float* ff_w    = (const float*)d_in[29];
  const float* ff_b    = (const float*)d_in[30];

  char* wsb = (char*)d_ws;
  const size_t off_Y1    = 0;             // 49.9 MB bf16 NHWC
  const size_t off_Y2    = 52000000;
  const size_t off_Y3    = 64000000;
  const size_t off_Y4    = 67000000;
  const size_t off_PANEL = 68000000;      // fp32 [512][256]
  const size_t off_WT    = 132000000;     // bf16 weights (3.75 MB)
  const size_t off_Pb    = 0;             // MLP ping-pong (convs dead by then)
  const size_t off_Qb    = 22000000;
  const size_t off_UV    = 44000000;      // fp32 [2304][1024] max = 9.44 MB
  const size_t off_OBJb  = 54000000;
  const size_t off_SJ    = 56000000;
  const size_t off_SJb   = 59000000;
  const size_t off_HS    = 61000000;
  const size_t off_F1    = 62000000;
  const size_t off_F2    = 63000000;

  unsigned short* WT = (unsigned short*)(wsb + off_WT);
  const size_t wt_g1   = 0;
  const size_t wt_g2   = 262144;
  const size_t wt_g3   = 524288;
  const size_t wt_g4   = 786432;
  const size_t wt_h1   = 917504;     // 3 x 131072
  const size_t wt_h2   = 1310720;    // 3 x 65536
  const size_t wt_h3   = 1507328;    // 3 x 65536
  const size_t wt_post = 1703936;
  const size_t wt_cw2  = 1835008;
  const size_t wt_cw3  = 1844224;
  const size_t wt_cw4  = 1853440;
  const size_t wt_cw1  = 1862656;

  dim3 b256(256);

  // single weight-prep dispatch (1871872 elems)
  k_prep<<<dim3(7312), b256, 0, stream>>>(g_w1, g_w2, g_w3, g_w4, h_w1, h_w2, h_w3,
                                          post_w, conv_w2, conv_w3, conv_w4, conv_w1, WT);

  unsigned short* Y1 = (unsigned short*)(wsb + off_Y1);
  unsigned short* Y2 = (unsigned short*)(wsb + off_Y2);
  unsigned short* Y3 = (unsigned short*)(wsb + off_Y3);
  unsigned short* Y4 = (unsigned short*)(wsb + off_Y4);
  float* PANEL = (float*)(wsb + off_PANEL);

  // conv stack (all MFMA)
  k_conv1m<<<dim3(512,13), b256, 0, stream>>>(batch, WT + wt_cw1, conv_b1, Y1);
  k_cmfma<39,39,19,19,10><<<dim3(512,2), b256, 0, stream>>>(Y1, WT + wt_cw2, conv_b2, Y2);
  k_cmfma<19,19, 9, 9, 9><<<dim3(512,1), b256, 0, stream>>>(Y2, WT + wt_cw3, conv_b3, Y3);
  k_cmfma< 9, 9, 4, 4, 4><<<dim3(512,1), b256, 0, stream>>>(Y3, WT + wt_cw4, conv_b4, Y4);

  // post: Y4(512x512 bf16) @ post (MFMA), PANEL fp32 ld 256
  k_mgemm<0,0><<<dim3(4,2), b256, 0, stream>>>(Y4, WT + wt_post, nullptr, PANEL, 512,256,512);

  unsigned short* OBJb = (unsigned short*)(wsb + off_OBJb);
  unsigned short* Pb   = (unsigned short*)(wsb + off_Pb);
  unsigned short* Qb   = (unsigned short*)(wsb + off_Qb);
  unsigned short* SJb  = (unsigned short*)(wsb + off_SJb);
  float* UV = (float*)(wsb + off_UV);
  float* SJ = (float*)(wsb + off_SJ);
  float* HS = (float*)(wsb + off_HS);
  float* F1 = (float*)(wsb + off_F1);
  float* F2 = (float*)(wsb + off_F2);

  k_objects<<<dim3(2304), b256, 0, stream>>>(PANEL, post_b, OBJb);

  // g1 (U|V combined, N=1024)
  k_mgemm<0,0><<<dim3(18,8), b256, 0, stream>>>(OBJb, WT + wt_g1, nullptr, UV, 2304,1024,256);
  k_expand<<<dim3(20736*512/256), b256, 0, stream>>>(UV, g_b1, Pb, 512);
  k_mgemm<1,1><<<dim3(162,4), b256, 0, stream>>>(Pb, WT + wt_g2, g_b2, Qb, 20736,512,512);
  k_mgemm<1,1><<<dim3(162,4), b256, 0, stream>>>(Qb, WT + wt_g3, g_b3, Pb, 20736,512,512);
  k_mgemm<1,1><<<dim3(162,2), b256, 0, stream>>>(Pb, WT + wt_g4, g_b4, Qb, 20736,256,512);
  k_sumj<<<dim3(2304), b256, 0, stream>>>(Qb, SJ, SJb, 256);

  for (int i = 0; i < 3; ++i) {
    k_mgemm<0,0><<<dim3(18,4), b256, 0, stream>>>(SJb, WT + wt_h1 + (size_t)i*131072, nullptr, UV, 2304,512,256);
    k_expand<<<dim3(20736*256/256), b256, 0, stream>>>(UV, h_b1 + i*256, Pb, 256);
    k_mgemm<1,1><<<dim3(162,2), b256, 0, stream>>>(Pb, WT + wt_h2 + (size_t)i*65536, h_b2 + i*256, Qb, 20736,256,256);
    k_mgemm<1,1><<<dim3(162,2), b256, 0, stream>>>(Qb, WT + wt_h3 + (size_t)i*65536, h_b3 + i*256, Pb, 20736,256,256);
    k_sumj<<<dim3(2304), b256, 0, stream>>>(Pb, SJ, SJb, 256);
  }

  // head
  k_hsum<<<dim3(256), b256, 0, stream>>>(SJ, HS);
  k_gemm<<<dim3(2,4), b256, 0, stream>>>(HS, f_w1, f_b1, F1, 256,256,256, 256, 1);
  k_gemm<<<dim3(2,4), b256, 0, stream>>>(F1, f_w2, f_b2, F2, 256,256,256, 256, 1);
  k_tailfin<<<dim3(1), b256, 0, stream>>>(HS, F2, ff_w, ff_b, (float*)d_out);
}

// Round 6
// 411.050 us; speedup vs baseline: 9.8052x; 1.2459x over previous
//
#include <hip/hip_runtime.h>
#include <hip/hip_bf16.h>
#include <math.h>

static __device__ __forceinline__ float lrelu(float v){ return v > 0.0f ? v : 0.01f*v; }

static __device__ __forceinline__ unsigned short f2bf(float f){
  unsigned int u = __float_as_uint(f);
  unsigned int r = (u + 0x7fffu + ((u >> 16) & 1u)) >> 16;
  return (unsigned short)r;
}
static __device__ __forceinline__ float bf2f(unsigned short u){
  return __uint_as_float(((unsigned int)u) << 16);
}
static __device__ __forceinline__ unsigned int pack_bf2(float lo, float hi){
  __hip_bfloat162 bb = __float22bfloat162_rn(make_float2(lo, hi));
  return *reinterpret_cast<unsigned int*>(&bb);
}

#define ENC_INV  2.5253813613805277f
#define ENC_NORM 1.4247939f

typedef __attribute__((ext_vector_type(4))) float f32x4;
typedef __attribute__((ext_vector_type(8))) short bf16x8;

// ================= unified weight prep =================
// WT element offsets:
//   wt_g1   = 0        [1024][256]
//   wt_g2   = 262144   [512][512]
//   wt_g3   = 524288   [512][512]
//   wt_g4   = 786432   [256][512]
//   wt_h1   = 917504   3 x [512][256]
//   wt_h2   = 1310720  3 x [256][256]
//   wt_h3   = 1507328  3 x [256][256]
//   wt_post = 1703936  [256][512]
//   wt_cw2  = 1835008  [9][32][32]; cw3=1844224; cw4=1853440
//   wt_cw1  = 1862656  [9][32][32] (c<20 valid)
//   wt_f1   = 1871872  [256][256]
//   wt_f2   = 1937408  [256][256]
// total 2002944 elems -> 7824 blocks
__global__ __launch_bounds__(256) void k_prep(
    const float* __restrict__ g_w1, const float* __restrict__ g_w2,
    const float* __restrict__ g_w3, const float* __restrict__ g_w4,
    const float* __restrict__ h_w1, const float* __restrict__ h_w2,
    const float* __restrict__ h_w3, const float* __restrict__ post_w,
    const float* __restrict__ conv_w2, const float* __restrict__ conv_w3,
    const float* __restrict__ conv_w4, const float* __restrict__ conv_w1,
    const float* __restrict__ f_w1, const float* __restrict__ f_w2,
    unsigned short* __restrict__ WT)
{
  int e = blockIdx.x*256 + threadIdx.x;
  float v;
  if (e < 262144) {
    int nn = e >> 8, kk = e & 255;
    v = (nn < 512) ? g_w1[kk*512 + nn] : g_w1[(256+kk)*512 + (nn-512)];
  } else if (e < 524288) {
    int r = e - 262144; int nn = r >> 9, kk = r & 511;
    v = g_w2[kk*512 + nn];
  } else if (e < 786432) {
    int r = e - 524288; int nn = r >> 9, kk = r & 511;
    v = g_w3[kk*512 + nn];
  } else if (e < 917504) {
    int r = e - 786432; int nn = r >> 9, kk = r & 511;
    v = g_w4[kk*256 + nn];
  } else if (e < 1310720) {
    int r = e - 917504; int i = r >> 17; int q = r & 131071;
    int nn = q >> 8, kk = q & 255;
    v = (nn < 256) ? h_w1[i*131072 + kk*256 + nn]
                   : h_w1[i*131072 + (256+kk)*256 + (nn-256)];
  } else if (e < 1507328) {
    int r = e - 1310720; int i = r >> 16; int q = r & 65535;
    int nn = q >> 8, kk = q & 255;
    v = h_w2[i*65536 + kk*256 + nn];
  } else if (e < 1703936) {
    int r = e - 1507328; int i = r >> 16; int q = r & 65535;
    int nn = q >> 8, kk = q & 255;
    v = h_w3[i*65536 + kk*256 + nn];
  } else if (e < 1835008) {
    int r = e - 1703936; int np = r >> 9, kp = r & 511;
    int px = kp >> 5, c = kp & 31;
    v = (np < 247) ? post_w[(c*16+px)*247 + np] : 0.f;
  } else if (e < 1862656) {
    int r = e - 1835008; int which = r / 9216; int q = r % 9216;
    int tap = q >> 10, o = (q >> 5) & 31, c = q & 31;
    const float* w = which==0 ? conv_w2 : (which==1 ? conv_w3 : conv_w4);
    v = w[(o*32+c)*9 + tap];
  } else if (e < 1871872) {
    int r = e - 1862656; int tap = r >> 10, o = (r >> 5) & 31, c = r & 31;
    v = (c < 20) ? conv_w1[(o*20+c)*9 + tap] : 0.f;
  } else if (e < 1937408) {
    int r = e - 1871872; int nn = r >> 8, kk = r & 255;
    v = f_w1[kk*256 + nn];
  } else {
    int r = e - 1937408; int nn = r >> 8, kk = r & 255;
    v = f_w2[kk*256 + nn];
  }
  WT[e] = f2bf(v);
}

// ================= conv1: fused encoding + MFMA implicit GEMM (20->32, k3 s2) =================
__global__ __launch_bounds__(256) void k_conv1m(
    const float* __restrict__ batch, const unsigned short* __restrict__ wc1,
    const float* __restrict__ bias, unsigned short* __restrict__ y)
{
  __shared__ unsigned short ench[7][80][40];   // 44.8 KB
  int n = blockIdx.x;
  int orow0 = blockIdx.y * 3;
  int irow0 = orow0 * 2;
  int tid = threadIdx.x;
  int lane = tid & 63, wid = tid >> 6;
  int lr = lane & 15, kg = lane >> 4;

  bf16x8 bf0[9], bf1[9];
  #pragma unroll
  for (int tap = 0; tap < 9; ++tap) {
    bf0[tap] = *(const bf16x8*)&wc1[tap*1024 + lr*32 + kg*8];
    bf1[tap] = *(const bf16x8*)&wc1[tap*1024 + (16+lr)*32 + kg*8];
  }

  const float* img = batch + (size_t)n*6400 + irow0*80;
  for (int p = tid; p < 7*79; p += 256) {
    int r = p / 79, col = p % 79;
    float x = img[r*80 + col];
    float t = tanhf(x * (2.0f/255.0f) - 1.0f);
    unsigned int pk[16];
    #pragma unroll
    for (int cp = 0; cp < 10; ++cp) {
      float mg0 = -1.0f + (2.0f/19.0f)*(float)(2*cp);
      float mg1 = -1.0f + (2.0f/19.0f)*(float)(2*cp+1);
      float u0 = (t + mg0)*ENC_INV, u1 = (t + mg1)*ENC_INV;
      pk[cp] = pack_bf2(ENC_NORM*__expf(-u0*u0), ENC_NORM*__expf(-u1*u1));
    }
    #pragma unroll
    for (int cp = 10; cp < 16; ++cp) pk[cp] = 0u;
    int hidx = (col & 1) ? 40 + (col >> 1) : (col >> 1);
    unsigned short* dst = &ench[r][hidx][0];
    *(uint4*)(dst)      = *(uint4*)&pk[0];
    *(uint4*)(dst + 8)  = *(uint4*)&pk[4];
    *(uint4*)(dst + 16) = *(uint4*)&pk[8];
    *(uint4*)(dst + 24) = *(uint4*)&pk[12];
  }
  __syncthreads();

  const int totpx = 117;
  float b0 = bias[lr], b1 = bias[16 + lr];
  for (int t = wid; t < 8; t += 4) {
    int pa = t*16 + lr;
    int pc = (pa < totpx) ? pa : (totpx - 1);
    int oh = pc / 39, ow = pc % 39;
    f32x4 acc0 = {0.f,0.f,0.f,0.f}, acc1 = {0.f,0.f,0.f,0.f};
    #pragma unroll
    for (int kh = 0; kh < 3; ++kh) {
      int r = oh*2 + kh;
      #pragma unroll
      for (int kw = 0; kw < 3; ++kw) {
        int hidx = (kw == 1) ? (40 + ow) : (ow + (kw >> 1));
        bf16x8 a = *(const bf16x8*)&ench[r][hidx][kg*8];
        int tap = kh*3 + kw;
        acc0 = __builtin_amdgcn_mfma_f32_16x16x32_bf16(a, bf0[tap], acc0, 0, 0, 0);
        acc1 = __builtin_amdgcn_mfma_f32_16x16x32_bf16(a, bf1[tap], acc1, 0, 0, 0);
      }
    }
    #pragma unroll
    for (int rr = 0; rr < 4; ++rr) {
      int ps = t*16 + kg*4 + rr;
      if (ps < totpx) {
        int soh = orow0 + ps / 39, sow = ps % 39;
        unsigned short* op = y + (((size_t)n*39 + soh)*39 + sow)*32;
        op[lr]      = f2bf(lrelu(acc0[rr] + b0));
        op[16 + lr] = f2bf(lrelu(acc1[rr] + b1));
      }
    }
  }
}

// ---------------- conv2/3/4: bf16 MFMA implicit GEMM ----------------
template<int H, int W, int OH, int OW, int ROWS>
__global__ __launch_bounds__(256) void k_cmfma(
    const unsigned short* __restrict__ in, const unsigned short* __restrict__ wc,
    const float* __restrict__ bias, unsigned short* __restrict__ out)
{
  constexpr int IR = 2*ROWS + 1;
  __shared__ unsigned short xs[IR][W][40];
  int n = blockIdx.x;
  int orow0 = blockIdx.y * ROWS;
  int nrows = min(ROWS, OH - orow0);
  int irow0 = orow0 * 2;
  int ir = min(2*nrows + 1, H - irow0);
  int tid = threadIdx.x;
  int lane = tid & 63, wid = tid >> 6;
  int lr = lane & 15, kg = lane >> 4;

  bf16x8 bf0[9], bf1[9];
  #pragma unroll
  for (int tap = 0; tap < 9; ++tap) {
    bf0[tap] = *(const bf16x8*)&wc[(tap*32 + lr)*32      + kg*8];
    bf1[tap] = *(const bf16x8*)&wc[(tap*32 + 16 + lr)*32 + kg*8];
  }

  const unsigned short* ip = in + ((size_t)n*H + irow0)*W*32;
  int npx = ir * W;
  for (int p = tid; p < npx; p += 256) {
    const uint4* src = (const uint4*)(ip + (size_t)p*32);
    uint4 v0 = src[0], v1 = src[1], v2 = src[2], v3 = src[3];
    int r = p / W, col = p % W;
    unsigned short* dst = &xs[r][col][0];
    *(uint4*)(dst)      = v0;
    *(uint4*)(dst + 8)  = v1;
    *(uint4*)(dst + 16) = v2;
    *(uint4*)(dst + 24) = v3;
  }
  __syncthreads();

  int totpx = nrows * OW;
  int ntiles = (totpx + 15) >> 4;
  float b0 = bias[lr], b1 = bias[16 + lr];
  for (int t = wid; t < ntiles; t += 4) {
    int pa = t*16 + lr;
    int pc = (pa < totpx) ? pa : 0;
    int oh = pc / OW, ow = pc % OW;
    f32x4 acc0 = {0.f,0.f,0.f,0.f}, acc1 = {0.f,0.f,0.f,0.f};
    #pragma unroll
    for (int kh = 0; kh < 3; ++kh)
      #pragma unroll
      for (int kw = 0; kw < 3; ++kw) {
        bf16x8 a = *(const bf16x8*)&xs[oh*2 + kh][ow*2 + kw][kg*8];
        acc0 = __builtin_amdgcn_mfma_f32_16x16x32_bf16(a, bf0[kh*3+kw], acc0, 0, 0, 0);
        acc1 = __builtin_amdgcn_mfma_f32_16x16x32_bf16(a, bf1[kh*3+kw], acc1, 0, 0, 0);
      }
    #pragma unroll
    for (int rr = 0; rr < 4; ++rr) {
      int ps = t*16 + kg*4 + rr;
      if (ps < totpx) {
        int soh = orow0 + ps / OW, sow = ps % OW;
        unsigned short* op = out + (((size_t)n*OH + soh)*OW + sow)*32;
        op[lr]      = f2bf(lrelu(acc0[rr] + b0));
        op[16 + lr] = f2bf(lrelu(acc1[rr] + b1));
      }
    }
  }
}

// ---------------- bf16 MFMA GEMM: C = act(A(MxK,bf16) @ Wt(NxK,bf16)^T + bias) ----------------
template<int OUT_BF16, int ACT>
__global__ __launch_bounds__(256) void k_mgemm(
    const unsigned short* __restrict__ A, const unsigned short* __restrict__ Wt,
    const float* __restrict__ bias, void* __restrict__ Cv,
    int M, int N, int K)
{
  __shared__ unsigned short As[128][72];
  __shared__ unsigned short Bs[128][72];
  int bm = blockIdx.x * 128;
  int bn = blockIdx.y * 128;
  int tid = threadIdx.x;
  int wid = tid >> 6, lane = tid & 63;
  int wr = (wid >> 1) * 64, wc = (wid & 1) * 64;
  int lr = lane & 15, lk = (lane >> 4) * 8;

  f32x4 acc[4][4];
  #pragma unroll
  for (int i = 0; i < 4; ++i)
    #pragma unroll
    for (int j = 0; j < 4; ++j)
      acc[i][j] = (f32x4){0.f,0.f,0.f,0.f};

  for (int k0 = 0; k0 < K; k0 += 64) {
    #pragma unroll
    for (int i = 0; i < 4; ++i) {
      int ch = tid + (i << 8);
      int r = ch >> 3, kc = (ch & 7) * 8;
      *(uint4*)&As[r][kc] = *(const uint4*)&A[(size_t)(bm + r)*K + k0 + kc];
      *(uint4*)&Bs[r][kc] = *(const uint4*)&Wt[(size_t)(bn + r)*K + k0 + kc];
    }
    __syncthreads();
    #pragma unroll
    for (int ks = 0; ks < 2; ++ks) {
      bf16x8 a[4], b[4];
      #pragma unroll
      for (int i = 0; i < 4; ++i)
        a[i] = *(const bf16x8*)&As[wr + i*16 + lr][ks*32 + lk];
      #pragma unroll
      for (int i = 0; i < 4; ++i)
        b[i] = *(const bf16x8*)&Bs[wc + i*16 + lr][ks*32 + lk];
      #pragma unroll
      for (int i = 0; i < 4; ++i)
        #pragma unroll
        for (int j = 0; j < 4; ++j)
          acc[i][j] = __builtin_amdgcn_mfma_f32_16x16x32_bf16(a[i], b[j], acc[i][j], 0, 0, 0);
    }
    __syncthreads();
  }
  int r0 = (lane >> 4) * 4;
  #pragma unroll
  for (int i = 0; i < 4; ++i) {
    #pragma unroll
    for (int j = 0; j < 4; ++j) {
      int col = bn + wc + j*16 + lr;
      float bv = bias ? bias[col] : 0.f;
      #pragma unroll
      for (int rr = 0; rr < 4; ++rr) {
        int row = bm + wr + i*16 + r0 + rr;
        float v = acc[i][j][rr] + bv;
        if (ACT) v = lrelu(v);
        if (OUT_BF16) ((unsigned short*)Cv)[(size_t)row*N + col] = f2bf(v);
        else          ((float*)Cv)[(size_t)row*N + col] = v;
      }
    }
  }
}

// ---------------- build objects (2304 x 256) bf16 ----------------
__global__ void k_objects(const float* __restrict__ panel, const float* __restrict__ post_b,
                          unsigned short* __restrict__ obj)
{
  int idx = blockIdx.x*256 + threadIdx.x;
  int row = idx >> 8;
  int k = idx & 255;
  int slot = row % 9;
  int nn = row / 9;
  int b = nn >> 3, opt = nn & 7;
  float v;
  if (k < 247) {
    int src = (slot < 8) ? (b*16 + slot) : (b*16 + 8 + opt);
    v = panel[(size_t)src*256 + k] + post_b[k];
  } else {
    v = ((k - 247) == slot) ? 1.0f : 0.0f;
  }
  obj[idx] = f2bf(v);
}

// ---------------- expand: Z = bf16(lrelu(UV[i-row] + UV[j-row] + b)), UV bf16 ----------------
__global__ void k_expand(const unsigned short* __restrict__ UV, const float* __restrict__ bias,
                         unsigned short* __restrict__ Z, int N)
{
  int idx = blockIdx.x*256 + threadIdx.x;
  int m = idx / N, k = idx % N;
  int n = m / 81, r = m % 81;
  int i = r / 9, j = r % 9;
  int ld = 2*N;
  float v = bf2f(UV[(size_t)(n*9 + i)*ld + k]) + bf2f(UV[(size_t)(n*9 + j)*ld + N + k]) + bias[k];
  Z[idx] = f2bf(lrelu(v));
}

// ---------------- sum over j ----------------
__global__ void k_sumj(const unsigned short* __restrict__ Z, float* __restrict__ SJ,
                       unsigned short* __restrict__ SJb, int C)
{
  int idx = blockIdx.x*256 + threadIdx.x;
  int orow = idx / C, k = idx % C;
  int n = orow / 9, i = orow % 9;
  const unsigned short* base = Z + (size_t)(n*81 + i*9)*C + k;
  float s = 0.f;
  #pragma unroll
  for (int j = 0; j < 9; ++j) s += bf2f(base[(size_t)j*C]);
  SJ[idx] = s;
  SJb[idx] = f2bf(s);
}

// ---------------- sum over i: fp32 + bf16 out ----------------
__global__ void k_hsum(const float* __restrict__ SJ, float* __restrict__ HS,
                       unsigned short* __restrict__ HSb)
{
  int idx = blockIdx.x*256 + threadIdx.x;
  int n = idx >> 8, k = idx & 255;
  const float* base = SJ + (size_t)n*9*256 + k;
  float s = 0.f;
  #pragma unroll
  for (int i = 0; i < 9; ++i) s += base[i*256];
  HS[idx] = s;
  HSb[idx] = f2bf(s);
}

// ---------------- fused tail: result + loss (F2 bf16) ----------------
__global__ __launch_bounds__(256) void k_tailfin(
    const float* __restrict__ HS, const unsigned short* __restrict__ F2,
    const float* __restrict__ ffw, const float* __restrict__ ffb,
    float* __restrict__ out)
{
  __shared__ float red[256];
  __shared__ float wsm[256];
  int tid = threadIdx.x;
  wsm[tid] = ffw[tid];
  float s = 0.f;
  for (int j = 0; j < 256; ++j) { float v = HS[j*256 + tid]; s += v*v; }
  red[tid] = s; __syncthreads();
  for (int off = 128; off > 0; off >>= 1) { if (tid < off) red[tid] += red[tid + off]; __syncthreads(); }
  float hsq = red[0];
  __syncthreads();
  float r = ffb[0];
  for (int k = 0; k < 256; ++k) r += bf2f(F2[(size_t)tid*256 + k])*wsm[k];
  red[tid] = r*r; __syncthreads();
  for (int off = 128; off > 0; off >>= 1) { if (tid < off) red[tid] += red[tid + off]; __syncthreads(); }
  out[tid] = r;
  if (tid == 0) out[256] = hsq/65536.0f + red[0]/256.0f;
}

extern "C" void kernel_launch(void* const* d_in, const int* in_sizes, int n_in,
                              void* d_out, int out_size, void* d_ws, size_t ws_size,
                              hipStream_t stream)
{
  const float* batch   = (const float*)d_in[0];
  const float* conv_w1 = (const float*)d_in[1];
  const float* conv_b1 = (const float*)d_in[2];
  const float* conv_w2 = (const float*)d_in[3];
  const float* conv_b2 = (const float*)d_in[4];
  const float* conv_w3 = (const float*)d_in[5];
  const float* conv_b3 = (const float*)d_in[6];
  const float* conv_w4 = (const float*)d_in[7];
  const float* conv_b4 = (const float*)d_in[8];
  const float* post_w  = (const float*)d_in[9];
  const float* post_b  = (const float*)d_in[10];
  const float* g_w1    = (const float*)d_in[11];
  const float* g_b1    = (const float*)d_in[12];
  const float* g_w2    = (const float*)d_in[13];
  const float* g_b2    = (const float*)d_in[14];
  const float* g_w3    = (const float*)d_in[15];
  const float* g_b3    = (const float*)d_in[16];
  const float* g_w4    = (const float*)d_in[17];
  const float* g_b4    = (const float*)d_in[18];
  const float* h_w1    = (const float*)d_in[19];
  const float* h_b1    = (const float*)d_in[20];
  const float* h_w2    = (const float*)d_in[21];
  const float* h_b2    = (const float*)d_in[22];
  const float* h_w3    = (const float*)d_in[23];
  const float* h_b3    = (const float*)d_in[24];
  const float* f_w1    = (const float*)d_in[25];
  const float* f_b1    = (const float*)d_in[26];
  const float* f_w2    = (const float*)d_in[27];
  const float* f_b2    = (const float*)d_in[28];
  const float* ff_w    = (const float*)d_in[29];
  const float* ff_b    = (const float*)d_in[30];

  char* wsb = (char*)d_ws;
  const size_t off_Y1    = 0;
  const size_t off_Y2    = 52000000;
  const size_t off_Y3    = 64000000;
  const size_t off_Y4    = 67000000;
  const size_t off_PANEL = 68000000;
  const size_t off_WT    = 132000000;
  const size_t off_Pb    = 0;
  const size_t off_Qb    = 22000000;
  const size_t off_UV    = 44000000;      // bf16 [2304][1024] max = 4.7 MB
  const size_t off_OBJb  = 54000000;
  const size_t off_SJ    = 56000000;
  const size_t off_SJb   = 59000000;
  const size_t off_HS    = 61000000;
  const size_t off_HSb   = 61500000;
  const size_t off_F1    = 62000000;
  const size_t off_F2    = 63000000;

  unsigned short* WT = (unsigned short*)(wsb + off_WT);
  const size_t wt_g1   = 0;
  const size_t wt_g2   = 262144;
  const size_t wt_g3   = 524288;
  const size_t wt_g4   = 786432;
  const size_t wt_h1   = 917504;
  const size_t wt_h2   = 1310720;
  const size_t wt_h3   = 1507328;
  const size_t wt_post = 1703936;
  const size_t wt_cw2  = 1835008;
  const size_t wt_cw3  = 1844224;
  const size_t wt_cw4  = 1853440;
  const size_t wt_cw1  = 1862656;
  const size_t wt_f1   = 1871872;
  const size_t wt_f2   = 1937408;

  dim3 b256(256);

  k_prep<<<dim3(7824), b256, 0, stream>>>(g_w1, g_w2, g_w3, g_w4, h_w1, h_w2, h_w3,
                                          post_w, conv_w2, conv_w3, conv_w4, conv_w1,
                                          f_w1, f_w2, WT);

  unsigned short* Y1 = (unsigned short*)(wsb + off_Y1);
  unsigned short* Y2 = (unsigned short*)(wsb + off_Y2);
  unsigned short* Y3 = (unsigned short*)(wsb + off_Y3);
  unsigned short* Y4 = (unsigned short*)(wsb + off_Y4);
  float* PANEL = (float*)(wsb + off_PANEL);

  k_conv1m<<<dim3(512,13), b256, 0, stream>>>(batch, WT + wt_cw1, conv_b1, Y1);
  k_cmfma<39,39,19,19,10><<<dim3(512,2), b256, 0, stream>>>(Y1, WT + wt_cw2, conv_b2, Y2);
  k_cmfma<19,19, 9, 9, 9><<<dim3(512,1), b256, 0, stream>>>(Y2, WT + wt_cw3, conv_b3, Y3);
  k_cmfma< 9, 9, 4, 4, 4><<<dim3(512,1), b256, 0, stream>>>(Y3, WT + wt_cw4, conv_b4, Y4);

  k_mgemm<0,0><<<dim3(4,2), b256, 0, stream>>>(Y4, WT + wt_post, nullptr, PANEL, 512,256,512);

  unsigned short* OBJb = (unsigned short*)(wsb + off_OBJb);
  unsigned short* Pb   = (unsigned short*)(wsb + off_Pb);
  unsigned short* Qb   = (unsigned short*)(wsb + off_Qb);
  unsigned short* SJb  = (unsigned short*)(wsb + off_SJb);
  unsigned short* UVb  = (unsigned short*)(wsb + off_UV);
  float* SJ = (float*)(wsb + off_SJ);
  float* HS = (float*)(wsb + off_HS);
  unsigned short* HSb = (unsigned short*)(wsb + off_HSb);
  unsigned short* F1 = (unsigned short*)(wsb + off_F1);
  unsigned short* F2 = (unsigned short*)(wsb + off_F2);

  k_objects<<<dim3(2304), b256, 0, stream>>>(PANEL, post_b, OBJb);

  // g1 (U|V combined, N=1024, bf16 out)
  k_mgemm<1,0><<<dim3(18,8), b256, 0, stream>>>(OBJb, WT + wt_g1, nullptr, UVb, 2304,1024,256);
  k_expand<<<dim3(20736*512/256), b256, 0, stream>>>(UVb, g_b1, Pb, 512);
  k_mgemm<1,1><<<dim3(162,4), b256, 0, stream>>>(Pb, WT + wt_g2, g_b2, Qb, 20736,512,512);
  k_mgemm<1,1><<<dim3(162,4), b256, 0, stream>>>(Qb, WT + wt_g3, g_b3, Pb, 20736,512,512);
  k_mgemm<1,1><<<dim3(162,2), b256, 0, stream>>>(Pb, WT + wt_g4, g_b4, Qb, 20736,256,512);
  k_sumj<<<dim3(2304), b256, 0, stream>>>(Qb, SJ, SJb, 256);

  for (int i = 0; i < 3; ++i) {
    k_mgemm<1,0><<<dim3(18,4), b256, 0, stream>>>(SJb, WT + wt_h1 + (size_t)i*131072, nullptr, UVb, 2304,512,256);
    k_expand<<<dim3(20736*256/256), b256, 0, stream>>>(UVb, h_b1 + i*256, Pb, 256);
    k_mgemm<1,1><<<dim3(162,2), b256, 0, stream>>>(Pb, WT + wt_h2 + (size_t)i*65536, h_b2 + i*256, Qb, 20736,256,256);
    k_mgemm<1,1><<<dim3(162,2), b256, 0, stream>>>(Qb, WT + wt_h3 + (size_t)i*65536, h_b3 + i*256, Pb, 20736,256,256);
    k_sumj<<<dim3(2304), b256, 0, stream>>>(Pb, SJ, SJb, 256);
  }

  // head (MFMA)
  k_hsum<<<dim3(256), b256, 0, stream>>>(SJ, HS, HSb);
  k_mgemm<1,1><<<dim3(2,2), b256, 0, stream>>>(HSb, WT + wt_f1, f_b1, F1, 256,256,256);
  k_mgemm<1,1><<<dim3(2,2), b256, 0, stream>>>(F1,  WT + wt_f2, f_b2, F2, 256,256,256);
  k_tailfin<<<dim3(1), b256, 0, stream>>>(HS, F2, ff_w, ff_b, (float*)d_out);
}

// Round 7
// 363.534 us; speedup vs baseline: 11.0868x; 1.1307x over previous
//
#include <hip/hip_runtime.h>
#include <hip/hip_bf16.h>
#include <math.h>

static __device__ __forceinline__ float lrelu(float v){ return v > 0.0f ? v : 0.01f*v; }

static __device__ __forceinline__ unsigned short f2bf(float f){
  unsigned int u = __float_as_uint(f);
  unsigned int r = (u + 0x7fffu + ((u >> 16) & 1u)) >> 16;
  return (unsigned short)r;
}
static __device__ __forceinline__ float bf2f(unsigned short u){
  return __uint_as_float(((unsigned int)u) << 16);
}
static __device__ __forceinline__ unsigned int pack_bf2(float lo, float hi){
  __hip_bfloat162 bb = __float22bfloat162_rn(make_float2(lo, hi));
  return *reinterpret_cast<unsigned int*>(&bb);
}

#define ENC_NORM 1.4247939f
// Gaussian-recurrence constants: c = 1/(2*0.28^2), d = 2/19
#define GC_C     6.3775511f
#define GC_2CD   1.3426423f      // 2*c*d
#define GC_CD2   0.070665395f    // c*d^2
#define GC_S1    0.86820227f     // exp(-2*c*d^2)

typedef __attribute__((ext_vector_type(4))) float f32x4;
typedef __attribute__((ext_vector_type(8))) short bf16x8;

// ================= unified weight prep =================
__global__ __launch_bounds__(256) void k_prep(
    const float* __restrict__ g_w1, const float* __restrict__ g_w2,
    const float* __restrict__ g_w3, const float* __restrict__ g_w4,
    const float* __restrict__ h_w1, const float* __restrict__ h_w2,
    const float* __restrict__ h_w3, const float* __restrict__ post_w,
    const float* __restrict__ conv_w2, const float* __restrict__ conv_w3,
    const float* __restrict__ conv_w4, const float* __restrict__ conv_w1,
    const float* __restrict__ f_w1, const float* __restrict__ f_w2,
    unsigned short* __restrict__ WT)
{
  int e = blockIdx.x*256 + threadIdx.x;
  float v;
  if (e < 262144) {
    int nn = e >> 8, kk = e & 255;
    v = (nn < 512) ? g_w1[kk*512 + nn] : g_w1[(256+kk)*512 + (nn-512)];
  } else if (e < 524288) {
    int r = e - 262144; int nn = r >> 9, kk = r & 511;
    v = g_w2[kk*512 + nn];
  } else if (e < 786432) {
    int r = e - 524288; int nn = r >> 9, kk = r & 511;
    v = g_w3[kk*512 + nn];
  } else if (e < 917504) {
    int r = e - 786432; int nn = r >> 9, kk = r & 511;
    v = g_w4[kk*256 + nn];
  } else if (e < 1310720) {
    int r = e - 917504; int i = r >> 17; int q = r & 131071;
    int nn = q >> 8, kk = q & 255;
    v = (nn < 256) ? h_w1[i*131072 + kk*256 + nn]
                   : h_w1[i*131072 + (256+kk)*256 + (nn-256)];
  } else if (e < 1507328) {
    int r = e - 1310720; int i = r >> 16; int q = r & 65535;
    int nn = q >> 8, kk = q & 255;
    v = h_w2[i*65536 + kk*256 + nn];
  } else if (e < 1703936) {
    int r = e - 1507328; int i = r >> 16; int q = r & 65535;
    int nn = q >> 8, kk = q & 255;
    v = h_w3[i*65536 + kk*256 + nn];
  } else if (e < 1835008) {
    int r = e - 1703936; int np = r >> 9, kp = r & 511;
    int px = kp >> 5, c = kp & 31;
    v = (np < 247) ? post_w[(c*16+px)*247 + np] : 0.f;
  } else if (e < 1862656) {
    int r = e - 1835008; int which = r / 9216; int q = r % 9216;
    int tap = q >> 10, o = (q >> 5) & 31, c = q & 31;
    const float* w = which==0 ? conv_w2 : (which==1 ? conv_w3 : conv_w4);
    v = w[(o*32+c)*9 + tap];
  } else if (e < 1871872) {
    int r = e - 1862656; int tap = r >> 10, o = (r >> 5) & 31, c = r & 31;
    v = (c < 20) ? conv_w1[(o*20+c)*9 + tap] : 0.f;
  } else if (e < 1937408) {
    int r = e - 1871872; int nn = r >> 8, kk = r & 255;
    v = f_w1[kk*256 + nn];
  } else {
    int r = e - 1937408; int nn = r >> 8, kk = r & 255;
    v = f_w2[kk*256 + nn];
  }
  WT[e] = f2bf(v);
}

// ================= conv1: fused encoding + MFMA implicit GEMM (20->32, k3 s2) =================
// enc via Gaussian recurrence: 2 exps + 1 fast-tanh per pixel instead of 21 transcendentals.
__global__ __launch_bounds__(256) void k_conv1m(
    const float* __restrict__ batch, const unsigned short* __restrict__ wc1,
    const float* __restrict__ bias, unsigned short* __restrict__ y)
{
  __shared__ unsigned short ench[7][80][40];   // 44.8 KB
  int n = blockIdx.x;
  int orow0 = blockIdx.y * 3;
  int irow0 = orow0 * 2;
  int tid = threadIdx.x;
  int lane = tid & 63, wid = tid >> 6;
  int lr = lane & 15, kg = lane >> 4;

  bf16x8 bf0[9], bf1[9];
  #pragma unroll
  for (int tap = 0; tap < 9; ++tap) {
    bf0[tap] = *(const bf16x8*)&wc1[tap*1024 + lr*32 + kg*8];
    bf1[tap] = *(const bf16x8*)&wc1[tap*1024 + (16+lr)*32 + kg*8];
  }

  const float* img = batch + (size_t)n*6400 + irow0*80;
  const float S2 = GC_S1 * GC_S1;
  for (int p = tid; p < 7*79; p += 256) {
    int row = p / 79, col = p % 79;
    float x = img[row*80 + col];
    // fast tanh(x*2/255 - 1):
    float E = __expf(x * (4.0f/255.0f) - 2.0f);
    float t = 1.0f - 2.0f*__builtin_amdgcn_rcpf(E + 1.0f);
    float z = t - 1.0f;                          // t + mg_0
    float e = ENC_NORM * __expf(-GC_C*z*z);      // e_0
    float rg = __expf(-GC_2CD*z - GC_CD2);       // rho_0
    unsigned int pk[16];
    #pragma unroll
    for (int cp = 0; cp < 10; ++cp) {
      float e1 = e * rg;
      pk[cp] = pack_bf2(e, e1);
      e  = e1 * rg * GC_S1;
      rg = rg * S2;
    }
    #pragma unroll
    for (int cp = 10; cp < 16; ++cp) pk[cp] = 0u;
    int hidx = (col & 1) ? 40 + (col >> 1) : (col >> 1);
    unsigned short* dst = &ench[row][hidx][0];
    *(uint4*)(dst)      = *(uint4*)&pk[0];
    *(uint4*)(dst + 8)  = *(uint4*)&pk[4];
    *(uint4*)(dst + 16) = *(uint4*)&pk[8];
    *(uint4*)(dst + 24) = *(uint4*)&pk[12];
  }
  __syncthreads();

  const int totpx = 117;
  float b0 = bias[lr], b1 = bias[16 + lr];
  for (int t = wid; t < 8; t += 4) {
    int pa = t*16 + lr;
    int pc = (pa < totpx) ? pa : (totpx - 1);
    int oh = pc / 39, ow = pc % 39;
    f32x4 acc0 = {0.f,0.f,0.f,0.f}, acc1 = {0.f,0.f,0.f,0.f};
    #pragma unroll
    for (int kh = 0; kh < 3; ++kh) {
      int r = oh*2 + kh;
      #pragma unroll
      for (int kw = 0; kw < 3; ++kw) {
        int hidx = (kw == 1) ? (40 + ow) : (ow + (kw >> 1));
        bf16x8 a = *(const bf16x8*)&ench[r][hidx][kg*8];
        int tap = kh*3 + kw;
        acc0 = __builtin_amdgcn_mfma_f32_16x16x32_bf16(a, bf0[tap], acc0, 0, 0, 0);
        acc1 = __builtin_amdgcn_mfma_f32_16x16x32_bf16(a, bf1[tap], acc1, 0, 0, 0);
      }
    }
    #pragma unroll
    for (int rr = 0; rr < 4; ++rr) {
      int ps = t*16 + kg*4 + rr;
      if (ps < totpx) {
        int soh = orow0 + ps / 39, sow = ps % 39;
        unsigned short* op = y + (((size_t)n*39 + soh)*39 + sow)*32;
        op[lr]      = f2bf(lrelu(acc0[rr] + b0));
        op[16 + lr] = f2bf(lrelu(acc1[rr] + b1));
      }
    }
  }
}

// ---------------- conv2/3/4: bf16 MFMA implicit GEMM ----------------
template<int H, int W, int OH, int OW, int ROWS>
__global__ __launch_bounds__(256) void k_cmfma(
    const unsigned short* __restrict__ in, const unsigned short* __restrict__ wc,
    const float* __restrict__ bias, unsigned short* __restrict__ out)
{
  constexpr int IR = 2*ROWS + 1;
  __shared__ unsigned short xs[IR][W][40];
  int n = blockIdx.x;
  int orow0 = blockIdx.y * ROWS;
  int nrows = min(ROWS, OH - orow0);
  int irow0 = orow0 * 2;
  int ir = min(2*nrows + 1, H - irow0);
  int tid = threadIdx.x;
  int lane = tid & 63, wid = tid >> 6;
  int lr = lane & 15, kg = lane >> 4;

  bf16x8 bf0[9], bf1[9];
  #pragma unroll
  for (int tap = 0; tap < 9; ++tap) {
    bf0[tap] = *(const bf16x8*)&wc[(tap*32 + lr)*32      + kg*8];
    bf1[tap] = *(const bf16x8*)&wc[(tap*32 + 16 + lr)*32 + kg*8];
  }

  const unsigned short* ip = in + ((size_t)n*H + irow0)*W*32;
  int npx = ir * W;
  for (int p = tid; p < npx; p += 256) {
    const uint4* src = (const uint4*)(ip + (size_t)p*32);
    uint4 v0 = src[0], v1 = src[1], v2 = src[2], v3 = src[3];
    int r = p / W, col = p % W;
    unsigned short* dst = &xs[r][col][0];
    *(uint4*)(dst)      = v0;
    *(uint4*)(dst + 8)  = v1;
    *(uint4*)(dst + 16) = v2;
    *(uint4*)(dst + 24) = v3;
  }
  __syncthreads();

  int totpx = nrows * OW;
  int ntiles = (totpx + 15) >> 4;
  float b0 = bias[lr], b1 = bias[16 + lr];
  for (int t = wid; t < ntiles; t += 4) {
    int pa = t*16 + lr;
    int pc = (pa < totpx) ? pa : 0;
    int oh = pc / OW, ow = pc % OW;
    f32x4 acc0 = {0.f,0.f,0.f,0.f}, acc1 = {0.f,0.f,0.f,0.f};
    #pragma unroll
    for (int kh = 0; kh < 3; ++kh)
      #pragma unroll
      for (int kw = 0; kw < 3; ++kw) {
        bf16x8 a = *(const bf16x8*)&xs[oh*2 + kh][ow*2 + kw][kg*8];
        acc0 = __builtin_amdgcn_mfma_f32_16x16x32_bf16(a, bf0[kh*3+kw], acc0, 0, 0, 0);
        acc1 = __builtin_amdgcn_mfma_f32_16x16x32_bf16(a, bf1[kh*3+kw], acc1, 0, 0, 0);
      }
    #pragma unroll
    for (int rr = 0; rr < 4; ++rr) {
      int ps = t*16 + kg*4 + rr;
      if (ps < totpx) {
        int soh = orow0 + ps / OW, sow = ps % OW;
        unsigned short* op = out + (((size_t)n*OH + soh)*OW + sow)*32;
        op[lr]      = f2bf(lrelu(acc0[rr] + b0));
        op[16 + lr] = f2bf(lrelu(acc1[rr] + b1));
      }
    }
  }
}

// ---------------- bf16 MFMA GEMM: C = act(A(MxK,bf16) @ Wt(NxK,bf16)^T + bias) ----------------
template<int OUT_BF16, int ACT>
__global__ __launch_bounds__(256) void k_mgemm(
    const unsigned short* __restrict__ A, const unsigned short* __restrict__ Wt,
    const float* __restrict__ bias, void* __restrict__ Cv,
    int M, int N, int K)
{
  __shared__ unsigned short As[128][72];
  __shared__ unsigned short Bs[128][72];
  int bm = blockIdx.x * 128;
  int bn = blockIdx.y * 128;
  int tid = threadIdx.x;
  int wid = tid >> 6, lane = tid & 63;
  int wr = (wid >> 1) * 64, wc = (wid & 1) * 64;
  int lr = lane & 15, lk = (lane >> 4) * 8;

  f32x4 acc[4][4];
  #pragma unroll
  for (int i = 0; i < 4; ++i)
    #pragma unroll
    for (int j = 0; j < 4; ++j)
      acc[i][j] = (f32x4){0.f,0.f,0.f,0.f};

  for (int k0 = 0; k0 < K; k0 += 64) {
    #pragma unroll
    for (int i = 0; i < 4; ++i) {
      int ch = tid + (i << 8);
      int r = ch >> 3, kc = (ch & 7) * 8;
      *(uint4*)&As[r][kc] = *(const uint4*)&A[(size_t)(bm + r)*K + k0 + kc];
      *(uint4*)&Bs[r][kc] = *(const uint4*)&Wt[(size_t)(bn + r)*K + k0 + kc];
    }
    __syncthreads();
    #pragma unroll
    for (int ks = 0; ks < 2; ++ks) {
      bf16x8 a[4], b[4];
      #pragma unroll
      for (int i = 0; i < 4; ++i)
        a[i] = *(const bf16x8*)&As[wr + i*16 + lr][ks*32 + lk];
      #pragma unroll
      for (int i = 0; i < 4; ++i)
        b[i] = *(const bf16x8*)&Bs[wc + i*16 + lr][ks*32 + lk];
      #pragma unroll
      for (int i = 0; i < 4; ++i)
        #pragma unroll
        for (int j = 0; j < 4; ++j)
          acc[i][j] = __builtin_amdgcn_mfma_f32_16x16x32_bf16(a[i], b[j], acc[i][j], 0, 0, 0);
    }
    __syncthreads();
  }
  int r0 = (lane >> 4) * 4;
  #pragma unroll
  for (int i = 0; i < 4; ++i) {
    #pragma unroll
    for (int j = 0; j < 4; ++j) {
      int col = bn + wc + j*16 + lr;
      float bv = bias ? bias[col] : 0.f;
      #pragma unroll
      for (int rr = 0; rr < 4; ++rr) {
        int row = bm + wr + i*16 + r0 + rr;
        float v = acc[i][j][rr] + bv;
        if (ACT) v = lrelu(v);
        if (OUT_BF16) ((unsigned short*)Cv)[(size_t)row*N + col] = f2bf(v);
        else          ((float*)Cv)[(size_t)row*N + col] = v;
      }
    }
  }
}

// ---------------- pair GEMM: fused expand + GEMM ----------------
// A[m][k] = lrelu(UV[n*9+i][k] + UV[n*9+j][K+k] + abias[k]), m = n*81+i*9+j.
// C = lrelu(A @ Wt^T + obias), bf16 out. M multiple of 128.
__global__ __launch_bounds__(256) void k_pgemm(
    const unsigned short* __restrict__ UV, const unsigned short* __restrict__ Wt,
    const float* __restrict__ abias, const float* __restrict__ obias,
    unsigned short* __restrict__ C, int M, int N, int K)
{
  __shared__ unsigned short As[128][72];
  __shared__ unsigned short Bs[128][72];
  __shared__ float absm[512];
  int bm = blockIdx.x * 128;
  int bn = blockIdx.y * 128;
  int tid = threadIdx.x;
  int wid = tid >> 6, lane = tid & 63;
  int wr = (wid >> 1) * 64, wc = (wid & 1) * 64;
  int lr = lane & 15, lk = (lane >> 4) * 8;
  int ld = 2*K;

  for (int idx = tid; idx < K; idx += 256) absm[idx] = abias[idx];
  __syncthreads();

  // per-thread staged rows: r = (tid + i*256)>>3 -> precompute pair row indices
  int urow[4], vrow[4];
  #pragma unroll
  for (int i = 0; i < 4; ++i) {
    int r = (tid + (i << 8)) >> 3;
    int m = bm + r;
    int n = m / 81; int rem = m - n*81;
    int ii = rem / 9; int jj = rem - ii*9;
    urow[i] = n*9 + ii; vrow[i] = n*9 + jj;
  }

  f32x4 acc[4][4];
  #pragma unroll
  for (int i = 0; i < 4; ++i)
    #pragma unroll
    for (int j = 0; j < 4; ++j)
      acc[i][j] = (f32x4){0.f,0.f,0.f,0.f};

  for (int k0 = 0; k0 < K; k0 += 64) {
    #pragma unroll
    for (int i = 0; i < 4; ++i) {
      int ch = tid + (i << 8);
      int r = ch >> 3, kc = (ch & 7) * 8;
      uint4 u4 = *(const uint4*)&UV[(size_t)urow[i]*ld + k0 + kc];
      uint4 v4 = *(const uint4*)&UV[(size_t)vrow[i]*ld + K + k0 + kc];
      const unsigned short* us = (const unsigned short*)&u4;
      const unsigned short* vs = (const unsigned short*)&v4;
      unsigned int pk[4];
      #pragma unroll
      for (int e2 = 0; e2 < 4; ++e2) {
        float a0 = bf2f(us[2*e2])   + bf2f(vs[2*e2])   + absm[k0 + kc + 2*e2];
        float a1 = bf2f(us[2*e2+1]) + bf2f(vs[2*e2+1]) + absm[k0 + kc + 2*e2+1];
        pk[e2] = pack_bf2(lrelu(a0), lrelu(a1));
      }
      *(uint4*)&As[r][kc] = *(uint4*)pk;
      *(uint4*)&Bs[r][kc] = *(const uint4*)&Wt[(size_t)(bn + r)*K + k0 + kc];
    }
    __syncthreads();
    #pragma unroll
    for (int ks = 0; ks < 2; ++ks) {
      bf16x8 a[4], b[4];
      #pragma unroll
      for (int i = 0; i < 4; ++i)
        a[i] = *(const bf16x8*)&As[wr + i*16 + lr][ks*32 + lk];
      #pragma unroll
      for (int i = 0; i < 4; ++i)
        b[i] = *(const bf16x8*)&Bs[wc + i*16 + lr][ks*32 + lk];
      #pragma unroll
      for (int i = 0; i < 4; ++i)
        #pragma unroll
        for (int j = 0; j < 4; ++j)
          acc[i][j] = __builtin_amdgcn_mfma_f32_16x16x32_bf16(a[i], b[j], acc[i][j], 0, 0, 0);
    }
    __syncthreads();
  }
  int r0 = (lane >> 4) * 4;
  #pragma unroll
  for (int i = 0; i < 4; ++i) {
    #pragma unroll
    for (int j = 0; j < 4; ++j) {
      int col = bn + wc + j*16 + lr;
      float bv = obias[col];
      #pragma unroll
      for (int rr = 0; rr < 4; ++rr) {
        int row = bm + wr + i*16 + r0 + rr;
        C[(size_t)row*N + col] = f2bf(lrelu(acc[i][j][rr] + bv));
      }
    }
  }
}

// ---------------- build objects (2304 x 256) bf16 ----------------
__global__ void k_objects(const float* __restrict__ panel, const float* __restrict__ post_b,
                          unsigned short* __restrict__ obj)
{
  int idx = blockIdx.x*256 + threadIdx.x;
  int row = idx >> 8;
  int k = idx & 255;
  int slot = row % 9;
  int nn = row / 9;
  int b = nn >> 3, opt = nn & 7;
  float v;
  if (k < 247) {
    int src = (slot < 8) ? (b*16 + slot) : (b*16 + 8 + opt);
    v = panel[(size_t)src*256 + k] + post_b[k];
  } else {
    v = ((k - 247) == slot) ? 1.0f : 0.0f;
  }
  obj[idx] = f2bf(v);
}

// ---------------- sum over j ----------------
__global__ void k_sumj(const unsigned short* __restrict__ Z, float* __restrict__ SJ,
                       unsigned short* __restrict__ SJb, int C)
{
  int idx = blockIdx.x*256 + threadIdx.x;
  int orow = idx / C, k = idx % C;
  int n = orow / 9, i = orow % 9;
  const unsigned short* base = Z + (size_t)(n*81 + i*9)*C + k;
  float s = 0.f;
  #pragma unroll
  for (int j = 0; j < 9; ++j) s += bf2f(base[(size_t)j*C]);
  SJ[idx] = s;
  SJb[idx] = f2bf(s);
}

// ---------------- sum over i: fp32 + bf16 out ----------------
__global__ void k_hsum(const float* __restrict__ SJ, float* __restrict__ HS,
                       unsigned short* __restrict__ HSb)
{
  int idx = blockIdx.x*256 + threadIdx.x;
  int n = idx >> 8, k = idx & 255;
  const float* base = SJ + (size_t)n*9*256 + k;
  float s = 0.f;
  #pragma unroll
  for (int i = 0; i < 9; ++i) s += base[i*256];
  HS[idx] = s;
  HSb[idx] = f2bf(s);
}

// ---------------- fused tail: result + loss (F2 bf16) ----------------
__global__ __launch_bounds__(256) void k_tailfin(
    const float* __restrict__ HS, const unsigned short* __restrict__ F2,
    const float* __restrict__ ffw, const float* __restrict__ ffb,
    float* __restrict__ out)
{
  __shared__ float red[256];
  __shared__ float wsm[256];
  int tid = threadIdx.x;
  wsm[tid] = ffw[tid];
  float s = 0.f;
  for (int j = 0; j < 256; ++j) { float v = HS[j*256 + tid]; s += v*v; }
  red[tid] = s; __syncthreads();
  for (int off = 128; off > 0; off >>= 1) { if (tid < off) red[tid] += red[tid + off]; __syncthreads(); }
  float hsq = red[0];
  __syncthreads();
  float r = ffb[0];
  for (int k = 0; k < 256; ++k) r += bf2f(F2[(size_t)tid*256 + k])*wsm[k];
  red[tid] = r*r; __syncthreads();
  for (int off = 128; off > 0; off >>= 1) { if (tid < off) red[tid] += red[tid + off]; __syncthreads(); }
  out[tid] = r;
  if (tid == 0) out[256] = hsq/65536.0f + red[0]/256.0f;
}

extern "C" void kernel_launch(void* const* d_in, const int* in_sizes, int n_in,
                              void* d_out, int out_size, void* d_ws, size_t ws_size,
                              hipStream_t stream)
{
  const float* batch   = (const float*)d_in[0];
  const float* conv_w1 = (const float*)d_in[1];
  const float* conv_b1 = (const float*)d_in[2];
  const float* conv_w2 = (const float*)d_in[3];
  const float* conv_b2 = (const float*)d_in[4];
  const float* conv_w3 = (const float*)d_in[5];
  const float* conv_b3 = (const float*)d_in[6];
  const float* conv_w4 = (const float*)d_in[7];
  const float* conv_b4 = (const float*)d_in[8];
  const float* post_w  = (const float*)d_in[9];
  const float* post_b  = (const float*)d_in[10];
  const float* g_w1    = (const float*)d_in[11];
  const float* g_b1    = (const float*)d_in[12];
  const float* g_w2    = (const float*)d_in[13];
  const float* g_b2    = (const float*)d_in[14];
  const float* g_w3    = (const float*)d_in[15];
  const float* g_b3    = (const float*)d_in[16];
  const float* g_w4    = (const float*)d_in[17];
  const float* g_b4    = (const float*)d_in[18];
  const float* h_w1    = (const float*)d_in[19];
  const float* h_b1    = (const float*)d_in[20];
  const float* h_w2    = (const float*)d_in[21];
  const float* h_b2    = (const float*)d_in[22];
  const float* h_w3    = (const float*)d_in[23];
  const float* h_b3    = (const float*)d_in[24];
  const float* f_w1    = (const float*)d_in[25];
  const float* f_b1    = (const float*)d_in[26];
  const float* f_w2    = (const float*)d_in[27];
  const float* f_b2    = (const float*)d_in[28];
  const float* ff_w    = (const float*)d_in[29];
  const float* ff_b    = (const float*)d_in[30];

  char* wsb = (char*)d_ws;
  const size_t off_Y1    = 0;
  const size_t off_Y2    = 52000000;
  const size_t off_Y3    = 64000000;
  const size_t off_Y4    = 67000000;
  const size_t off_PANEL = 68000000;
  const size_t off_WT    = 132000000;
  const size_t off_Pb    = 0;
  const size_t off_Qb    = 22000000;
  const size_t off_UV    = 44000000;
  const size_t off_OBJb  = 54000000;
  const size_t off_SJ    = 56000000;
  const size_t off_SJb   = 59000000;
  const size_t off_HS    = 61000000;
  const size_t off_HSb   = 61500000;
  const size_t off_F1    = 62000000;
  const size_t off_F2    = 63000000;

  unsigned short* WT = (unsigned short*)(wsb + off_WT);
  const size_t wt_g1   = 0;
  const size_t wt_g2   = 262144;
  const size_t wt_g3   = 524288;
  const size_t wt_g4   = 786432;
  const size_t wt_h1   = 917504;
  const size_t wt_h2   = 1310720;
  const size_t wt_h3   = 1507328;
  const size_t wt_post = 1703936;
  const size_t wt_cw2  = 1835008;
  const size_t wt_cw3  = 1844224;
  const size_t wt_cw4  = 1853440;
  const size_t wt_cw1  = 1862656;
  const size_t wt_f1   = 1871872;
  const size_t wt_f2   = 1937408;

  dim3 b256(256);

  k_prep<<<dim3(7824), b256, 0, stream>>>(g_w1, g_w2, g_w3, g_w4, h_w1, h_w2, h_w3,
                                          post_w, conv_w2, conv_w3, conv_w4, conv_w1,
                                          f_w1, f_w2, WT);

  unsigned short* Y1 = (unsigned short*)(wsb + off_Y1);
  unsigned short* Y2 = (unsigned short*)(wsb + off_Y2);
  unsigned short* Y3 = (unsigned short*)(wsb + off_Y3);
  unsigned short* Y4 = (unsigned short*)(wsb + off_Y4);
  float* PANEL = (float*)(wsb + off_PANEL);

  k_conv1m<<<dim3(512,13), b256, 0, stream>>>(batch, WT + wt_cw1, conv_b1, Y1);
  k_cmfma<39,39,19,19,10><<<dim3(512,2), b256, 0, stream>>>(Y1, WT + wt_cw2, conv_b2, Y2);
  k_cmfma<19,19, 9, 9, 9><<<dim3(512,1), b256, 0, stream>>>(Y2, WT + wt_cw3, conv_b3, Y3);
  k_cmfma< 9, 9, 4, 4, 4><<<dim3(512,1), b256, 0, stream>>>(Y3, WT + wt_cw4, conv_b4, Y4);

  k_mgemm<0,0><<<dim3(4,2), b256, 0, stream>>>(Y4, WT + wt_post, nullptr, PANEL, 512,256,512);

  unsigned short* OBJb = (unsigned short*)(wsb + off_OBJb);
  unsigned short* Pb   = (unsigned short*)(wsb + off_Pb);
  unsigned short* Qb   = (unsigned short*)(wsb + off_Qb);
  unsigned short* SJb  = (unsigned short*)(wsb + off_SJb);
  unsigned short* UVb  = (unsigned short*)(wsb + off_UV);
  float* SJ = (float*)(wsb + off_SJ);
  float* HS = (float*)(wsb + off_HS);
  unsigned short* HSb = (unsigned short*)(wsb + off_HSb);
  unsigned short* F1 = (unsigned short*)(wsb + off_F1);
  unsigned short* F2 = (unsigned short*)(wsb + off_F2);

  k_objects<<<dim3(2304), b256, 0, stream>>>(PANEL, post_b, OBJb);

  // g-MLP: g1 -> fused(expand+g2) -> g3 -> g4 -> sumj
  k_mgemm<1,0><<<dim3(18,8), b256, 0, stream>>>(OBJb, WT + wt_g1, nullptr, UVb, 2304,1024,256);
  k_pgemm<<<dim3(162,4), b256, 0, stream>>>(UVb, WT + wt_g2, g_b1, g_b2, Qb, 20736,512,512);
  k_mgemm<1,1><<<dim3(162,4), b256, 0, stream>>>(Qb, WT + wt_g3, g_b3, Pb, 20736,512,512);
  k_mgemm<1,1><<<dim3(162,2), b256, 0, stream>>>(Pb, WT + wt_g4, g_b4, Qb, 20736,256,512);
  k_sumj<<<dim3(2304), b256, 0, stream>>>(Qb, SJ, SJb, 256);

  for (int i = 0; i < 3; ++i) {
    k_mgemm<1,0><<<dim3(18,4), b256, 0, stream>>>(SJb, WT + wt_h1 + (size_t)i*131072, nullptr, UVb, 2304,512,256);
    k_pgemm<<<dim3(162,2), b256, 0, stream>>>(UVb, WT + wt_h2 + (size_t)i*65536, h_b1 + i*256, h_b2 + i*256, Qb, 20736,256,256);
    k_mgemm<1,1><<<dim3(162,2), b256, 0, stream>>>(Qb, WT + wt_h3 + (size_t)i*65536, h_b3 + i*256, Pb, 20736,256,256);
    k_sumj<<<dim3(2304), b256, 0, stream>>>(Pb, SJ, SJb, 256);
  }

  // head (MFMA)
  k_hsum<<<dim3(256), b256, 0, stream>>>(SJ, HS, HSb);
  k_mgemm<1,1><<<dim3(2,2), b256, 0, stream>>>(HSb, WT + wt_f1, f_b1, F1, 256,256,256);
  k_mgemm<1,1><<<dim3(2,2), b256, 0, stream>>>(F1,  WT + wt_f2, f_b2, F2, 256,256,256);
  k_tailfin<<<dim3(1), b256, 0, stream>>>(HS, F2, ff_w, ff_b, (float*)d_out);
}

// Round 8
// 355.569 us; speedup vs baseline: 11.3352x; 1.0224x over previous
//
#include <hip/hip_runtime.h>
#include <hip/hip_bf16.h>
#include <math.h>

static __device__ __forceinline__ float lrelu(float v){ return v > 0.0f ? v : 0.01f*v; }

static __device__ __forceinline__ unsigned short f2bf(float f){
  unsigned int u = __float_as_uint(f);
  unsigned int r = (u + 0x7fffu + ((u >> 16) & 1u)) >> 16;
  return (unsigned short)r;
}
static __device__ __forceinline__ float bf2f(unsigned short u){
  return __uint_as_float(((unsigned int)u) << 16);
}
static __device__ __forceinline__ unsigned int pack_bf2(float lo, float hi){
  __hip_bfloat162 bb = __float22bfloat162_rn(make_float2(lo, hi));
  return *reinterpret_cast<unsigned int*>(&bb);
}
// async global->LDS, 16B per lane; LDS dest = uniform base + lane*16
static __device__ __forceinline__ void gload16(const void* g, void* l){
  __builtin_amdgcn_global_load_lds(
    (const __attribute__((address_space(1))) void*)(const void*)g,
    (__attribute__((address_space(3))) void*)l, 16, 0, 0);
}

#define ENC_NORM 1.4247939f
#define GC_C     6.3775511f
#define GC_2CD   1.3426423f
#define GC_CD2   0.070665395f
#define GC_S1    0.86820227f

typedef __attribute__((ext_vector_type(4))) float f32x4;
typedef __attribute__((ext_vector_type(8))) short bf16x8;

// ================= unified weight prep =================
__global__ __launch_bounds__(256) void k_prep(
    const float* __restrict__ g_w1, const float* __restrict__ g_w2,
    const float* __restrict__ g_w3, const float* __restrict__ g_w4,
    const float* __restrict__ h_w1, const float* __restrict__ h_w2,
    const float* __restrict__ h_w3, const float* __restrict__ post_w,
    const float* __restrict__ conv_w2, const float* __restrict__ conv_w3,
    const float* __restrict__ conv_w4, const float* __restrict__ conv_w1,
    const float* __restrict__ f_w1, const float* __restrict__ f_w2,
    unsigned short* __restrict__ WT)
{
  int e = blockIdx.x*256 + threadIdx.x;
  float v;
  if (e < 262144) {
    int nn = e >> 8, kk = e & 255;
    v = (nn < 512) ? g_w1[kk*512 + nn] : g_w1[(256+kk)*512 + (nn-512)];
  } else if (e < 524288) {
    int r = e - 262144; int nn = r >> 9, kk = r & 511;
    v = g_w2[kk*512 + nn];
  } else if (e < 786432) {
    int r = e - 524288; int nn = r >> 9, kk = r & 511;
    v = g_w3[kk*512 + nn];
  } else if (e < 917504) {
    int r = e - 786432; int nn = r >> 9, kk = r & 511;
    v = g_w4[kk*256 + nn];
  } else if (e < 1310720) {
    int r = e - 917504; int i = r >> 17; int q = r & 131071;
    int nn = q >> 8, kk = q & 255;
    v = (nn < 256) ? h_w1[i*131072 + kk*256 + nn]
                   : h_w1[i*131072 + (256+kk)*256 + (nn-256)];
  } else if (e < 1507328) {
    int r = e - 1310720; int i = r >> 16; int q = r & 65535;
    int nn = q >> 8, kk = q & 255;
    v = h_w2[i*65536 + kk*256 + nn];
  } else if (e < 1703936) {
    int r = e - 1507328; int i = r >> 16; int q = r & 65535;
    int nn = q >> 8, kk = q & 255;
    v = h_w3[i*65536 + kk*256 + nn];
  } else if (e < 1835008) {
    int r = e - 1703936; int np = r >> 9, kp = r & 511;
    int px = kp >> 5, c = kp & 31;
    v = (np < 247) ? post_w[(c*16+px)*247 + np] : 0.f;
  } else if (e < 1862656) {
    int r = e - 1835008; int which = r / 9216; int q = r % 9216;
    int tap = q >> 10, o = (q >> 5) & 31, c = q & 31;
    const float* w = which==0 ? conv_w2 : (which==1 ? conv_w3 : conv_w4);
    v = w[(o*32+c)*9 + tap];
  } else if (e < 1871872) {
    int r = e - 1862656; int tap = r >> 10, o = (r >> 5) & 31, c = r & 31;
    v = (c < 20) ? conv_w1[(o*20+c)*9 + tap] : 0.f;
  } else if (e < 1937408) {
    int r = e - 1871872; int nn = r >> 8, kk = r & 255;
    v = f_w1[kk*256 + nn];
  } else {
    int r = e - 1937408; int nn = r >> 8, kk = r & 255;
    v = f_w2[kk*256 + nn];
  }
  WT[e] = f2bf(v);
}

// ================= conv1: fused encoding + MFMA implicit GEMM (20->32, k3 s2) =================
// Threads iterate hidx-linearly: writes walk stride-80B consecutively (conflict-floor).
__global__ __launch_bounds__(256) void k_conv1m(
    const float* __restrict__ batch, const unsigned short* __restrict__ wc1,
    const float* __restrict__ bias, unsigned short* __restrict__ y)
{
  __shared__ unsigned short ench[7][80][40];   // 44.8 KB
  int n = blockIdx.x;
  int orow0 = blockIdx.y * 3;
  int irow0 = orow0 * 2;
  int tid = threadIdx.x;
  int lane = tid & 63, wid = tid >> 6;
  int lr = lane & 15, kg = lane >> 4;

  bf16x8 bf0[9], bf1[9];
  #pragma unroll
  for (int tap = 0; tap < 9; ++tap) {
    bf0[tap] = *(const bf16x8*)&wc1[tap*1024 + lr*32 + kg*8];
    bf1[tap] = *(const bf16x8*)&wc1[tap*1024 + (16+lr)*32 + kg*8];
  }

  const float* img = batch + (size_t)n*6400 + irow0*80;
  const float S2 = GC_S1 * GC_S1;
  for (int p = tid; p < 7*80; p += 256) {
    int row = p / 80, hx = p % 80;
    int col = (hx < 40) ? 2*hx : 2*(hx-40)+1;
    if (col > 78) continue;
    float x = img[row*80 + col];
    float E = __expf(x * (4.0f/255.0f) - 2.0f);
    float t = 1.0f - 2.0f*__builtin_amdgcn_rcpf(E + 1.0f);
    float z = t - 1.0f;
    float e = ENC_NORM * __expf(-GC_C*z*z);
    float rg = __expf(-GC_2CD*z - GC_CD2);
    unsigned int pk[16];
    #pragma unroll
    for (int cp = 0; cp < 10; ++cp) {
      float e1 = e * rg;
      pk[cp] = pack_bf2(e, e1);
      e  = e1 * rg * GC_S1;
      rg = rg * S2;
    }
    #pragma unroll
    for (int cp = 10; cp < 16; ++cp) pk[cp] = 0u;
    unsigned short* dst = &ench[row][hx][0];
    *(uint4*)(dst)      = *(uint4*)&pk[0];
    *(uint4*)(dst + 8)  = *(uint4*)&pk[4];
    *(uint4*)(dst + 16) = *(uint4*)&pk[8];
    *(uint4*)(dst + 24) = *(uint4*)&pk[12];
  }
  __syncthreads();

  const int totpx = 117;
  float b0 = bias[lr], b1 = bias[16 + lr];
  for (int t = wid; t < 8; t += 4) {
    int pa = t*16 + lr;
    int pc = (pa < totpx) ? pa : (totpx - 1);
    int oh = pc / 39, ow = pc % 39;
    f32x4 acc0 = {0.f,0.f,0.f,0.f}, acc1 = {0.f,0.f,0.f,0.f};
    #pragma unroll
    for (int kh = 0; kh < 3; ++kh) {
      int r = oh*2 + kh;
      #pragma unroll
      for (int kw = 0; kw < 3; ++kw) {
        int hidx = (kw == 1) ? (40 + ow) : (ow + (kw >> 1));
        bf16x8 a = *(const bf16x8*)&ench[r][hidx][kg*8];
        int tap = kh*3 + kw;
        acc0 = __builtin_amdgcn_mfma_f32_16x16x32_bf16(a, bf0[tap], acc0, 0, 0, 0);
        acc1 = __builtin_amdgcn_mfma_f32_16x16x32_bf16(a, bf1[tap], acc1, 0, 0, 0);
      }
    }
    #pragma unroll
    for (int rr = 0; rr < 4; ++rr) {
      int ps = t*16 + kg*4 + rr;
      if (ps < totpx) {
        int soh = orow0 + ps / 39, sow = ps % 39;
        unsigned short* op = y + (((size_t)n*39 + soh)*39 + sow)*32;
        op[lr]      = f2bf(lrelu(acc0[rr] + b0));
        op[16 + lr] = f2bf(lrelu(acc1[rr] + b1));
      }
    }
  }
}

// ---------------- conv2/3/4: bf16 MFMA implicit GEMM; LDS even/odd de-interleaved ----------------
template<int H, int W, int OH, int OW, int ROWS>
__global__ __launch_bounds__(256) void k_cmfma(
    const unsigned short* __restrict__ in, const unsigned short* __restrict__ wc,
    const float* __restrict__ bias, unsigned short* __restrict__ out)
{
  constexpr int IR = 2*ROWS + 1;
  constexpr int EV = (W + 1) / 2;
  __shared__ unsigned short xs[IR][W][40];
  int n = blockIdx.x;
  int orow0 = blockIdx.y * ROWS;
  int nrows = min(ROWS, OH - orow0);
  int irow0 = orow0 * 2;
  int ir = min(2*nrows + 1, H - irow0);
  int tid = threadIdx.x;
  int lane = tid & 63, wid = tid >> 6;
  int lr = lane & 15, kg = lane >> 4;

  bf16x8 bf0[9], bf1[9];
  #pragma unroll
  for (int tap = 0; tap < 9; ++tap) {
    bf0[tap] = *(const bf16x8*)&wc[(tap*32 + lr)*32      + kg*8];
    bf1[tap] = *(const bf16x8*)&wc[(tap*32 + 16 + lr)*32 + kg*8];
  }

  const unsigned short* ip = in + ((size_t)n*H + irow0)*W*32;
  int npx = ir * W;
  for (int p = tid; p < npx; p += 256) {
    const uint4* src = (const uint4*)(ip + (size_t)p*32);
    uint4 v0 = src[0], v1 = src[1], v2 = src[2], v3 = src[3];
    int r = p / W, col = p % W;
    int hx = (col & 1) ? EV + (col >> 1) : (col >> 1);
    unsigned short* dst = &xs[r][hx][0];
    *(uint4*)(dst)      = v0;
    *(uint4*)(dst + 8)  = v1;
    *(uint4*)(dst + 16) = v2;
    *(uint4*)(dst + 24) = v3;
  }
  __syncthreads();

  int totpx = nrows * OW;
  int ntiles = (totpx + 15) >> 4;
  float b0 = bias[lr], b1 = bias[16 + lr];
  for (int t = wid; t < ntiles; t += 4) {
    int pa = t*16 + lr;
    int pc = (pa < totpx) ? pa : 0;
    int oh = pc / OW, ow = pc % OW;
    f32x4 acc0 = {0.f,0.f,0.f,0.f}, acc1 = {0.f,0.f,0.f,0.f};
    #pragma unroll
    for (int kh = 0; kh < 3; ++kh)
      #pragma unroll
      for (int kw = 0; kw < 3; ++kw) {
        int hidx = (kw == 1) ? (EV + ow) : (ow + (kw >> 1));
        bf16x8 a = *(const bf16x8*)&xs[oh*2 + kh][hidx][kg*8];
        acc0 = __builtin_amdgcn_mfma_f32_16x16x32_bf16(a, bf0[kh*3+kw], acc0, 0, 0, 0);
        acc1 = __builtin_amdgcn_mfma_f32_16x16x32_bf16(a, bf1[kh*3+kw], acc1, 0, 0, 0);
      }
    #pragma unroll
    for (int rr = 0; rr < 4; ++rr) {
      int ps = t*16 + kg*4 + rr;
      if (ps < totpx) {
        int soh = orow0 + ps / OW, sow = ps % OW;
        unsigned short* op = out + (((size_t)n*OH + soh)*OW + sow)*32;
        op[lr]      = f2bf(lrelu(acc0[rr] + b0));
        op[16 + lr] = f2bf(lrelu(acc1[rr] + b1));
      }
    }
  }
}

// ---------------- bf16 MFMA GEMM via global_load_lds + XOR-swizzled LDS ----------------
// C = act(A(MxK,bf16) @ Wt(NxK,bf16)^T + bias). M,N mult of 128, K mult of 64.
template<int OUT_BF16, int ACT>
__global__ __launch_bounds__(256) void k_mgemm(
    const unsigned short* __restrict__ A, const unsigned short* __restrict__ Wt,
    const float* __restrict__ bias, void* __restrict__ Cv,
    int M, int N, int K)
{
  __shared__ unsigned short As[128*64];
  __shared__ unsigned short Bs[128*64];
  int bm = blockIdx.x * 128;
  int bn = blockIdx.y * 128;
  int tid = threadIdx.x;
  int wid = tid >> 6, lane = tid & 63;
  int wr = (wid >> 1) * 64, wc = (wid & 1) * 64;
  int lr = lane & 15, kg = lane >> 4;

  int srow = lane >> 3;                       // row within 8-row chunk
  int ssw  = ((lane & 7) * 16) ^ (srow << 4); // swizzled source byte-in-row
  int rsw  = (lr & 7) << 4;                   // read-side XOR (bytes)

  f32x4 acc[4][4];
  #pragma unroll
  for (int i = 0; i < 4; ++i)
    #pragma unroll
    for (int j = 0; j < 4; ++j)
      acc[i][j] = (f32x4){0.f,0.f,0.f,0.f};

  for (int k0 = 0; k0 < K; k0 += 64) {
    #pragma unroll
    for (int i = 0; i < 4; ++i) {
      int rowc = wid*32 + i*8;
      int row  = rowc + srow;
      gload16((const char*)&A[(size_t)(bm + row)*K + k0] + ssw, &As[rowc*64]);
      gload16((const char*)&Wt[(size_t)(bn + row)*K + k0] + ssw, &Bs[rowc*64]);
    }
    __syncthreads();
    #pragma unroll
    for (int ks = 0; ks < 2; ++ks) {
      int roff = ((ks*64 + kg*16) ^ rsw) >> 1;   // halfword offset in row
      bf16x8 a[4], b[4];
      #pragma unroll
      for (int i = 0; i < 4; ++i) {
        a[i] = *(const bf16x8*)&As[(wr + i*16 + lr)*64 + roff];
        b[i] = *(const bf16x8*)&Bs[(wc + i*16 + lr)*64 + roff];
      }
      #pragma unroll
      for (int i = 0; i < 4; ++i)
        #pragma unroll
        for (int j = 0; j < 4; ++j)
          acc[i][j] = __builtin_amdgcn_mfma_f32_16x16x32_bf16(a[i], b[j], acc[i][j], 0, 0, 0);
    }
    __syncthreads();
  }
  int r0 = (lane >> 4) * 4;
  #pragma unroll
  for (int i = 0; i < 4; ++i) {
    #pragma unroll
    for (int j = 0; j < 4; ++j) {
      int col = bn + wc + j*16 + lr;
      float bv = bias ? bias[col] : 0.f;
      #pragma unroll
      for (int rr = 0; rr < 4; ++rr) {
        int row = bm + wr + i*16 + r0 + rr;
        float v = acc[i][j][rr] + bv;
        if (ACT) v = lrelu(v);
        if (OUT_BF16) ((unsigned short*)Cv)[(size_t)row*N + col] = f2bf(v);
        else          ((float*)Cv)[(size_t)row*N + col] = v;
      }
    }
  }
}

// ---------------- pair GEMM: fused expand + GEMM (A computed, swizzled ds_write; B gload) ----------------
__global__ __launch_bounds__(256) void k_pgemm(
    const unsigned short* __restrict__ UV, const unsigned short* __restrict__ Wt,
    const float* __restrict__ abias, const float* __restrict__ obias,
    unsigned short* __restrict__ C, int M, int N, int K)
{
  __shared__ unsigned short As[128*64];
  __shared__ unsigned short Bs[128*64];
  __shared__ float absm[512];
  int bm = blockIdx.x * 128;
  int bn = blockIdx.y * 128;
  int tid = threadIdx.x;
  int wid = tid >> 6, lane = tid & 63;
  int wr = (wid >> 1) * 64, wc = (wid & 1) * 64;
  int lr = lane & 15, kg = lane >> 4;
  int ld = 2*K;

  int srow = lane >> 3;
  int ssw  = ((lane & 7) * 16) ^ (srow << 4);
  int rsw  = (lr & 7) << 4;

  for (int idx = tid; idx < K; idx += 256) absm[idx] = abias[idx];

  // per-thread A rows (thread ch handles row r = ch>>3, chunk c = ch&7)
  int urow[4], vrow[4], arow[4], asw[4];
  #pragma unroll
  for (int i = 0; i < 4; ++i) {
    int ch = tid + (i << 8);
    int r = ch >> 3;
    int m = bm + r;
    int n = m / 81; int rem = m - n*81;
    int ii = rem / 9; int jj = rem - ii*9;
    urow[i] = n*9 + ii; vrow[i] = n*9 + jj;
    arow[i] = r;
    asw[i] = (((ch & 7) * 16) ^ ((r & 7) << 4)) >> 1;  // halfword offset in row
  }
  __syncthreads();

  f32x4 acc[4][4];
  #pragma unroll
  for (int i = 0; i < 4; ++i)
    #pragma unroll
    for (int j = 0; j < 4; ++j)
      acc[i][j] = (f32x4){0.f,0.f,0.f,0.f};

  for (int k0 = 0; k0 < K; k0 += 64) {
    #pragma unroll
    for (int i = 0; i < 4; ++i) {
      int rowc = wid*32 + i*8;
      int row  = rowc + srow;
      gload16((const char*)&Wt[(size_t)(bn + row)*K + k0] + ssw, &Bs[rowc*64]);
    }
    #pragma unroll
    for (int i = 0; i < 4; ++i) {
      int ch = tid + (i << 8);
      int kc = (ch & 7) * 8;
      uint4 u4 = *(const uint4*)&UV[(size_t)urow[i]*ld + k0 + kc];
      uint4 v4 = *(const uint4*)&UV[(size_t)vrow[i]*ld + K + k0 + kc];
      const unsigned short* us = (const unsigned short*)&u4;
      const unsigned short* vs = (const unsigned short*)&v4;
      unsigned int pk[4];
      #pragma unroll
      for (int e2 = 0; e2 < 4; ++e2) {
        float a0 = bf2f(us[2*e2])   + bf2f(vs[2*e2])   + absm[k0 + kc + 2*e2];
        float a1 = bf2f(us[2*e2+1]) + bf2f(vs[2*e2+1]) + absm[k0 + kc + 2*e2+1];
        pk[e2] = pack_bf2(lrelu(a0), lrelu(a1));
      }
      *(uint4*)&As[arow[i]*64 + asw[i]] = *(uint4*)pk;
    }
    __syncthreads();
    #pragma unroll
    for (int ks = 0; ks < 2; ++ks) {
      int roff = ((ks*64 + kg*16) ^ rsw) >> 1;
      bf16x8 a[4], b[4];
      #pragma unroll
      for (int i = 0; i < 4; ++i) {
        a[i] = *(const bf16x8*)&As[(wr + i*16 + lr)*64 + roff];
        b[i] = *(const bf16x8*)&Bs[(wc + i*16 + lr)*64 + roff];
      }
      #pragma unroll
      for (int i = 0; i < 4; ++i)
        #pragma unroll
        for (int j = 0; j < 4; ++j)
          acc[i][j] = __builtin_amdgcn_mfma_f32_16x16x32_bf16(a[i], b[j], acc[i][j], 0, 0, 0);
    }
    __syncthreads();
  }
  int r0 = (lane >> 4) * 4;
  #pragma unroll
  for (int i = 0; i < 4; ++i) {
    #pragma unroll
    for (int j = 0; j < 4; ++j) {
      int col = bn + wc + j*16 + lr;
      float bv = obias[col];
      #pragma unroll
      for (int rr = 0; rr < 4; ++rr) {
        int row = bm + wr + i*16 + r0 + rr;
        C[(size_t)row*N + col] = f2bf(lrelu(acc[i][j][rr] + bv));
      }
    }
  }
}

// ---------------- build objects (2304 x 256) bf16 ----------------
__global__ void k_objects(const float* __restrict__ panel, const float* __restrict__ post_b,
                          unsigned short* __restrict__ obj)
{
  int idx = blockIdx.x*256 + threadIdx.x;
  int row = idx >> 8;
  int k = idx & 255;
  int slot = row % 9;
  int nn = row / 9;
  int b = nn >> 3, opt = nn & 7;
  float v;
  if (k < 247) {
    int src = (slot < 8) ? (b*16 + slot) : (b*16 + 8 + opt);
    v = panel[(size_t)src*256 + k] + post_b[k];
  } else {
    v = ((k - 247) == slot) ? 1.0f : 0.0f;
  }
  obj[idx] = f2bf(v);
}

// ---------------- sum over j ----------------
__global__ void k_sumj(const unsigned short* __restrict__ Z, float* __restrict__ SJ,
                       unsigned short* __restrict__ SJb, int C)
{
  int idx = blockIdx.x*256 + threadIdx.x;
  int orow = idx / C, k = idx % C;
  int n = orow / 9, i = orow % 9;
  const unsigned short* base = Z + (size_t)(n*81 + i*9)*C + k;
  float s = 0.f;
  #pragma unroll
  for (int j = 0; j < 9; ++j) s += bf2f(base[(size_t)j*C]);
  SJ[idx] = s;
  SJb[idx] = f2bf(s);
}

// ---------------- sum over i ----------------
__global__ void k_hsum(const float* __restrict__ SJ, float* __restrict__ HS,
                       unsigned short* __restrict__ HSb)
{
  int idx = blockIdx.x*256 + threadIdx.x;
  int n = idx >> 8, k = idx & 255;
  const float* base = SJ + (size_t)n*9*256 + k;
  float s = 0.f;
  #pragma unroll
  for (int i = 0; i < 9; ++i) s += base[i*256];
  HS[idx] = s;
  HSb[idx] = f2bf(s);
}

// ---------------- fused tail ----------------
__global__ __launch_bounds__(256) void k_tailfin(
    const float* __restrict__ HS, const unsigned short* __restrict__ F2,
    const float* __restrict__ ffw, const float* __restrict__ ffb,
    float* __restrict__ out)
{
  __shared__ float red[256];
  __shared__ float wsm[256];
  int tid = threadIdx.x;
  wsm[tid] = ffw[tid];
  float s = 0.f;
  for (int j = 0; j < 256; ++j) { float v = HS[j*256 + tid]; s += v*v; }
  red[tid] = s; __syncthreads();
  for (int off = 128; off > 0; off >>= 1) { if (tid < off) red[tid] += red[tid + off]; __syncthreads(); }
  float hsq = red[0];
  __syncthreads();
  float r = ffb[0];
  for (int k = 0; k < 256; ++k) r += bf2f(F2[(size_t)tid*256 + k])*wsm[k];
  red[tid] = r*r; __syncthreads();
  for (int off = 128; off > 0; off >>= 1) { if (tid < off) red[tid] += red[tid + off]; __syncthreads(); }
  out[tid] = r;
  if (tid == 0) out[256] = hsq/65536.0f + red[0]/256.0f;
}

extern "C" void kernel_launch(void* const* d_in, const int* in_sizes, int n_in,
                              void* d_out, int out_size, void* d_ws, size_t ws_size,
                              hipStream_t stream)
{
  const float* batch   = (const float*)d_in[0];
  const float* conv_w1 = (const float*)d_in[1];
  const float* conv_b1 = (const float*)d_in[2];
  const float* conv_w2 = (const float*)d_in[3];
  const float* conv_b2 = (const float*)d_in[4];
  const float* conv_w3 = (const float*)d_in[5];
  const float* conv_b3 = (const float*)d_in[6];
  const float* conv_w4 = (const float*)d_in[7];
  const float* conv_b4 = (const float*)d_in[8];
  const float* post_w  = (const float*)d_in[9];
  const float* post_b  = (const float*)d_in[10];
  const float* g_w1    = (const float*)d_in[11];
  const float* g_b1    = (const float*)d_in[12];
  const float* g_w2    = (const float*)d_in[13];
  const float* g_b2    = (const float*)d_in[14];
  const float* g_w3    = (const float*)d_in[15];
  const float* g_b3    = (const float*)d_in[16];
  const float* g_w4    = (const float*)d_in[17];
  const float* g_b4    = (const float*)d_in[18];
  const float* h_w1    = (const float*)d_in[19];
  const float* h_b1    = (const float*)d_in[20];
  const float* h_w2    = (const float*)d_in[21];
  const float* h_b2    = (const float*)d_in[22];
  const float* h_w3    = (const float*)d_in[23];
  const float* h_b3    = (const float*)d_in[24];
  const float* f_w1    = (const float*)d_in[25];
  const float* f_b1    = (const float*)d_in[26];
  const float* f_w2    = (const float*)d_in[27];
  const float* f_b2    = (const float*)d_in[28];
  const float* ff_w    = (const float*)d_in[29];
  const float* ff_b    = (const float*)d_in[30];

  char* wsb = (char*)d_ws;
  const size_t off_Y1    = 0;
  const size_t off_Y2    = 52000000;
  const size_t off_Y3    = 64000000;
  const size_t off_Y4    = 67000000;
  const size_t off_PANEL = 68000000;
  const size_t off_WT    = 132000000;
  const size_t off_Pb    = 0;
  const size_t off_Qb    = 22000000;
  const size_t off_UV    = 44000000;
  const size_t off_OBJb  = 54000000;
  const size_t off_SJ    = 56000000;
  const size_t off_SJb   = 59000000;
  const size_t off_HS    = 61000000;
  const size_t off_HSb   = 61500000;
  const size_t off_F1    = 62000000;
  const size_t off_F2    = 63000000;

  unsigned short* WT = (unsigned short*)(wsb + off_WT);
  const size_t wt_g1   = 0;
  const size_t wt_g2   = 262144;
  const size_t wt_g3   = 524288;
  const size_t wt_g4   = 786432;
  const size_t wt_h1   = 917504;
  const size_t wt_h2   = 1310720;
  const size_t wt_h3   = 1507328;
  const size_t wt_post = 1703936;
  const size_t wt_cw2  = 1835008;
  const size_t wt_cw3  = 1844224;
  const size_t wt_cw4  = 1853440;
  const size_t wt_cw1  = 1862656;
  const size_t wt_f1   = 1871872;
  const size_t wt_f2   = 1937408;

  dim3 b256(256);

  k_prep<<<dim3(7824), b256, 0, stream>>>(g_w1, g_w2, g_w3, g_w4, h_w1, h_w2, h_w3,
                                          post_w, conv_w2, conv_w3, conv_w4, conv_w1,
                                          f_w1, f_w2, WT);

  unsigned short* Y1 = (unsigned short*)(wsb + off_Y1);
  unsigned short* Y2 = (unsigned short*)(wsb + off_Y2);
  unsigned short* Y3 = (unsigned short*)(wsb + off_Y3);
  unsigned short* Y4 = (unsigned short*)(wsb + off_Y4);
  float* PANEL = (float*)(wsb + off_PANEL);

  k_conv1m<<<dim3(512,13), b256, 0, stream>>>(batch, WT + wt_cw1, conv_b1, Y1);
  k_cmfma<39,39,19,19,10><<<dim3(512,2), b256, 0, stream>>>(Y1, WT + wt_cw2, conv_b2, Y2);
  k_cmfma<19,19, 9, 9, 9><<<dim3(512,1), b256, 0, stream>>>(Y2, WT + wt_cw3, conv_b3, Y3);
  k_cmfma< 9, 9, 4, 4, 4><<<dim3(512,1), b256, 0, stream>>>(Y3, WT + wt_cw4, conv_b4, Y4);

  k_mgemm<0,0><<<dim3(4,2), b256, 0, stream>>>(Y4, WT + wt_post, nullptr, PANEL, 512,256,512);

  unsigned short* OBJb = (unsigned short*)(wsb + off_OBJb);
  unsigned short* Pb   = (unsigned short*)(wsb + off_Pb);
  unsigned short* Qb   = (unsigned short*)(wsb + off_Qb);
  unsigned short* SJb  = (unsigned short*)(wsb + off_SJb);
  unsigned short* UVb  = (unsigned short*)(wsb + off_UV);
  float* SJ = (float*)(wsb + off_SJ);
  float* HS = (float*)(wsb + off_HS);
  unsigned short* HSb = (unsigned short*)(wsb + off_HSb);
  unsigned short* F1 = (unsigned short*)(wsb + off_F1);
  unsigned short* F2 = (unsigned short*)(wsb + off_F2);

  k_objects<<<dim3(2304), b256, 0, stream>>>(PANEL, post_b, OBJb);

  // g-MLP
  k_mgemm<1,0><<<dim3(18,8), b256, 0, stream>>>(OBJb, WT + wt_g1, nullptr, UVb, 2304,1024,256);
  k_pgemm<<<dim3(162,4), b256, 0, stream>>>(UVb, WT + wt_g2, g_b1, g_b2, Qb, 20736,512,512);
  k_mgemm<1,1><<<dim3(162,4), b256, 0, stream>>>(Qb, WT + wt_g3, g_b3, Pb, 20736,512,512);
  k_mgemm<1,1><<<dim3(162,2), b256, 0, stream>>>(Pb, WT + wt_g4, g_b4, Qb, 20736,256,512);
  k_sumj<<<dim3(2304), b256, 0, stream>>>(Qb, SJ, SJb, 256);

  for (int i = 0; i < 3; ++i) {
    k_mgemm<1,0><<<dim3(18,4), b256, 0, stream>>>(SJb, WT + wt_h1 + (size_t)i*131072, nullptr, UVb, 2304,512,256);
    k_pgemm<<<dim3(162,2), b256, 0, stream>>>(UVb, WT + wt_h2 + (size_t)i*65536, h_b1 + i*256, h_b2 + i*256, Qb, 20736,256,256);
    k_mgemm<1,1><<<dim3(162,2), b256, 0, stream>>>(Qb, WT + wt_h3 + (size_t)i*65536, h_b3 + i*256, Pb, 20736,256,256);
    k_sumj<<<dim3(2304), b256, 0, stream>>>(Pb, SJ, SJb, 256);
  }

  // head
  k_hsum<<<dim3(256), b256, 0, stream>>>(SJ, HS, HSb);
  k_mgemm<1,1><<<dim3(2,2), b256, 0, stream>>>(HSb, WT + wt_f1, f_b1, F1, 256,256,256);
  k_mgemm<1,1><<<dim3(2,2), b256, 0, stream>>>(F1,  WT + wt_f2, f_b2, F2, 256,256,256);
  k_tailfin<<<dim3(1), b256, 0, stream>>>(HS, F2, ff_w, ff_b, (float*)d_out);
}

// Round 9
// 350.035 us; speedup vs baseline: 11.5144x; 1.0158x over previous
//
#include <hip/hip_runtime.h>
#include <hip/hip_bf16.h>
#include <math.h>

static __device__ __forceinline__ float lrelu(float v){ return v > 0.0f ? v : 0.01f*v; }

static __device__ __forceinline__ unsigned short f2bf(float f){
  unsigned int u = __float_as_uint(f);
  unsigned int r = (u + 0x7fffu + ((u >> 16) & 1u)) >> 16;
  return (unsigned short)r;
}
static __device__ __forceinline__ float bf2f(unsigned short u){
  return __uint_as_float(((unsigned int)u) << 16);
}
static __device__ __forceinline__ unsigned int pack_bf2(float lo, float hi){
  __hip_bfloat162 bb = __float22bfloat162_rn(make_float2(lo, hi));
  return *reinterpret_cast<unsigned int*>(&bb);
}
static __device__ __forceinline__ void gload16(const void* g, void* l){
  __builtin_amdgcn_global_load_lds(
    (const __attribute__((address_space(1))) void*)(const void*)g,
    (__attribute__((address_space(3))) void*)l, 16, 0, 0);
}

#define ENC_NORM 1.4247939f
#define GC_C     6.3775511f
#define GC_2CD   1.3426423f
#define GC_CD2   0.070665395f
#define GC_S1    0.86820227f

typedef __attribute__((ext_vector_type(4))) float f32x4;
typedef __attribute__((ext_vector_type(8))) short bf16x8;

// ================= unified weight prep =================
__global__ __launch_bounds__(256) void k_prep(
    const float* __restrict__ g_w1, const float* __restrict__ g_w2,
    const float* __restrict__ g_w3, const float* __restrict__ g_w4,
    const float* __restrict__ h_w1, const float* __restrict__ h_w2,
    const float* __restrict__ h_w3, const float* __restrict__ post_w,
    const float* __restrict__ conv_w2, const float* __restrict__ conv_w3,
    const float* __restrict__ conv_w4, const float* __restrict__ conv_w1,
    const float* __restrict__ f_w1, const float* __restrict__ f_w2,
    unsigned short* __restrict__ WT)
{
  int e = blockIdx.x*256 + threadIdx.x;
  float v;
  if (e < 262144) {
    int nn = e >> 8, kk = e & 255;
    v = (nn < 512) ? g_w1[kk*512 + nn] : g_w1[(256+kk)*512 + (nn-512)];
  } else if (e < 524288) {
    int r = e - 262144; int nn = r >> 9, kk = r & 511;
    v = g_w2[kk*512 + nn];
  } else if (e < 786432) {
    int r = e - 524288; int nn = r >> 9, kk = r & 511;
    v = g_w3[kk*512 + nn];
  } else if (e < 917504) {
    int r = e - 786432; int nn = r >> 9, kk = r & 511;
    v = g_w4[kk*256 + nn];
  } else if (e < 1310720) {
    int r = e - 917504; int i = r >> 17; int q = r & 131071;
    int nn = q >> 8, kk = q & 255;
    v = (nn < 256) ? h_w1[i*131072 + kk*256 + nn]
                   : h_w1[i*131072 + (256+kk)*256 + (nn-256)];
  } else if (e < 1507328) {
    int r = e - 1310720; int i = r >> 16; int q = r & 65535;
    int nn = q >> 8, kk = q & 255;
    v = h_w2[i*65536 + kk*256 + nn];
  } else if (e < 1703936) {
    int r = e - 1507328; int i = r >> 16; int q = r & 65535;
    int nn = q >> 8, kk = q & 255;
    v = h_w3[i*65536 + kk*256 + nn];
  } else if (e < 1835008) {
    int r = e - 1703936; int np = r >> 9, kp = r & 511;
    int px = kp >> 5, c = kp & 31;
    v = (np < 247) ? post_w[(c*16+px)*247 + np] : 0.f;
  } else if (e < 1862656) {
    int r = e - 1835008; int which = r / 9216; int q = r % 9216;
    int tap = q >> 10, o = (q >> 5) & 31, c = q & 31;
    const float* w = which==0 ? conv_w2 : (which==1 ? conv_w3 : conv_w4);
    v = w[(o*32+c)*9 + tap];
  } else if (e < 1871872) {
    int r = e - 1862656; int tap = r >> 10, o = (r >> 5) & 31, c = r & 31;
    v = (c < 20) ? conv_w1[(o*20+c)*9 + tap] : 0.f;
  } else if (e < 1937408) {
    int r = e - 1871872; int nn = r >> 8, kk = r & 255;
    v = f_w1[kk*256 + nn];
  } else {
    int r = e - 1937408; int nn = r >> 8, kk = r & 255;
    v = f_w2[kk*256 + nn];
  }
  WT[e] = f2bf(v);
}

// ================= conv1: fused encoding + MFMA implicit GEMM, slab loop =================
// grid (512,2): block handles 7 (half 0) or 6 (half 1) slabs of 3 output rows.
// Weight-fragment prologue amortized over all slabs.
__global__ __launch_bounds__(256) void k_conv1m(
    const float* __restrict__ batch, const unsigned short* __restrict__ wc1,
    const float* __restrict__ bias, unsigned short* __restrict__ y)
{
  __shared__ unsigned short ench[7][80][40];   // 44.8 KB -> 3 blk/CU
  int n = blockIdx.x;
  int s0 = blockIdx.y ? 7 : 0;
  int s1 = blockIdx.y ? 13 : 7;
  int tid = threadIdx.x;
  int lane = tid & 63, wid = tid >> 6;
  int lr = lane & 15, kg = lane >> 4;

  bf16x8 bf0[9], bf1[9];
  #pragma unroll
  for (int tap = 0; tap < 9; ++tap) {
    bf0[tap] = *(const bf16x8*)&wc1[tap*1024 + lr*32 + kg*8];
    bf1[tap] = *(const bf16x8*)&wc1[tap*1024 + (16+lr)*32 + kg*8];
  }
  float b0 = bias[lr], b1 = bias[16 + lr];
  const float S2 = GC_S1 * GC_S1;

  for (int s = s0; s < s1; ++s) {
    int orow0 = s * 3;
    int irow0 = orow0 * 2;
    const float* img = batch + (size_t)n*6400 + irow0*80;
    for (int p = tid; p < 7*80; p += 256) {
      int row = p / 80, hx = p % 80;
      int col = (hx < 40) ? 2*hx : 2*(hx-40)+1;
      if (col > 78) continue;
      float x = img[row*80 + col];
      float E = __expf(x * (4.0f/255.0f) - 2.0f);
      float t = 1.0f - 2.0f*__builtin_amdgcn_rcpf(E + 1.0f);
      float z = t - 1.0f;
      float e = ENC_NORM * __expf(-GC_C*z*z);
      float rg = __expf(-GC_2CD*z - GC_CD2);
      unsigned int pk[16];
      #pragma unroll
      for (int cp = 0; cp < 10; ++cp) {
        float e1 = e * rg;
        pk[cp] = pack_bf2(e, e1);
        e  = e1 * rg * GC_S1;
        rg = rg * S2;
      }
      #pragma unroll
      for (int cp = 10; cp < 16; ++cp) pk[cp] = 0u;
      unsigned short* dst = &ench[row][hx][0];
      *(uint4*)(dst)      = *(uint4*)&pk[0];
      *(uint4*)(dst + 8)  = *(uint4*)&pk[4];
      *(uint4*)(dst + 16) = *(uint4*)&pk[8];
      *(uint4*)(dst + 24) = *(uint4*)&pk[12];
    }
    __syncthreads();

    const int totpx = 117;
    for (int t = wid; t < 8; t += 4) {
      int pa = t*16 + lr;
      int pc = (pa < totpx) ? pa : (totpx - 1);
      int oh = pc / 39, ow = pc % 39;
      f32x4 acc0 = {0.f,0.f,0.f,0.f}, acc1 = {0.f,0.f,0.f,0.f};
      #pragma unroll
      for (int kh = 0; kh < 3; ++kh) {
        int r = oh*2 + kh;
        #pragma unroll
        for (int kw = 0; kw < 3; ++kw) {
          int hidx = (kw == 1) ? (40 + ow) : (ow + (kw >> 1));
          bf16x8 a = *(const bf16x8*)&ench[r][hidx][kg*8];
          int tap = kh*3 + kw;
          acc0 = __builtin_amdgcn_mfma_f32_16x16x32_bf16(a, bf0[tap], acc0, 0, 0, 0);
          acc1 = __builtin_amdgcn_mfma_f32_16x16x32_bf16(a, bf1[tap], acc1, 0, 0, 0);
        }
      }
      #pragma unroll
      for (int rr = 0; rr < 4; ++rr) {
        int ps = t*16 + kg*4 + rr;
        if (ps < totpx) {
          int soh = orow0 + ps / 39, sow = ps % 39;
          unsigned short* op = y + (((size_t)n*39 + soh)*39 + sow)*32;
          op[lr]      = f2bf(lrelu(acc0[rr] + b0));
          op[16 + lr] = f2bf(lrelu(acc1[rr] + b1));
        }
      }
    }
    __syncthreads();
  }
}

// ---------------- conv2/3/4: bf16 MFMA implicit GEMM, slab loop ----------------
template<int H, int W, int OH, int OW, int ROWS, int SLABS>
__global__ __launch_bounds__(256) void k_cmfma(
    const unsigned short* __restrict__ in, const unsigned short* __restrict__ wc,
    const float* __restrict__ bias, unsigned short* __restrict__ out)
{
  constexpr int IR = 2*ROWS + 1;
  constexpr int EV = (W + 1) / 2;
  __shared__ unsigned short xs[IR][W][40];
  int n = blockIdx.x;
  int tid = threadIdx.x;
  int lane = tid & 63, wid = tid >> 6;
  int lr = lane & 15, kg = lane >> 4;

  bf16x8 bf0[9], bf1[9];
  #pragma unroll
  for (int tap = 0; tap < 9; ++tap) {
    bf0[tap] = *(const bf16x8*)&wc[(tap*32 + lr)*32      + kg*8];
    bf1[tap] = *(const bf16x8*)&wc[(tap*32 + 16 + lr)*32 + kg*8];
  }
  float b0 = bias[lr], b1 = bias[16 + lr];

  for (int s = 0; s < SLABS; ++s) {
    int orow0 = (blockIdx.y * SLABS + s) * ROWS;
    if (orow0 >= OH) break;
    int nrows = min(ROWS, OH - orow0);
    int irow0 = orow0 * 2;
    int ir = min(2*nrows + 1, H - irow0);

    const unsigned short* ip = in + ((size_t)n*H + irow0)*W*32;
    int npx = ir * W;
    for (int p = tid; p < npx; p += 256) {
      const uint4* src = (const uint4*)(ip + (size_t)p*32);
      uint4 v0 = src[0], v1 = src[1], v2 = src[2], v3 = src[3];
      int r = p / W, col = p % W;
      int hx = (col & 1) ? EV + (col >> 1) : (col >> 1);
      unsigned short* dst = &xs[r][hx][0];
      *(uint4*)(dst)      = v0;
      *(uint4*)(dst + 8)  = v1;
      *(uint4*)(dst + 16) = v2;
      *(uint4*)(dst + 24) = v3;
    }
    __syncthreads();

    int totpx = nrows * OW;
    int ntiles = (totpx + 15) >> 4;
    for (int t = wid; t < ntiles; t += 4) {
      int pa = t*16 + lr;
      int pc = (pa < totpx) ? pa : 0;
      int oh = pc / OW, ow = pc % OW;
      f32x4 acc0 = {0.f,0.f,0.f,0.f}, acc1 = {0.f,0.f,0.f,0.f};
      #pragma unroll
      for (int kh = 0; kh < 3; ++kh)
        #pragma unroll
        for (int kw = 0; kw < 3; ++kw) {
          int hidx = (kw == 1) ? (EV + ow) : (ow + (kw >> 1));
          bf16x8 a = *(const bf16x8*)&xs[oh*2 + kh][hidx][kg*8];
          acc0 = __builtin_amdgcn_mfma_f32_16x16x32_bf16(a, bf0[kh*3+kw], acc0, 0, 0, 0);
          acc1 = __builtin_amdgcn_mfma_f32_16x16x32_bf16(a, bf1[kh*3+kw], acc1, 0, 0, 0);
        }
      #pragma unroll
      for (int rr = 0; rr < 4; ++rr) {
        int ps = t*16 + kg*4 + rr;
        if (ps < totpx) {
          int soh = orow0 + ps / OW, sow = ps % OW;
          unsigned short* op = out + (((size_t)n*OH + soh)*OW + sow)*32;
          op[lr]      = f2bf(lrelu(acc0[rr] + b0));
          op[16 + lr] = f2bf(lrelu(acc1[rr] + b1));
        }
      }
    }
    __syncthreads();
  }
}

// ---------------- bf16 MFMA GEMM via global_load_lds + XOR-swizzled LDS ----------------
template<int OUT_BF16, int ACT>
__global__ __launch_bounds__(256) void k_mgemm(
    const unsigned short* __restrict__ A, const unsigned short* __restrict__ Wt,
    const float* __restrict__ bias, void* __restrict__ Cv,
    int M, int N, int K)
{
  __shared__ unsigned short As[128*64];
  __shared__ unsigned short Bs[128*64];
  int bm = blockIdx.x * 128;
  int bn = blockIdx.y * 128;
  int tid = threadIdx.x;
  int wid = tid >> 6, lane = tid & 63;
  int wr = (wid >> 1) * 64, wc = (wid & 1) * 64;
  int lr = lane & 15, kg = lane >> 4;

  int srow = lane >> 3;
  int ssw  = ((lane & 7) * 16) ^ (srow << 4);
  int rsw  = (lr & 7) << 4;

  f32x4 acc[4][4];
  #pragma unroll
  for (int i = 0; i < 4; ++i)
    #pragma unroll
    for (int j = 0; j < 4; ++j)
      acc[i][j] = (f32x4){0.f,0.f,0.f,0.f};

  for (int k0 = 0; k0 < K; k0 += 64) {
    #pragma unroll
    for (int i = 0; i < 4; ++i) {
      int rowc = wid*32 + i*8;
      int row  = rowc + srow;
      gload16((const char*)&A[(size_t)(bm + row)*K + k0] + ssw, &As[rowc*64]);
      gload16((const char*)&Wt[(size_t)(bn + row)*K + k0] + ssw, &Bs[rowc*64]);
    }
    __syncthreads();
    #pragma unroll
    for (int ks = 0; ks < 2; ++ks) {
      int roff = ((ks*64 + kg*16) ^ rsw) >> 1;
      bf16x8 a[4], b[4];
      #pragma unroll
      for (int i = 0; i < 4; ++i) {
        a[i] = *(const bf16x8*)&As[(wr + i*16 + lr)*64 + roff];
        b[i] = *(const bf16x8*)&Bs[(wc + i*16 + lr)*64 + roff];
      }
      #pragma unroll
      for (int i = 0; i < 4; ++i)
        #pragma unroll
        for (int j = 0; j < 4; ++j)
          acc[i][j] = __builtin_amdgcn_mfma_f32_16x16x32_bf16(a[i], b[j], acc[i][j], 0, 0, 0);
    }
    __syncthreads();
  }
  int r0 = (lane >> 4) * 4;
  #pragma unroll
  for (int i = 0; i < 4; ++i) {
    #pragma unroll
    for (int j = 0; j < 4; ++j) {
      int col = bn + wc + j*16 + lr;
      float bv = bias ? bias[col] : 0.f;
      #pragma unroll
      for (int rr = 0; rr < 4; ++rr) {
        int row = bm + wr + i*16 + r0 + rr;
        float v = acc[i][j][rr] + bv;
        if (ACT) v = lrelu(v);
        if (OUT_BF16) ((unsigned short*)Cv)[(size_t)row*N + col] = f2bf(v);
        else          ((float*)Cv)[(size_t)row*N + col] = v;
      }
    }
  }
}

// ---------------- pair GEMM: fused expand + GEMM ----------------
__global__ __launch_bounds__(256) void k_pgemm(
    const unsigned short* __restrict__ UV, const unsigned short* __restrict__ Wt,
    const float* __restrict__ abias, const float* __restrict__ obias,
    unsigned short* __restrict__ C, int M, int N, int K)
{
  __shared__ unsigned short As[128*64];
  __shared__ unsigned short Bs[128*64];
  __shared__ float absm[512];
  int bm = blockIdx.x * 128;
  int bn = blockIdx.y * 128;
  int tid = threadIdx.x;
  int wid = tid >> 6, lane = tid & 63;
  int wr = (wid >> 1) * 64, wc = (wid & 1) * 64;
  int lr = lane & 15, kg = lane >> 4;
  int ld = 2*K;

  int srow = lane >> 3;
  int ssw  = ((lane & 7) * 16) ^ (srow << 4);
  int rsw  = (lr & 7) << 4;

  for (int idx = tid; idx < K; idx += 256) absm[idx] = abias[idx];

  int urow[4], vrow[4], arow[4], asw[4];
  #pragma unroll
  for (int i = 0; i < 4; ++i) {
    int ch = tid + (i << 8);
    int r = ch >> 3;
    int m = bm + r;
    int n = m / 81; int rem = m - n*81;
    int ii = rem / 9; int jj = rem - ii*9;
    urow[i] = n*9 + ii; vrow[i] = n*9 + jj;
    arow[i] = r;
    asw[i] = (((ch & 7) * 16) ^ ((r & 7) << 4)) >> 1;
  }
  __syncthreads();

  f32x4 acc[4][4];
  #pragma unroll
  for (int i = 0; i < 4; ++i)
    #pragma unroll
    for (int j = 0; j < 4; ++j)
      acc[i][j] = (f32x4){0.f,0.f,0.f,0.f};

  for (int k0 = 0; k0 < K; k0 += 64) {
    #pragma unroll
    for (int i = 0; i < 4; ++i) {
      int rowc = wid*32 + i*8;
      int row  = rowc + srow;
      gload16((const char*)&Wt[(size_t)(bn + row)*K + k0] + ssw, &Bs[rowc*64]);
    }
    #pragma unroll
    for (int i = 0; i < 4; ++i) {
      int ch = tid + (i << 8);
      int kc = (ch & 7) * 8;
      uint4 u4 = *(const uint4*)&UV[(size_t)urow[i]*ld + k0 + kc];
      uint4 v4 = *(const uint4*)&UV[(size_t)vrow[i]*ld + K + k0 + kc];
      const unsigned short* us = (const unsigned short*)&u4;
      const unsigned short* vs = (const unsigned short*)&v4;
      unsigned int pk[4];
      #pragma unroll
      for (int e2 = 0; e2 < 4; ++e2) {
        float a0 = bf2f(us[2*e2])   + bf2f(vs[2*e2])   + absm[k0 + kc + 2*e2];
        float a1 = bf2f(us[2*e2+1]) + bf2f(vs[2*e2+1]) + absm[k0 + kc + 2*e2+1];
        pk[e2] = pack_bf2(lrelu(a0), lrelu(a1));
      }
      *(uint4*)&As[arow[i]*64 + asw[i]] = *(uint4*)pk;
    }
    __syncthreads();
    #pragma unroll
    for (int ks = 0; ks < 2; ++ks) {
      int roff = ((ks*64 + kg*16) ^ rsw) >> 1;
      bf16x8 a[4], b[4];
      #pragma unroll
      for (int i = 0; i < 4; ++i) {
        a[i] = *(const bf16x8*)&As[(wr + i*16 + lr)*64 + roff];
        b[i] = *(const bf16x8*)&Bs[(wc + i*16 + lr)*64 + roff];
      }
      #pragma unroll
      for (int i = 0; i < 4; ++i)
        #pragma unroll
        for (int j = 0; j < 4; ++j)
          acc[i][j] = __builtin_amdgcn_mfma_f32_16x16x32_bf16(a[i], b[j], acc[i][j], 0, 0, 0);
    }
    __syncthreads();
  }
  int r0 = (lane >> 4) * 4;
  #pragma unroll
  for (int i = 0; i < 4; ++i) {
    #pragma unroll
    for (int j = 0; j < 4; ++j) {
      int col = bn + wc + j*16 + lr;
      float bv = obias[col];
      #pragma unroll
      for (int rr = 0; rr < 4; ++rr) {
        int row = bm + wr + i*16 + r0 + rr;
        C[(size_t)row*N + col] = f2bf(lrelu(acc[i][j][rr] + bv));
      }
    }
  }
}

// ---------------- build objects (2304 x 256) bf16 ----------------
__global__ void k_objects(const float* __restrict__ panel, const float* __restrict__ post_b,
                          unsigned short* __restrict__ obj)
{
  int idx = blockIdx.x*256 + threadIdx.x;
  int row = idx >> 8;
  int k = idx & 255;
  int slot = row % 9;
  int nn = row / 9;
  int b = nn >> 3, opt = nn & 7;
  float v;
  if (k < 247) {
    int src = (slot < 8) ? (b*16 + slot) : (b*16 + 8 + opt);
    v = panel[(size_t)src*256 + k] + post_b[k];
  } else {
    v = ((k - 247) == slot) ? 1.0f : 0.0f;
  }
  obj[idx] = f2bf(v);
}

// ---------------- sum over j ----------------
__global__ void k_sumj(const unsigned short* __restrict__ Z, float* __restrict__ SJ,
                       unsigned short* __restrict__ SJb, int C)
{
  int idx = blockIdx.x*256 + threadIdx.x;
  int orow = idx / C, k = idx % C;
  int n = orow / 9, i = orow % 9;
  const unsigned short* base = Z + (size_t)(n*81 + i*9)*C + k;
  float s = 0.f;
  #pragma unroll
  for (int j = 0; j < 9; ++j) s += bf2f(base[(size_t)j*C]);
  SJ[idx] = s;
  SJb[idx] = f2bf(s);
}

// ---------------- sum over i ----------------
__global__ void k_hsum(const float* __restrict__ SJ, float* __restrict__ HS,
                       unsigned short* __restrict__ HSb)
{
  int idx = blockIdx.x*256 + threadIdx.x;
  int n = idx >> 8, k = idx & 255;
  const float* base = SJ + (size_t)n*9*256 + k;
  float s = 0.f;
  #pragma unroll
  for (int i = 0; i < 9; ++i) s += base[i*256];
  HS[idx] = s;
  HSb[idx] = f2bf(s);
}

// ---------------- fused tail ----------------
__global__ __launch_bounds__(256) void k_tailfin(
    const float* __restrict__ HS, const unsigned short* __restrict__ F2,
    const float* __restrict__ ffw, const float* __restrict__ ffb,
    float* __restrict__ out)
{
  __shared__ float red[256];
  __shared__ float wsm[256];
  int tid = threadIdx.x;
  wsm[tid] = ffw[tid];
  float s = 0.f;
  for (int j = 0; j < 256; ++j) { float v = HS[j*256 + tid]; s += v*v; }
  red[tid] = s; __syncthreads();
  for (int off = 128; off > 0; off >>= 1) { if (tid < off) red[tid] += red[tid + off]; __syncthreads(); }
  float hsq = red[0];
  __syncthreads();
  float r = ffb[0];
  for (int k = 0; k < 256; ++k) r += bf2f(F2[(size_t)tid*256 + k])*wsm[k];
  red[tid] = r*r; __syncthreads();
  for (int off = 128; off > 0; off >>= 1) { if (tid < off) red[tid] += red[tid + off]; __syncthreads(); }
  out[tid] = r;
  if (tid == 0) out[256] = hsq/65536.0f + red[0]/256.0f;
}

extern "C" void kernel_launch(void* const* d_in, const int* in_sizes, int n_in,
                              void* d_out, int out_size, void* d_ws, size_t ws_size,
                              hipStream_t stream)
{
  const float* batch   = (const float*)d_in[0];
  const float* conv_w1 = (const float*)d_in[1];
  const float* conv_b1 = (const float*)d_in[2];
  const float* conv_w2 = (const float*)d_in[3];
  const float* conv_b2 = (const float*)d_in[4];
  const float* conv_w3 = (const float*)d_in[5];
  const float* conv_b3 = (const float*)d_in[6];
  const float* conv_w4 = (const float*)d_in[7];
  const float* conv_b4 = (const float*)d_in[8];
  const float* post_w  = (const float*)d_in[9];
  const float* post_b  = (const float*)d_in[10];
  const float* g_w1    = (const float*)d_in[11];
  const float* g_b1    = (const float*)d_in[12];
  const float* g_w2    = (const float*)d_in[13];
  const float* g_b2    = (const float*)d_in[14];
  const float* g_w3    = (const float*)d_in[15];
  const float* g_b3    = (const float*)d_in[16];
  const float* g_w4    = (const float*)d_in[17];
  const float* g_b4    = (const float*)d_in[18];
  const float* h_w1    = (const float*)d_in[19];
  const float* h_b1    = (const float*)d_in[20];
  const float* h_w2    = (const float*)d_in[21];
  const float* h_b2    = (const float*)d_in[22];
  const float* h_w3    = (const float*)d_in[23];
  const float* h_b3    = (const float*)d_in[24];
  const float* f_w1    = (const float*)d_in[25];
  const float* f_b1    = (const float*)d_in[26];
  const float* f_w2    = (const float*)d_in[27];
  const float* f_b2    = (const float*)d_in[28];
  const float* ff_w    = (const float*)d_in[29];
  const float* ff_b    = (const float*)d_in[30];

  char* wsb = (char*)d_ws;
  const size_t off_Y1    = 0;
  const size_t off_Y2    = 52000000;
  const size_t off_Y3    = 64000000;
  const size_t off_Y4    = 67000000;
  const size_t off_PANEL = 68000000;
  const size_t off_WT    = 132000000;
  const size_t off_Pb    = 0;
  const size_t off_Qb    = 22000000;
  const size_t off_UV    = 44000000;
  const size_t off_OBJb  = 54000000;
  const size_t off_SJ    = 56000000;
  const size_t off_SJb   = 59000000;
  const size_t off_HS    = 61000000;
  const size_t off_HSb   = 61500000;
  const size_t off_F1    = 62000000;
  const size_t off_F2    = 63000000;

  unsigned short* WT = (unsigned short*)(wsb + off_WT);
  const size_t wt_g1   = 0;
  const size_t wt_g2   = 262144;
  const size_t wt_g3   = 524288;
  const size_t wt_g4   = 786432;
  const size_t wt_h1   = 917504;
  const size_t wt_h2   = 1310720;
  const size_t wt_h3   = 1507328;
  const size_t wt_post = 1703936;
  const size_t wt_cw2  = 1835008;
  const size_t wt_cw3  = 1844224;
  const size_t wt_cw4  = 1853440;
  const size_t wt_cw1  = 1862656;
  const size_t wt_f1   = 1871872;
  const size_t wt_f2   = 1937408;

  dim3 b256(256);

  k_prep<<<dim3(7824), b256, 0, stream>>>(g_w1, g_w2, g_w3, g_w4, h_w1, h_w2, h_w3,
                                          post_w, conv_w2, conv_w3, conv_w4, conv_w1,
                                          f_w1, f_w2, WT);

  unsigned short* Y1 = (unsigned short*)(wsb + off_Y1);
  unsigned short* Y2 = (unsigned short*)(wsb + off_Y2);
  unsigned short* Y3 = (unsigned short*)(wsb + off_Y3);
  unsigned short* Y4 = (unsigned short*)(wsb + off_Y4);
  float* PANEL = (float*)(wsb + off_PANEL);

  k_conv1m<<<dim3(512,2), b256, 0, stream>>>(batch, WT + wt_cw1, conv_b1, Y1);
  k_cmfma<39,39,19,19,10,2><<<dim3(512,1), b256, 0, stream>>>(Y1, WT + wt_cw2, conv_b2, Y2);
  k_cmfma<19,19, 9, 9, 9,1><<<dim3(512,1), b256, 0, stream>>>(Y2, WT + wt_cw3, conv_b3, Y3);
  k_cmfma< 9, 9, 4, 4, 4,1><<<dim3(512,1), b256, 0, stream>>>(Y3, WT + wt_cw4, conv_b4, Y4);

  k_mgemm<0,0><<<dim3(4,2), b256, 0, stream>>>(Y4, WT + wt_post, nullptr, PANEL, 512,256,512);

  unsigned short* OBJb = (unsigned short*)(wsb + off_OBJb);
  unsigned short* Pb   = (unsigned short*)(wsb + off_Pb);
  unsigned short* Qb   = (unsigned short*)(wsb + off_Qb);
  unsigned short* SJb  = (unsigned short*)(wsb + off_SJb);
  unsigned short* UVb  = (unsigned short*)(wsb + off_UV);
  float* SJ = (float*)(wsb + off_SJ);
  float* HS = (float*)(wsb + off_HS);
  unsigned short* HSb = (unsigned short*)(wsb + off_HSb);
  unsigned short* F1 = (unsigned short*)(wsb + off_F1);
  unsigned short* F2 = (unsigned short*)(wsb + off_F2);

  k_objects<<<dim3(2304), b256, 0, stream>>>(PANEL, post_b, OBJb);

  // g-MLP
  k_mgemm<1,0><<<dim3(18,8), b256, 0, stream>>>(OBJb, WT + wt_g1, nullptr, UVb, 2304,1024,256);
  k_pgemm<<<dim3(162,4), b256, 0, stream>>>(UVb, WT + wt_g2, g_b1, g_b2, Qb, 20736,512,512);
  k_mgemm<1,1><<<dim3(162,4), b256, 0, stream>>>(Qb, WT + wt_g3, g_b3, Pb, 20736,512,512);
  k_mgemm<1,1><<<dim3(162,2), b256, 0, stream>>>(Pb, WT + wt_g4, g_b4, Qb, 20736,256,512);
  k_sumj<<<dim3(2304), b256, 0, stream>>>(Qb, SJ, SJb, 256);

  for (int i = 0; i < 3; ++i) {
    k_mgemm<1,0><<<dim3(18,4), b256, 0, stream>>>(SJb, WT + wt_h1 + (size_t)i*131072, nullptr, UVb, 2304,512,256);
    k_pgemm<<<dim3(162,2), b256, 0, stream>>>(UVb, WT + wt_h2 + (size_t)i*65536, h_b1 + i*256, h_b2 + i*256, Qb, 20736,256,256);
    k_mgemm<1,1><<<dim3(162,2), b256, 0, stream>>>(Qb, WT + wt_h3 + (size_t)i*65536, h_b3 + i*256, Pb, 20736,256,256);
    k_sumj<<<dim3(2304), b256, 0, stream>>>(Pb, SJ, SJb, 256);
  }

  // head
  k_hsum<<<dim3(256), b256, 0, stream>>>(SJ, HS, HSb);
  k_mgemm<1,1><<<dim3(2,2), b256, 0, stream>>>(HSb, WT + wt_f1, f_b1, F1, 256,256,256);
  k_mgemm<1,1><<<dim3(2,2), b256, 0, stream>>>(F1,  WT + wt_f2, f_b2, F2, 256,256,256);
  k_tailfin<<<dim3(1), b256, 0, stream>>>(HS, F2, ff_w, ff_b, (float*)d_out);
}

// Round 10
// 348.971 us; speedup vs baseline: 11.5495x; 1.0031x over previous
//
#include <hip/hip_runtime.h>
#include <hip/hip_bf16.h>
#include <math.h>

static __device__ __forceinline__ float lrelu(float v){ return v > 0.0f ? v : 0.01f*v; }

static __device__ __forceinline__ unsigned short f2bf(float f){
  unsigned int u = __float_as_uint(f);
  unsigned int r = (u + 0x7fffu + ((u >> 16) & 1u)) >> 16;
  return (unsigned short)r;
}
static __device__ __forceinline__ float bf2f(unsigned short u){
  return __uint_as_float(((unsigned int)u) << 16);
}
static __device__ __forceinline__ unsigned int pack_bf2(float lo, float hi){
  __hip_bfloat162 bb = __float22bfloat162_rn(make_float2(lo, hi));
  return *reinterpret_cast<unsigned int*>(&bb);
}
static __device__ __forceinline__ void gload16(const void* g, void* l){
  __builtin_amdgcn_global_load_lds(
    (const __attribute__((address_space(1))) void*)(const void*)g,
    (__attribute__((address_space(3))) void*)l, 16, 0, 0);
}

#define ENC_NORM 1.4247939f
#define GC_C     6.3775511f
#define GC_2CD   1.3426423f
#define GC_CD2   0.070665395f
#define GC_S1    0.86820227f

typedef __attribute__((ext_vector_type(4))) float f32x4;
typedef __attribute__((ext_vector_type(8))) short bf16x8;

// ================= unified weight prep =================
__global__ __launch_bounds__(256) void k_prep(
    const float* __restrict__ g_w1, const float* __restrict__ g_w2,
    const float* __restrict__ g_w3, const float* __restrict__ g_w4,
    const float* __restrict__ h_w1, const float* __restrict__ h_w2,
    const float* __restrict__ h_w3, const float* __restrict__ post_w,
    const float* __restrict__ conv_w2, const float* __restrict__ conv_w3,
    const float* __restrict__ conv_w4, const float* __restrict__ conv_w1,
    const float* __restrict__ f_w1, const float* __restrict__ f_w2,
    unsigned short* __restrict__ WT)
{
  int e = blockIdx.x*256 + threadIdx.x;
  float v;
  if (e < 262144) {
    int nn = e >> 8, kk = e & 255;
    v = (nn < 512) ? g_w1[kk*512 + nn] : g_w1[(256+kk)*512 + (nn-512)];
  } else if (e < 524288) {
    int r = e - 262144; int nn = r >> 9, kk = r & 511;
    v = g_w2[kk*512 + nn];
  } else if (e < 786432) {
    int r = e - 524288; int nn = r >> 9, kk = r & 511;
    v = g_w3[kk*512 + nn];
  } else if (e < 917504) {
    int r = e - 786432; int nn = r >> 9, kk = r & 511;
    v = g_w4[kk*256 + nn];
  } else if (e < 1310720) {
    int r = e - 917504; int i = r >> 17; int q = r & 131071;
    int nn = q >> 8, kk = q & 255;
    v = (nn < 256) ? h_w1[i*131072 + kk*256 + nn]
                   : h_w1[i*131072 + (256+kk)*256 + (nn-256)];
  } else if (e < 1507328) {
    int r = e - 1310720; int i = r >> 16; int q = r & 65535;
    int nn = q >> 8, kk = q & 255;
    v = h_w2[i*65536 + kk*256 + nn];
  } else if (e < 1703936) {
    int r = e - 1507328; int i = r >> 16; int q = r & 65535;
    int nn = q >> 8, kk = q & 255;
    v = h_w3[i*65536 + kk*256 + nn];
  } else if (e < 1835008) {
    int r = e - 1703936; int np = r >> 9, kp = r & 511;
    int px = kp >> 5, c = kp & 31;
    v = (np < 247) ? post_w[(c*16+px)*247 + np] : 0.f;
  } else if (e < 1862656) {
    int r = e - 1835008; int which = r / 9216; int q = r % 9216;
    int tap = q >> 10, o = (q >> 5) & 31, c = q & 31;
    const float* w = which==0 ? conv_w2 : (which==1 ? conv_w3 : conv_w4);
    v = w[(o*32+c)*9 + tap];
  } else if (e < 1871872) {
    int r = e - 1862656; int tap = r >> 10, o = (r >> 5) & 31, c = r & 31;
    v = (c < 20) ? conv_w1[(o*20+c)*9 + tap] : 0.f;
  } else if (e < 1937408) {
    int r = e - 1871872; int nn = r >> 8, kk = r & 255;
    v = f_w1[kk*256 + nn];
  } else {
    int r = e - 1937408; int nn = r >> 8, kk = r & 255;
    v = f_w2[kk*256 + nn];
  }
  WT[e] = f2bf(v);
}

// ================= conv1: fused encoding + MFMA implicit GEMM, slab loop =================
// launch_bounds(256,1): let the allocator keep the 72-VGPR weight-fragment array
// resident (LDS caps occupancy at 3 blk/CU anyway).
__global__ __launch_bounds__(256, 1) void k_conv1m(
    const float* __restrict__ batch, const unsigned short* __restrict__ wc1,
    const float* __restrict__ bias, unsigned short* __restrict__ y)
{
  __shared__ unsigned short ench[7][80][40];   // 44.8 KB -> 3 blk/CU
  int n = blockIdx.x;
  int s0 = blockIdx.y ? 7 : 0;
  int s1 = blockIdx.y ? 13 : 7;
  int tid = threadIdx.x;
  int lane = tid & 63, wid = tid >> 6;
  int lr = lane & 15, kg = lane >> 4;

  bf16x8 bf0[9], bf1[9];
  #pragma unroll
  for (int tap = 0; tap < 9; ++tap) {
    bf0[tap] = *(const bf16x8*)&wc1[tap*1024 + lr*32 + kg*8];
    bf1[tap] = *(const bf16x8*)&wc1[tap*1024 + (16+lr)*32 + kg*8];
  }
  float b0 = bias[lr], b1 = bias[16 + lr];
  const float S2 = GC_S1 * GC_S1;

  for (int s = s0; s < s1; ++s) {
    int orow0 = s * 3;
    int irow0 = orow0 * 2;
    const float* img = batch + (size_t)n*6400 + irow0*80;
    for (int p = tid; p < 7*80; p += 256) {
      int row = p / 80, hx = p % 80;
      int col = (hx < 40) ? 2*hx : 2*(hx-40)+1;
      if (col > 78) continue;
      float x = img[row*80 + col];
      float E = __expf(x * (4.0f/255.0f) - 2.0f);
      float t = 1.0f - 2.0f*__builtin_amdgcn_rcpf(E + 1.0f);
      float z = t - 1.0f;
      float e = ENC_NORM * __expf(-GC_C*z*z);
      float rg = __expf(-GC_2CD*z - GC_CD2);
      unsigned int pk[16];
      #pragma unroll
      for (int cp = 0; cp < 10; ++cp) {
        float e1 = e * rg;
        pk[cp] = pack_bf2(e, e1);
        e  = e1 * rg * GC_S1;
        rg = rg * S2;
      }
      #pragma unroll
      for (int cp = 10; cp < 16; ++cp) pk[cp] = 0u;
      unsigned short* dst = &ench[row][hx][0];
      *(uint4*)(dst)      = *(uint4*)&pk[0];
      *(uint4*)(dst + 8)  = *(uint4*)&pk[4];
      *(uint4*)(dst + 16) = *(uint4*)&pk[8];
      *(uint4*)(dst + 24) = *(uint4*)&pk[12];
    }
    __syncthreads();

    const int totpx = 117;
    for (int t = wid; t < 8; t += 4) {
      int pa = t*16 + lr;
      int pc = (pa < totpx) ? pa : (totpx - 1);
      int oh = pc / 39, ow = pc % 39;
      f32x4 acc0 = {0.f,0.f,0.f,0.f}, acc1 = {0.f,0.f,0.f,0.f};
      #pragma unroll
      for (int kh = 0; kh < 3; ++kh) {
        int r = oh*2 + kh;
        #pragma unroll
        for (int kw = 0; kw < 3; ++kw) {
          int hidx = (kw == 1) ? (40 + ow) : (ow + (kw >> 1));
          bf16x8 a = *(const bf16x8*)&ench[r][hidx][kg*8];
          int tap = kh*3 + kw;
          acc0 = __builtin_amdgcn_mfma_f32_16x16x32_bf16(a, bf0[tap], acc0, 0, 0, 0);
          acc1 = __builtin_amdgcn_mfma_f32_16x16x32_bf16(a, bf1[tap], acc1, 0, 0, 0);
        }
      }
      #pragma unroll
      for (int rr = 0; rr < 4; ++rr) {
        int ps = t*16 + kg*4 + rr;
        if (ps < totpx) {
          int soh = orow0 + ps / 39, sow = ps % 39;
          unsigned short* op = y + (((size_t)n*39 + soh)*39 + sow)*32;
          op[lr]      = f2bf(lrelu(acc0[rr] + b0));
          op[16 + lr] = f2bf(lrelu(acc1[rr] + b1));
        }
      }
    }
    __syncthreads();
  }
}

// ---------------- conv2/3/4: bf16 MFMA implicit GEMM, slab loop ----------------
template<int H, int W, int OH, int OW, int ROWS, int SLABS>
__global__ __launch_bounds__(256, 1) void k_cmfma(
    const unsigned short* __restrict__ in, const unsigned short* __restrict__ wc,
    const float* __restrict__ bias, unsigned short* __restrict__ out)
{
  constexpr int IR = 2*ROWS + 1;
  constexpr int EV = (W + 1) / 2;
  __shared__ unsigned short xs[IR][W][40];
  int n = blockIdx.x;
  int tid = threadIdx.x;
  int lane = tid & 63, wid = tid >> 6;
  int lr = lane & 15, kg = lane >> 4;

  bf16x8 bf0[9], bf1[9];
  #pragma unroll
  for (int tap = 0; tap < 9; ++tap) {
    bf0[tap] = *(const bf16x8*)&wc[(tap*32 + lr)*32      + kg*8];
    bf1[tap] = *(const bf16x8*)&wc[(tap*32 + 16 + lr)*32 + kg*8];
  }
  float b0 = bias[lr], b1 = bias[16 + lr];

  for (int s = 0; s < SLABS; ++s) {
    int orow0 = (blockIdx.y * SLABS + s) * ROWS;
    if (orow0 >= OH) break;
    int nrows = min(ROWS, OH - orow0);
    int irow0 = orow0 * 2;
    int ir = min(2*nrows + 1, H - irow0);

    const unsigned short* ip = in + ((size_t)n*H + irow0)*W*32;
    int npx = ir * W;
    for (int p = tid; p < npx; p += 256) {
      const uint4* src = (const uint4*)(ip + (size_t)p*32);
      uint4 v0 = src[0], v1 = src[1], v2 = src[2], v3 = src[3];
      int r = p / W, col = p % W;
      int hx = (col & 1) ? EV + (col >> 1) : (col >> 1);
      unsigned short* dst = &xs[r][hx][0];
      *(uint4*)(dst)      = v0;
      *(uint4*)(dst + 8)  = v1;
      *(uint4*)(dst + 16) = v2;
      *(uint4*)(dst + 24) = v3;
    }
    __syncthreads();

    int totpx = nrows * OW;
    int ntiles = (totpx + 15) >> 4;
    for (int t = wid; t < ntiles; t += 4) {
      int pa = t*16 + lr;
      int pc = (pa < totpx) ? pa : 0;
      int oh = pc / OW, ow = pc % OW;
      f32x4 acc0 = {0.f,0.f,0.f,0.f}, acc1 = {0.f,0.f,0.f,0.f};
      #pragma unroll
      for (int kh = 0; kh < 3; ++kh)
        #pragma unroll
        for (int kw = 0; kw < 3; ++kw) {
          int hidx = (kw == 1) ? (EV + ow) : (ow + (kw >> 1));
          bf16x8 a = *(const bf16x8*)&xs[oh*2 + kh][hidx][kg*8];
          acc0 = __builtin_amdgcn_mfma_f32_16x16x32_bf16(a, bf0[kh*3+kw], acc0, 0, 0, 0);
          acc1 = __builtin_amdgcn_mfma_f32_16x16x32_bf16(a, bf1[kh*3+kw], acc1, 0, 0, 0);
        }
      #pragma unroll
      for (int rr = 0; rr < 4; ++rr) {
        int ps = t*16 + kg*4 + rr;
        if (ps < totpx) {
          int soh = orow0 + ps / OW, sow = ps % OW;
          unsigned short* op = out + (((size_t)n*OH + soh)*OW + sow)*32;
          op[lr]      = f2bf(lrelu(acc0[rr] + b0));
          op[16 + lr] = f2bf(lrelu(acc1[rr] + b1));
        }
      }
    }
    __syncthreads();
  }
}

// ---------------- bf16 MFMA GEMM via global_load_lds + XOR-swizzled LDS ----------------
template<int OUT_BF16, int ACT>
__global__ __launch_bounds__(256) void k_mgemm(
    const unsigned short* __restrict__ A, const unsigned short* __restrict__ Wt,
    const float* __restrict__ bias, void* __restrict__ Cv,
    int M, int N, int K)
{
  __shared__ unsigned short As[128*64];
  __shared__ unsigned short Bs[128*64];
  int bm = blockIdx.x * 128;
  int bn = blockIdx.y * 128;
  int tid = threadIdx.x;
  int wid = tid >> 6, lane = tid & 63;
  int wr = (wid >> 1) * 64, wc = (wid & 1) * 64;
  int lr = lane & 15, kg = lane >> 4;

  int srow = lane >> 3;
  int ssw  = ((lane & 7) * 16) ^ (srow << 4);
  int rsw  = (lr & 7) << 4;

  f32x4 acc[4][4];
  #pragma unroll
  for (int i = 0; i < 4; ++i)
    #pragma unroll
    for (int j = 0; j < 4; ++j)
      acc[i][j] = (f32x4){0.f,0.f,0.f,0.f};

  for (int k0 = 0; k0 < K; k0 += 64) {
    #pragma unroll
    for (int i = 0; i < 4; ++i) {
      int rowc = wid*32 + i*8;
      int row  = rowc + srow;
      gload16((const char*)&A[(size_t)(bm + row)*K + k0] + ssw, &As[rowc*64]);
      gload16((const char*)&Wt[(size_t)(bn + row)*K + k0] + ssw, &Bs[rowc*64]);
    }
    __syncthreads();
    #pragma unroll
    for (int ks = 0; ks < 2; ++ks) {
      int roff = ((ks*64 + kg*16) ^ rsw) >> 1;
      bf16x8 a[4], b[4];
      #pragma unroll
      for (int i = 0; i < 4; ++i) {
        a[i] = *(const bf16x8*)&As[(wr + i*16 + lr)*64 + roff];
        b[i] = *(const bf16x8*)&Bs[(wc + i*16 + lr)*64 + roff];
      }
      #pragma unroll
      for (int i = 0; i < 4; ++i)
        #pragma unroll
        for (int j = 0; j < 4; ++j)
          acc[i][j] = __builtin_amdgcn_mfma_f32_16x16x32_bf16(a[i], b[j], acc[i][j], 0, 0, 0);
    }
    __syncthreads();
  }
  int r0 = (lane >> 4) * 4;
  #pragma unroll
  for (int i = 0; i < 4; ++i) {
    #pragma unroll
    for (int j = 0; j < 4; ++j) {
      int col = bn + wc + j*16 + lr;
      float bv = bias ? bias[col] : 0.f;
      #pragma unroll
      for (int rr = 0; rr < 4; ++rr) {
        int row = bm + wr + i*16 + r0 + rr;
        float v = acc[i][j][rr] + bv;
        if (ACT) v = lrelu(v);
        if (OUT_BF16) ((unsigned short*)Cv)[(size_t)row*N + col] = f2bf(v);
        else          ((float*)Cv)[(size_t)row*N + col] = v;
      }
    }
  }
}

// ---------------- pair GEMM: fused expand + GEMM ----------------
__global__ __launch_bounds__(256) void k_pgemm(
    const unsigned short* __restrict__ UV, const unsigned short* __restrict__ Wt,
    const float* __restrict__ abias, const float* __restrict__ obias,
    unsigned short* __restrict__ C, int M, int N, int K)
{
  __shared__ unsigned short As[128*64];
  __shared__ unsigned short Bs[128*64];
  __shared__ float absm[512];
  int bm = blockIdx.x * 128;
  int bn = blockIdx.y * 128;
  int tid = threadIdx.x;
  int wid = tid >> 6, lane = tid & 63;
  int wr = (wid >> 1) * 64, wc = (wid & 1) * 64;
  int lr = lane & 15, kg = lane >> 4;
  int ld = 2*K;

  int srow = lane >> 3;
  int ssw  = ((lane & 7) * 16) ^ (srow << 4);
  int rsw  = (lr & 7) << 4;

  for (int idx = tid; idx < K; idx += 256) absm[idx] = abias[idx];

  int urow[4], vrow[4], arow[4], asw[4];
  #pragma unroll
  for (int i = 0; i < 4; ++i) {
    int ch = tid + (i << 8);
    int r = ch >> 3;
    int m = bm + r;
    int n = m / 81; int rem = m - n*81;
    int ii = rem / 9; int jj = rem - ii*9;
    urow[i] = n*9 + ii; vrow[i] = n*9 + jj;
    arow[i] = r;
    asw[i] = (((ch & 7) * 16) ^ ((r & 7) << 4)) >> 1;
  }
  __syncthreads();

  f32x4 acc[4][4];
  #pragma unroll
  for (int i = 0; i < 4; ++i)
    #pragma unroll
    for (int j = 0; j < 4; ++j)
      acc[i][j] = (f32x4){0.f,0.f,0.f,0.f};

  for (int k0 = 0; k0 < K; k0 += 64) {
    #pragma unroll
    for (int i = 0; i < 4; ++i) {
      int rowc = wid*32 + i*8;
      int row  = rowc + srow;
      gload16((const char*)&Wt[(size_t)(bn + row)*K + k0] + ssw, &Bs[rowc*64]);
    }
    #pragma unroll
    for (int i = 0; i < 4; ++i) {
      int ch = tid + (i << 8);
      int kc = (ch & 7) * 8;
      uint4 u4 = *(const uint4*)&UV[(size_t)urow[i]*ld + k0 + kc];
      uint4 v4 = *(const uint4*)&UV[(size_t)vrow[i]*ld + K + k0 + kc];
      const unsigned short* us = (const unsigned short*)&u4;
      const unsigned short* vs = (const unsigned short*)&v4;
      unsigned int pk[4];
      #pragma unroll
      for (int e2 = 0; e2 < 4; ++e2) {
        float a0 = bf2f(us[2*e2])   + bf2f(vs[2*e2])   + absm[k0 + kc + 2*e2];
        float a1 = bf2f(us[2*e2+1]) + bf2f(vs[2*e2+1]) + absm[k0 + kc + 2*e2+1];
        pk[e2] = pack_bf2(lrelu(a0), lrelu(a1));
      }
      *(uint4*)&As[arow[i]*64 + asw[i]] = *(uint4*)pk;
    }
    __syncthreads();
    #pragma unroll
    for (int ks = 0; ks < 2; ++ks) {
      int roff = ((ks*64 + kg*16) ^ rsw) >> 1;
      bf16x8 a[4], b[4];
      #pragma unroll
      for (int i = 0; i < 4; ++i) {
        a[i] = *(const bf16x8*)&As[(wr + i*16 + lr)*64 + roff];
        b[i] = *(const bf16x8*)&Bs[(wc + i*16 + lr)*64 + roff];
      }
      #pragma unroll
      for (int i = 0; i < 4; ++i)
        #pragma unroll
        for (int j = 0; j < 4; ++j)
          acc[i][j] = __builtin_amdgcn_mfma_f32_16x16x32_bf16(a[i], b[j], acc[i][j], 0, 0, 0);
    }
    __syncthreads();
  }
  int r0 = (lane >> 4) * 4;
  #pragma unroll
  for (int i = 0; i < 4; ++i) {
    #pragma unroll
    for (int j = 0; j < 4; ++j) {
      int col = bn + wc + j*16 + lr;
      float bv = obias[col];
      #pragma unroll
      for (int rr = 0; rr < 4; ++rr) {
        int row = bm + wr + i*16 + r0 + rr;
        C[(size_t)row*N + col] = f2bf(lrelu(acc[i][j][rr] + bv));
      }
    }
  }
}

// ---------------- build objects (2304 x 256) bf16 ----------------
__global__ void k_objects(const float* __restrict__ panel, const float* __restrict__ post_b,
                          unsigned short* __restrict__ obj)
{
  int idx = blockIdx.x*256 + threadIdx.x;
  int row = idx >> 8;
  int k = idx & 255;
  int slot = row % 9;
  int nn = row / 9;
  int b = nn >> 3, opt = nn & 7;
  float v;
  if (k < 247) {
    int src = (slot < 8) ? (b*16 + slot) : (b*16 + 8 + opt);
    v = panel[(size_t)src*256 + k] + post_b[k];
  } else {
    v = ((k - 247) == slot) ? 1.0f : 0.0f;
  }
  obj[idx] = f2bf(v);
}

// ---------------- sum over j ----------------
__global__ void k_sumj(const unsigned short* __restrict__ Z, float* __restrict__ SJ,
                       unsigned short* __restrict__ SJb, int C)
{
  int idx = blockIdx.x*256 + threadIdx.x;
  int orow = idx / C, k = idx % C;
  int n = orow / 9, i = orow % 9;
  const unsigned short* base = Z + (size_t)(n*81 + i*9)*C + k;
  float s = 0.f;
  #pragma unroll
  for (int j = 0; j < 9; ++j) s += bf2f(base[(size_t)j*C]);
  SJ[idx] = s;
  SJb[idx] = f2bf(s);
}

// ---------------- sum over i ----------------
__global__ void k_hsum(const float* __restrict__ SJ, float* __restrict__ HS,
                       unsigned short* __restrict__ HSb)
{
  int idx = blockIdx.x*256 + threadIdx.x;
  int n = idx >> 8, k = idx & 255;
  const float* base = SJ + (size_t)n*9*256 + k;
  float s = 0.f;
  #pragma unroll
  for (int i = 0; i < 9; ++i) s += base[i*256];
  HS[idx] = s;
  HSb[idx] = f2bf(s);
}

// ---------------- fused tail ----------------
__global__ __launch_bounds__(256) void k_tailfin(
    const float* __restrict__ HS, const unsigned short* __restrict__ F2,
    const float* __restrict__ ffw, const float* __restrict__ ffb,
    float* __restrict__ out)
{
  __shared__ float red[256];
  __shared__ float wsm[256];
  int tid = threadIdx.x;
  wsm[tid] = ffw[tid];
  float s = 0.f;
  for (int j = 0; j < 256; ++j) { float v = HS[j*256 + tid]; s += v*v; }
  red[tid] = s; __syncthreads();
  for (int off = 128; off > 0; off >>= 1) { if (tid < off) red[tid] += red[tid + off]; __syncthreads(); }
  float hsq = red[0];
  __syncthreads();
  float r = ffb[0];
  for (int k = 0; k < 256; ++k) r += bf2f(F2[(size_t)tid*256 + k])*wsm[k];
  red[tid] = r*r; __syncthreads();
  for (int off = 128; off > 0; off >>= 1) { if (tid < off) red[tid] += red[tid + off]; __syncthreads(); }
  out[tid] = r;
  if (tid == 0) out[256] = hsq/65536.0f + red[0]/256.0f;
}

extern "C" void kernel_launch(void* const* d_in, const int* in_sizes, int n_in,
                              void* d_out, int out_size, void* d_ws, size_t ws_size,
                              hipStream_t stream)
{
  const float* batch   = (const float*)d_in[0];
  const float* conv_w1 = (const float*)d_in[1];
  const float* conv_b1 = (const float*)d_in[2];
  const float* conv_w2 = (const float*)d_in[3];
  const float* conv_b2 = (const float*)d_in[4];
  const float* conv_w3 = (const float*)d_in[5];
  const float* conv_b3 = (const float*)d_in[6];
  const float* conv_w4 = (const float*)d_in[7];
  const float* conv_b4 = (const float*)d_in[8];
  const float* post_w  = (const float*)d_in[9];
  const float* post_b  = (const float*)d_in[10];
  const float* g_w1    = (const float*)d_in[11];
  const float* g_b1    = (const float*)d_in[12];
  const float* g_w2    = (const float*)d_in[13];
  const float* g_b2    = (const float*)d_in[14];
  const float* g_w3    = (const float*)d_in[15];
  const float* g_b3    = (const float*)d_in[16];
  const float* g_w4    = (const float*)d_in[17];
  const float* g_b4    = (const float*)d_in[18];
  const float* h_w1    = (const float*)d_in[19];
  const float* h_b1    = (const float*)d_in[20];
  const float* h_w2    = (const float*)d_in[21];
  const float* h_b2    = (const float*)d_in[22];
  const float* h_w3    = (const float*)d_in[23];
  const float* h_b3    = (const float*)d_in[24];
  const float* f_w1    = (const float*)d_in[25];
  const float* f_b1    = (const float*)d_in[26];
  const float* f_w2    = (const float*)d_in[27];
  const float* f_b2    = (const float*)d_in[28];
  const float* ff_w    = (const float*)d_in[29];
  const float* ff_b    = (const float*)d_in[30];

  char* wsb = (char*)d_ws;
  const size_t off_Y1    = 0;
  const size_t off_Y2    = 52000000;
  const size_t off_Y3    = 64000000;
  const size_t off_Y4    = 67000000;
  const size_t off_PANEL = 68000000;
  const size_t off_WT    = 132000000;
  const size_t off_Pb    = 0;
  const size_t off_Qb    = 22000000;
  const size_t off_UV    = 44000000;
  const size_t off_OBJb  = 54000000;
  const size_t off_SJ    = 56000000;
  const size_t off_SJb   = 59000000;
  const size_t off_HS    = 61000000;
  const size_t off_HSb   = 61500000;
  const size_t off_F1    = 62000000;
  const size_t off_F2    = 63000000;

  unsigned short* WT = (unsigned short*)(wsb + off_WT);
  const size_t wt_g1   = 0;
  const size_t wt_g2   = 262144;
  const size_t wt_g3   = 524288;
  const size_t wt_g4   = 786432;
  const size_t wt_h1   = 917504;
  const size_t wt_h2   = 1310720;
  const size_t wt_h3   = 1507328;
  const size_t wt_post = 1703936;
  const size_t wt_cw2  = 1835008;
  const size_t wt_cw3  = 1844224;
  const size_t wt_cw4  = 1853440;
  const size_t wt_cw1  = 1862656;
  const size_t wt_f1   = 1871872;
  const size_t wt_f2   = 1937408;

  dim3 b256(256);

  k_prep<<<dim3(7824), b256, 0, stream>>>(g_w1, g_w2, g_w3, g_w4, h_w1, h_w2, h_w3,
                                          post_w, conv_w2, conv_w3, conv_w4, conv_w1,
                                          f_w1, f_w2, WT);

  unsigned short* Y1 = (unsigned short*)(wsb + off_Y1);
  unsigned short* Y2 = (unsigned short*)(wsb + off_Y2);
  unsigned short* Y3 = (unsigned short*)(wsb + off_Y3);
  unsigned short* Y4 = (unsigned short*)(wsb + off_Y4);
  float* PANEL = (float*)(wsb + off_PANEL);

  k_conv1m<<<dim3(512,2), b256, 0, stream>>>(batch, WT + wt_cw1, conv_b1, Y1);
  k_cmfma<39,39,19,19,10,2><<<dim3(512,1), b256, 0, stream>>>(Y1, WT + wt_cw2, conv_b2, Y2);
  k_cmfma<19,19, 9, 9, 9,1><<<dim3(512,1), b256, 0, stream>>>(Y2, WT + wt_cw3, conv_b3, Y3);
  k_cmfma< 9, 9, 4, 4, 4,1><<<dim3(512,1), b256, 0, stream>>>(Y3, WT + wt_cw4, conv_b4, Y4);

  k_mgemm<0,0><<<dim3(4,2), b256, 0, stream>>>(Y4, WT + wt_post, nullptr, PANEL, 512,256,512);

  unsigned short* OBJb = (unsigned short*)(wsb + off_OBJb);
  unsigned short* Pb   = (unsigned short*)(wsb + off_Pb);
  unsigned short* Qb   = (unsigned short*)(wsb + off_Qb);
  unsigned short* SJb  = (unsigned short*)(wsb + off_SJb);
  unsigned short* UVb  = (unsigned short*)(wsb + off_UV);
  float* SJ = (float*)(wsb + off_SJ);
  float* HS = (float*)(wsb + off_HS);
  unsigned short* HSb = (unsigned short*)(wsb + off_HSb);
  unsigned short* F1 = (unsigned short*)(wsb + off_F1);
  unsigned short* F2 = (unsigned short*)(wsb + off_F2);

  k_objects<<<dim3(2304), b256, 0, stream>>>(PANEL, post_b, OBJb);

  // g-MLP
  k_mgemm<1,0><<<dim3(18,8), b256, 0, stream>>>(OBJb, WT + wt_g1, nullptr, UVb, 2304,1024,256);
  k_pgemm<<<dim3(162,4), b256, 0, stream>>>(UVb, WT + wt_g2, g_b1, g_b2, Qb, 20736,512,512);
  k_mgemm<1,1><<<dim3(162,4), b256, 0, stream>>>(Qb, WT + wt_g3, g_b3, Pb, 20736,512,512);
  k_mgemm<1,1><<<dim3(162,2), b256, 0, stream>>>(Pb, WT + wt_g4, g_b4, Qb, 20736,256,512);
  k_sumj<<<dim3(2304), b256, 0, stream>>>(Qb, SJ, SJb, 256);

  for (int i = 0; i < 3; ++i) {
    k_mgemm<1,0><<<dim3(18,4), b256, 0, stream>>>(SJb, WT + wt_h1 + (size_t)i*131072, nullptr, UVb, 2304,512,256);
    k_pgemm<<<dim3(162,2), b256, 0, stream>>>(UVb, WT + wt_h2 + (size_t)i*65536, h_b1 + i*256, h_b2 + i*256, Qb, 20736,256,256);
    k_mgemm<1,1><<<dim3(162,2), b256, 0, stream>>>(Qb, WT + wt_h3 + (size_t)i*65536, h_b3 + i*256, Pb, 20736,256,256);
    k_sumj<<<dim3(2304), b256, 0, stream>>>(Pb, SJ, SJb, 256);
  }

  // head
  k_hsum<<<dim3(256), b256, 0, stream>>>(SJ, HS, HSb);
  k_mgemm<1,1><<<dim3(2,2), b256, 0, stream>>>(HSb, WT + wt_f1, f_b1, F1, 256,256,256);
  k_mgemm<1,1><<<dim3(2,2), b256, 0, stream>>>(F1,  WT + wt_f2, f_b2, F2, 256,256,256);
  k_tailfin<<<dim3(1), b256, 0, stream>>>(HS, F2, ff_w, ff_b, (float*)d_out);
}

// Round 11
// 340.392 us; speedup vs baseline: 11.8406x; 1.0252x over previous
//
#include <hip/hip_runtime.h>
#include <hip/hip_bf16.h>
#include <math.h>

static __device__ __forceinline__ float lrelu(float v){ return v > 0.0f ? v : 0.01f*v; }

static __device__ __forceinline__ unsigned short f2bf(float f){
  unsigned int u = __float_as_uint(f);
  unsigned int r = (u + 0x7fffu + ((u >> 16) & 1u)) >> 16;
  return (unsigned short)r;
}
static __device__ __forceinline__ float bf2f(unsigned short u){
  return __uint_as_float(((unsigned int)u) << 16);
}
static __device__ __forceinline__ unsigned int pack_bf2(float lo, float hi){
  __hip_bfloat162 bb = __float22bfloat162_rn(make_float2(lo, hi));
  return *reinterpret_cast<unsigned int*>(&bb);
}
static __device__ __forceinline__ void gload16(const void* g, void* l){
  __builtin_amdgcn_global_load_lds(
    (const __attribute__((address_space(1))) void*)(const void*)g,
    (__attribute__((address_space(3))) void*)l, 16, 0, 0);
}

#define ENC_NORM 1.4247939f
#define GC_C     6.3775511f
#define GC_2CD   1.3426423f
#define GC_CD2   0.070665395f
#define GC_S1    0.86820227f

typedef __attribute__((ext_vector_type(4))) float f32x4;
typedef __attribute__((ext_vector_type(8))) short bf16x8;

// ================= unified weight prep =================
__global__ __launch_bounds__(256) void k_prep(
    const float* __restrict__ g_w1, const float* __restrict__ g_w2,
    const float* __restrict__ g_w3, const float* __restrict__ g_w4,
    const float* __restrict__ h_w1, const float* __restrict__ h_w2,
    const float* __restrict__ h_w3, const float* __restrict__ post_w,
    const float* __restrict__ conv_w2, const float* __restrict__ conv_w3,
    const float* __restrict__ conv_w4, const float* __restrict__ conv_w1,
    const float* __restrict__ f_w1, const float* __restrict__ f_w2,
    unsigned short* __restrict__ WT)
{
  int e = blockIdx.x*256 + threadIdx.x;
  float v;
  if (e < 262144) {
    int nn = e >> 8, kk = e & 255;
    v = (nn < 512) ? g_w1[kk*512 + nn] : g_w1[(256+kk)*512 + (nn-512)];
  } else if (e < 524288) {
    int r = e - 262144; int nn = r >> 9, kk = r & 511;
    v = g_w2[kk*512 + nn];
  } else if (e < 786432) {
    int r = e - 524288; int nn = r >> 9, kk = r & 511;
    v = g_w3[kk*512 + nn];
  } else if (e < 917504) {
    int r = e - 786432; int nn = r >> 9, kk = r & 511;
    v = g_w4[kk*256 + nn];
  } else if (e < 1310720) {
    int r = e - 917504; int i = r >> 17; int q = r & 131071;
    int nn = q >> 8, kk = q & 255;
    v = (nn < 256) ? h_w1[i*131072 + kk*256 + nn]
                   : h_w1[i*131072 + (256+kk)*256 + (nn-256)];
  } else if (e < 1507328) {
    int r = e - 1310720; int i = r >> 16; int q = r & 65535;
    int nn = q >> 8, kk = q & 255;
    v = h_w2[i*65536 + kk*256 + nn];
  } else if (e < 1703936) {
    int r = e - 1507328; int i = r >> 16; int q = r & 65535;
    int nn = q >> 8, kk = q & 255;
    v = h_w3[i*65536 + kk*256 + nn];
  } else if (e < 1835008) {
    int r = e - 1703936; int np = r >> 9, kp = r & 511;
    int px = kp >> 5, c = kp & 31;
    v = (np < 247) ? post_w[(c*16+px)*247 + np] : 0.f;
  } else if (e < 1862656) {
    int r = e - 1835008; int which = r / 9216; int q = r % 9216;
    int tap = q >> 10, o = (q >> 5) & 31, c = q & 31;
    const float* w = which==0 ? conv_w2 : (which==1 ? conv_w3 : conv_w4);
    v = w[(o*32+c)*9 + tap];
  } else if (e < 1871872) {
    int r = e - 1862656; int tap = r >> 10, o = (r >> 5) & 31, c = r & 31;
    v = (c < 20) ? conv_w1[(o*20+c)*9 + tap] : 0.f;
  } else if (e < 1937408) {
    int r = e - 1871872; int nn = r >> 8, kk = r & 255;
    v = f_w1[kk*256 + nn];
  } else {
    int r = e - 1937408; int nn = r >> 8, kk = r & 255;
    v = f_w2[kk*256 + nn];
  }
  WT[e] = f2bf(v);
}

// ================= conv1: fused encoding + MFMA implicit GEMM =================
// Column-split: block = (image, col-half). LDS 23 KB -> 6 blocks/CU.
// h=0: ow 0..19 (cols 0..40); h=1: ow 20..38 (cols 40..78). 13 row-slabs looped.
__global__ __launch_bounds__(256, 1) void k_conv1m(
    const float* __restrict__ batch, const unsigned short* __restrict__ wc1,
    const float* __restrict__ bias, unsigned short* __restrict__ y)
{
  __shared__ unsigned short ench[7][41][40];   // 23 KB
  int n = blockIdx.x;
  int h = blockIdx.y;
  int c0 = h * 40;
  int OWH = h ? 19 : 20;
  int owbase = h * 20;
  int tid = threadIdx.x;
  int lane = tid & 63, wid = tid >> 6;
  int lr = lane & 15, kg = lane >> 4;

  bf16x8 bf0[9], bf1[9];
  #pragma unroll
  for (int tap = 0; tap < 9; ++tap) {
    bf0[tap] = *(const bf16x8*)&wc1[tap*1024 + lr*32 + kg*8];
    bf1[tap] = *(const bf16x8*)&wc1[tap*1024 + (16+lr)*32 + kg*8];
  }
  float b0 = bias[lr], b1 = bias[16 + lr];
  const float S2 = GC_S1 * GC_S1;

  for (int s = 0; s < 13; ++s) {
    int orow0 = s * 3;
    int irow0 = orow0 * 2;
    const float* img = batch + (size_t)n*6400 + irow0*80;
    for (int p = tid; p < 7*41; p += 256) {
      int row = p / 41, hx = p % 41;
      int lc = (hx < 21) ? 2*hx : 2*(hx-21)+1;
      int c = c0 + lc;
      if (c > 78) continue;
      float x = img[row*80 + c];
      float E = __expf(x * (4.0f/255.0f) - 2.0f);
      float t = 1.0f - 2.0f*__builtin_amdgcn_rcpf(E + 1.0f);
      float z = t - 1.0f;
      float e = ENC_NORM * __expf(-GC_C*z*z);
      float rg = __expf(-GC_2CD*z - GC_CD2);
      unsigned int pk[16];
      #pragma unroll
      for (int cp = 0; cp < 10; ++cp) {
        float e1 = e * rg;
        pk[cp] = pack_bf2(e, e1);
        e  = e1 * rg * GC_S1;
        rg = rg * S2;
      }
      #pragma unroll
      for (int cp = 10; cp < 16; ++cp) pk[cp] = 0u;
      unsigned short* dst = &ench[row][hx][0];
      *(uint4*)(dst)      = *(uint4*)&pk[0];
      *(uint4*)(dst + 8)  = *(uint4*)&pk[4];
      *(uint4*)(dst + 16) = *(uint4*)&pk[8];
      *(uint4*)(dst + 24) = *(uint4*)&pk[12];
    }
    __syncthreads();

    int totpx = 3 * OWH;    // 60 or 57 -> 4 tiles, one per wave
    {
      int t = wid;
      int pa = t*16 + lr;
      int pc = (pa < totpx) ? pa : (totpx - 1);
      int ohl = pc / OWH, lw = pc % OWH;
      f32x4 acc0 = {0.f,0.f,0.f,0.f}, acc1 = {0.f,0.f,0.f,0.f};
      #pragma unroll
      for (int kh = 0; kh < 3; ++kh) {
        int r = ohl*2 + kh;
        #pragma unroll
        for (int kw = 0; kw < 3; ++kw) {
          int hidx = (kw == 1) ? (21 + lw) : (lw + (kw >> 1));
          bf16x8 a = *(const bf16x8*)&ench[r][hidx][kg*8];
          int tap = kh*3 + kw;
          acc0 = __builtin_amdgcn_mfma_f32_16x16x32_bf16(a, bf0[tap], acc0, 0, 0, 0);
          acc1 = __builtin_amdgcn_mfma_f32_16x16x32_bf16(a, bf1[tap], acc1, 0, 0, 0);
        }
      }
      #pragma unroll
      for (int rr = 0; rr < 4; ++rr) {
        int ps = t*16 + kg*4 + rr;
        if (ps < totpx) {
          int soh = orow0 + ps / OWH, sow = owbase + ps % OWH;
          unsigned short* op = y + (((size_t)n*39 + soh)*39 + sow)*32;
          op[lr]      = f2bf(lrelu(acc0[rr] + b0));
          op[16 + lr] = f2bf(lrelu(acc1[rr] + b1));
        }
      }
    }
    __syncthreads();
  }
}

// ---------------- conv2/3/4: bf16 MFMA implicit GEMM, slab loop ----------------
template<int H, int W, int OH, int OW, int ROWS, int SLABS>
__global__ __launch_bounds__(256, 1) void k_cmfma(
    const unsigned short* __restrict__ in, const unsigned short* __restrict__ wc,
    const float* __restrict__ bias, unsigned short* __restrict__ out)
{
  constexpr int IR = 2*ROWS + 1;
  constexpr int EV = (W + 1) / 2;
  __shared__ unsigned short xs[IR][W][40];
  int n = blockIdx.x;
  int tid = threadIdx.x;
  int lane = tid & 63, wid = tid >> 6;
  int lr = lane & 15, kg = lane >> 4;

  bf16x8 bf0[9], bf1[9];
  #pragma unroll
  for (int tap = 0; tap < 9; ++tap) {
    bf0[tap] = *(const bf16x8*)&wc[(tap*32 + lr)*32      + kg*8];
    bf1[tap] = *(const bf16x8*)&wc[(tap*32 + 16 + lr)*32 + kg*8];
  }
  float b0 = bias[lr], b1 = bias[16 + lr];

  for (int s = 0; s < SLABS; ++s) {
    int orow0 = (blockIdx.y * SLABS + s) * ROWS;
    if (orow0 >= OH) break;
    int nrows = min(ROWS, OH - orow0);
    int irow0 = orow0 * 2;
    int ir = min(2*nrows + 1, H - irow0);

    const unsigned short* ip = in + ((size_t)n*H + irow0)*W*32;
    int npx = ir * W;
    for (int p = tid; p < npx; p += 256) {
      const uint4* src = (const uint4*)(ip + (size_t)p*32);
      uint4 v0 = src[0], v1 = src[1], v2 = src[2], v3 = src[3];
      int r = p / W, col = p % W;
      int hx = (col & 1) ? EV + (col >> 1) : (col >> 1);
      unsigned short* dst = &xs[r][hx][0];
      *(uint4*)(dst)      = v0;
      *(uint4*)(dst + 8)  = v1;
      *(uint4*)(dst + 16) = v2;
      *(uint4*)(dst + 24) = v3;
    }
    __syncthreads();

    int totpx = nrows * OW;
    int ntiles = (totpx + 15) >> 4;
    for (int t = wid; t < ntiles; t += 4) {
      int pa = t*16 + lr;
      int pc = (pa < totpx) ? pa : 0;
      int oh = pc / OW, ow = pc % OW;
      f32x4 acc0 = {0.f,0.f,0.f,0.f}, acc1 = {0.f,0.f,0.f,0.f};
      #pragma unroll
      for (int kh = 0; kh < 3; ++kh)
        #pragma unroll
        for (int kw = 0; kw < 3; ++kw) {
          int hidx = (kw == 1) ? (EV + ow) : (ow + (kw >> 1));
          bf16x8 a = *(const bf16x8*)&xs[oh*2 + kh][hidx][kg*8];
          acc0 = __builtin_amdgcn_mfma_f32_16x16x32_bf16(a, bf0[kh*3+kw], acc0, 0, 0, 0);
          acc1 = __builtin_amdgcn_mfma_f32_16x16x32_bf16(a, bf1[kh*3+kw], acc1, 0, 0, 0);
        }
      #pragma unroll
      for (int rr = 0; rr < 4; ++rr) {
        int ps = t*16 + kg*4 + rr;
        if (ps < totpx) {
          int soh = orow0 + ps / OW, sow = ps % OW;
          unsigned short* op = out + (((size_t)n*OH + soh)*OW + sow)*32;
          op[lr]      = f2bf(lrelu(acc0[rr] + b0));
          op[16 + lr] = f2bf(lrelu(acc1[rr] + b1));
        }
      }
    }
    __syncthreads();
  }
}

// ---------------- bf16 MFMA GEMM via global_load_lds + XOR-swizzled LDS ----------------
template<int OUT_BF16, int ACT>
__global__ __launch_bounds__(256) void k_mgemm(
    const unsigned short* __restrict__ A, const unsigned short* __restrict__ Wt,
    const float* __restrict__ bias, void* __restrict__ Cv,
    int M, int N, int K)
{
  __shared__ unsigned short As[128*64];
  __shared__ unsigned short Bs[128*64];
  int bm = blockIdx.x * 128;
  int bn = blockIdx.y * 128;
  int tid = threadIdx.x;
  int wid = tid >> 6, lane = tid & 63;
  int wr = (wid >> 1) * 64, wc = (wid & 1) * 64;
  int lr = lane & 15, kg = lane >> 4;

  int srow = lane >> 3;
  int ssw  = ((lane & 7) * 16) ^ (srow << 4);
  int rsw  = (lr & 7) << 4;

  f32x4 acc[4][4];
  #pragma unroll
  for (int i = 0; i < 4; ++i)
    #pragma unroll
    for (int j = 0; j < 4; ++j)
      acc[i][j] = (f32x4){0.f,0.f,0.f,0.f};

  for (int k0 = 0; k0 < K; k0 += 64) {
    #pragma unroll
    for (int i = 0; i < 4; ++i) {
      int rowc = wid*32 + i*8;
      int row  = rowc + srow;
      gload16((const char*)&A[(size_t)(bm + row)*K + k0] + ssw, &As[rowc*64]);
      gload16((const char*)&Wt[(size_t)(bn + row)*K + k0] + ssw, &Bs[rowc*64]);
    }
    __syncthreads();
    #pragma unroll
    for (int ks = 0; ks < 2; ++ks) {
      int roff = ((ks*64 + kg*16) ^ rsw) >> 1;
      bf16x8 a[4], b[4];
      #pragma unroll
      for (int i = 0; i < 4; ++i) {
        a[i] = *(const bf16x8*)&As[(wr + i*16 + lr)*64 + roff];
        b[i] = *(const bf16x8*)&Bs[(wc + i*16 + lr)*64 + roff];
      }
      #pragma unroll
      for (int i = 0; i < 4; ++i)
        #pragma unroll
        for (int j = 0; j < 4; ++j)
          acc[i][j] = __builtin_amdgcn_mfma_f32_16x16x32_bf16(a[i], b[j], acc[i][j], 0, 0, 0);
    }
    __syncthreads();
  }
  int r0 = (lane >> 4) * 4;
  #pragma unroll
  for (int i = 0; i < 4; ++i) {
    #pragma unroll
    for (int j = 0; j < 4; ++j) {
      int col = bn + wc + j*16 + lr;
      float bv = bias ? bias[col] : 0.f;
      #pragma unroll
      for (int rr = 0; rr < 4; ++rr) {
        int row = bm + wr + i*16 + r0 + rr;
        float v = acc[i][j][rr] + bv;
        if (ACT) v = lrelu(v);
        if (OUT_BF16) ((unsigned short*)Cv)[(size_t)row*N + col] = f2bf(v);
        else          ((float*)Cv)[(size_t)row*N + col] = v;
      }
    }
  }
}

// ---------------- pair GEMM: fused expand + GEMM ----------------
__global__ __launch_bounds__(256) void k_pgemm(
    const unsigned short* __restrict__ UV, const unsigned short* __restrict__ Wt,
    const float* __restrict__ abias, const float* __restrict__ obias,
    unsigned short* __restrict__ C, int M, int N, int K)
{
  __shared__ unsigned short As[128*64];
  __shared__ unsigned short Bs[128*64];
  __shared__ float absm[512];
  int bm = blockIdx.x * 128;
  int bn = blockIdx.y * 128;
  int tid = threadIdx.x;
  int wid = tid >> 6, lane = tid & 63;
  int wr = (wid >> 1) * 64, wc = (wid & 1) * 64;
  int lr = lane & 15, kg = lane >> 4;
  int ld = 2*K;

  int srow = lane >> 3;
  int ssw  = ((lane & 7) * 16) ^ (srow << 4);
  int rsw  = (lr & 7) << 4;

  for (int idx = tid; idx < K; idx += 256) absm[idx] = abias[idx];

  int urow[4], vrow[4], arow[4], asw[4];
  #pragma unroll
  for (int i = 0; i < 4; ++i) {
    int ch = tid + (i << 8);
    int r = ch >> 3;
    int m = bm + r;
    int n = m / 81; int rem = m - n*81;
    int ii = rem / 9; int jj = rem - ii*9;
    urow[i] = n*9 + ii; vrow[i] = n*9 + jj;
    arow[i] = r;
    asw[i] = (((ch & 7) * 16) ^ ((r & 7) << 4)) >> 1;
  }
  __syncthreads();

  f32x4 acc[4][4];
  #pragma unroll
  for (int i = 0; i < 4; ++i)
    #pragma unroll
    for (int j = 0; j < 4; ++j)
      acc[i][j] = (f32x4){0.f,0.f,0.f,0.f};

  for (int k0 = 0; k0 < K; k0 += 64) {
    #pragma unroll
    for (int i = 0; i < 4; ++i) {
      int rowc = wid*32 + i*8;
      int row  = rowc + srow;
      gload16((const char*)&Wt[(size_t)(bn + row)*K + k0] + ssw, &Bs[rowc*64]);
    }
    #pragma unroll
    for (int i = 0; i < 4; ++i) {
      int ch = tid + (i << 8);
      int kc = (ch & 7) * 8;
      uint4 u4 = *(const uint4*)&UV[(size_t)urow[i]*ld + k0 + kc];
      uint4 v4 = *(const uint4*)&UV[(size_t)vrow[i]*ld + K + k0 + kc];
      const unsigned short* us = (const unsigned short*)&u4;
      const unsigned short* vs = (const unsigned short*)&v4;
      unsigned int pk[4];
      #pragma unroll
      for (int e2 = 0; e2 < 4; ++e2) {
        float a0 = bf2f(us[2*e2])   + bf2f(vs[2*e2])   + absm[k0 + kc + 2*e2];
        float a1 = bf2f(us[2*e2+1]) + bf2f(vs[2*e2+1]) + absm[k0 + kc + 2*e2+1];
        pk[e2] = pack_bf2(lrelu(a0), lrelu(a1));
      }
      *(uint4*)&As[arow[i]*64 + asw[i]] = *(uint4*)pk;
    }
    __syncthreads();
    #pragma unroll
    for (int ks = 0; ks < 2; ++ks) {
      int roff = ((ks*64 + kg*16) ^ rsw) >> 1;
      bf16x8 a[4], b[4];
      #pragma unroll
      for (int i = 0; i < 4; ++i) {
        a[i] = *(const bf16x8*)&As[(wr + i*16 + lr)*64 + roff];
        b[i] = *(const bf16x8*)&Bs[(wc + i*16 + lr)*64 + roff];
      }
      #pragma unroll
      for (int i = 0; i < 4; ++i)
        #pragma unroll
        for (int j = 0; j < 4; ++j)
          acc[i][j] = __builtin_amdgcn_mfma_f32_16x16x32_bf16(a[i], b[j], acc[i][j], 0, 0, 0);
    }
    __syncthreads();
  }
  int r0 = (lane >> 4) * 4;
  #pragma unroll
  for (int i = 0; i < 4; ++i) {
    #pragma unroll
    for (int j = 0; j < 4; ++j) {
      int col = bn + wc + j*16 + lr;
      float bv = obias[col];
      #pragma unroll
      for (int rr = 0; rr < 4; ++rr) {
        int row = bm + wr + i*16 + r0 + rr;
        C[(size_t)row*N + col] = f2bf(lrelu(acc[i][j][rr] + bv));
      }
    }
  }
}

// ---------------- build objects (2304 x 256) bf16 ----------------
__global__ void k_objects(const float* __restrict__ panel, const float* __restrict__ post_b,
                          unsigned short* __restrict__ obj)
{
  int idx = blockIdx.x*256 + threadIdx.x;
  int row = idx >> 8;
  int k = idx & 255;
  int slot = row % 9;
  int nn = row / 9;
  int b = nn >> 3, opt = nn & 7;
  float v;
  if (k < 247) {
    int src = (slot < 8) ? (b*16 + slot) : (b*16 + 8 + opt);
    v = panel[(size_t)src*256 + k] + post_b[k];
  } else {
    v = ((k - 247) == slot) ? 1.0f : 0.0f;
  }
  obj[idx] = f2bf(v);
}

// ---------------- sum over j (vectorized x8) ----------------
__global__ void k_sumj(const unsigned short* __restrict__ Z, float* __restrict__ SJ,
                       unsigned short* __restrict__ SJb, int C)
{
  int idx = blockIdx.x*256 + threadIdx.x;     // total 2304*C/8
  int vpr = C >> 3;
  int orow = idx / vpr, kv = (idx - orow*vpr) << 3;
  int n = orow / 9, i = orow % 9;
  const unsigned short* base = Z + (size_t)(n*81 + i*9)*C + kv;
  float s[8];
  #pragma unroll
  for (int e = 0; e < 8; ++e) s[e] = 0.f;
  #pragma unroll
  for (int j = 0; j < 9; ++j) {
    bf16x8 v = *(const bf16x8*)(base + (size_t)j*C);
    #pragma unroll
    for (int e = 0; e < 8; ++e) s[e] += bf2f(((const unsigned short*)&v)[e]);
  }
  float* so = SJ + (size_t)orow*C + kv;
  #pragma unroll
  for (int e = 0; e < 8; ++e) so[e] = s[e];
  unsigned int pk[4];
  #pragma unroll
  for (int e2 = 0; e2 < 4; ++e2) pk[e2] = pack_bf2(s[2*e2], s[2*e2+1]);
  *(uint4*)(SJb + (size_t)orow*C + kv) = *(uint4*)pk;
}

// ---------------- sum over i (vectorized x4) ----------------
__global__ void k_hsum(const float* __restrict__ SJ, float* __restrict__ HS,
                       unsigned short* __restrict__ HSb)
{
  int idx = blockIdx.x*256 + threadIdx.x;     // 16384 total
  int n = idx >> 6, kc = (idx & 63) << 2;
  const float* base = SJ + (size_t)n*9*256 + kc;
  float4 s = {0.f,0.f,0.f,0.f};
  #pragma unroll
  for (int i = 0; i < 9; ++i) {
    float4 v = *(const float4*)(base + (size_t)i*256);
    s.x += v.x; s.y += v.y; s.z += v.z; s.w += v.w;
  }
  *(float4*)(HS + (size_t)n*256 + kc) = s;
  unsigned int pk[2];
  pk[0] = pack_bf2(s.x, s.y);
  pk[1] = pack_bf2(s.z, s.w);
  *(uint2*)(HSb + (size_t)n*256 + kc) = *(uint2*)pk;
}

// ---------------- fused tail ----------------
__global__ __launch_bounds__(256) void k_tailfin(
    const float* __restrict__ HS, const unsigned short* __restrict__ F2,
    const float* __restrict__ ffw, const float* __restrict__ ffb,
    float* __restrict__ out)
{
  __shared__ float red[256];
  __shared__ float wsm[256];
  int tid = threadIdx.x;
  wsm[tid] = ffw[tid];
  float s = 0.f;
  for (int j = 0; j < 256; ++j) { float v = HS[j*256 + tid]; s += v*v; }
  red[tid] = s; __syncthreads();
  for (int off = 128; off > 0; off >>= 1) { if (tid < off) red[tid] += red[tid + off]; __syncthreads(); }
  float hsq = red[0];
  __syncthreads();
  float r = ffb[0];
  for (int k = 0; k < 256; ++k) r += bf2f(F2[(size_t)tid*256 + k])*wsm[k];
  red[tid] = r*r; __syncthreads();
  for (int off = 128; off > 0; off >>= 1) { if (tid < off) red[tid] += red[tid + off]; __syncthreads(); }
  out[tid] = r;
  if (tid == 0) out[256] = hsq/65536.0f + red[0]/256.0f;
}

extern "C" void kernel_launch(void* const* d_in, const int* in_sizes, int n_in,
                              void* d_out, int out_size, void* d_ws, size_t ws_size,
                              hipStream_t stream)
{
  const float* batch   = (const float*)d_in[0];
  const float* conv_w1 = (const float*)d_in[1];
  const float* conv_b1 = (const float*)d_in[2];
  const float* conv_w2 = (const float*)d_in[3];
  const float* conv_b2 = (const float*)d_in[4];
  const float* conv_w3 = (const float*)d_in[5];
  const float* conv_b3 = (const float*)d_in[6];
  const float* conv_w4 = (const float*)d_in[7];
  const float* conv_b4 = (const float*)d_in[8];
  const float* post_w  = (const float*)d_in[9];
  const float* post_b  = (const float*)d_in[10];
  const float* g_w1    = (const float*)d_in[11];
  const float* g_b1    = (const float*)d_in[12];
  const float* g_w2    = (const float*)d_in[13];
  const float* g_b2    = (const float*)d_in[14];
  const float* g_w3    = (const float*)d_in[15];
  const float* g_b3    = (const float*)d_in[16];
  const float* g_w4    = (const float*)d_in[17];
  const float* g_b4    = (const float*)d_in[18];
  const float* h_w1    = (const float*)d_in[19];
  const float* h_b1    = (const float*)d_in[20];
  const float* h_w2    = (const float*)d_in[21];
  const float* h_b2    = (const float*)d_in[22];
  const float* h_w3    = (const float*)d_in[23];
  const float* h_b3    = (const float*)d_in[24];
  const float* f_w1    = (const float*)d_in[25];
  const float* f_b1    = (const float*)d_in[26];
  const float* f_w2    = (const float*)d_in[27];
  const float* f_b2    = (const float*)d_in[28];
  const float* ff_w    = (const float*)d_in[29];
  const float* ff_b    = (const float*)d_in[30];

  char* wsb = (char*)d_ws;
  const size_t off_Y1    = 0;
  const size_t off_Y2    = 52000000;
  const size_t off_Y3    = 64000000;
  const size_t off_Y4    = 67000000;
  const size_t off_PANEL = 68000000;
  const size_t off_WT    = 132000000;
  const size_t off_Pb    = 0;
  const size_t off_Qb    = 22000000;
  const size_t off_UV    = 44000000;
  const size_t off_OBJb  = 54000000;
  const size_t off_SJ    = 56000000;
  const size_t off_SJb   = 59000000;
  const size_t off_HS    = 61000000;
  const size_t off_HSb   = 61500000;
  const size_t off_F1    = 62000000;
  const size_t off_F2    = 63000000;

  unsigned short* WT = (unsigned short*)(wsb + off_WT);
  const size_t wt_g1   = 0;
  const size_t wt_g2   = 262144;
  const size_t wt_g3   = 524288;
  const size_t wt_g4   = 786432;
  const size_t wt_h1   = 917504;
  const size_t wt_h2   = 1310720;
  const size_t wt_h3   = 1507328;
  const size_t wt_post = 1703936;
  const size_t wt_cw2  = 1835008;
  const size_t wt_cw3  = 1844224;
  const size_t wt_cw4  = 1853440;
  const size_t wt_cw1  = 1862656;
  const size_t wt_f1   = 1871872;
  const size_t wt_f2   = 1937408;

  dim3 b256(256);

  k_prep<<<dim3(7824), b256, 0, stream>>>(g_w1, g_w2, g_w3, g_w4, h_w1, h_w2, h_w3,
                                          post_w, conv_w2, conv_w3, conv_w4, conv_w1,
                                          f_w1, f_w2, WT);

  unsigned short* Y1 = (unsigned short*)(wsb + off_Y1);
  unsigned short* Y2 = (unsigned short*)(wsb + off_Y2);
  unsigned short* Y3 = (unsigned short*)(wsb + off_Y3);
  unsigned short* Y4 = (unsigned short*)(wsb + off_Y4);
  float* PANEL = (float*)(wsb + off_PANEL);

  k_conv1m<<<dim3(512,2), b256, 0, stream>>>(batch, WT + wt_cw1, conv_b1, Y1);
  k_cmfma<39,39,19,19, 5,2><<<dim3(512,2), b256, 0, stream>>>(Y1, WT + wt_cw2, conv_b2, Y2);
  k_cmfma<19,19, 9, 9, 9,1><<<dim3(512,1), b256, 0, stream>>>(Y2, WT + wt_cw3, conv_b3, Y3);
  k_cmfma< 9, 9, 4, 4, 4,1><<<dim3(512,1), b256, 0, stream>>>(Y3, WT + wt_cw4, conv_b4, Y4);

  k_mgemm<0,0><<<dim3(4,2), b256, 0, stream>>>(Y4, WT + wt_post, nullptr, PANEL, 512,256,512);

  unsigned short* OBJb = (unsigned short*)(wsb + off_OBJb);
  unsigned short* Pb   = (unsigned short*)(wsb + off_Pb);
  unsigned short* Qb   = (unsigned short*)(wsb + off_Qb);
  unsigned short* SJb  = (unsigned short*)(wsb + off_SJb);
  unsigned short* UVb  = (unsigned short*)(wsb + off_UV);
  float* SJ = (float*)(wsb + off_SJ);
  float* HS = (float*)(wsb + off_HS);
  unsigned short* HSb = (unsigned short*)(wsb + off_HSb);
  unsigned short* F1 = (unsigned short*)(wsb + off_F1);
  unsigned short* F2 = (unsigned short*)(wsb + off_F2);

  k_objects<<<dim3(2304), b256, 0, stream>>>(PANEL, post_b, OBJb);

  // g-MLP
  k_mgemm<1,0><<<dim3(18,8), b256, 0, stream>>>(OBJb, WT + wt_g1, nullptr, UVb, 2304,1024,256);
  k_pgemm<<<dim3(162,4), b256, 0, stream>>>(UVb, WT + wt_g2, g_b1, g_b2, Qb, 20736,512,512);
  k_mgemm<1,1><<<dim3(162,4), b256, 0, stream>>>(Qb, WT + wt_g3, g_b3, Pb, 20736,512,512);
  k_mgemm<1,1><<<dim3(162,2), b256, 0, stream>>>(Pb, WT + wt_g4, g_b4, Qb, 20736,256,512);
  k_sumj<<<dim3(288), b256, 0, stream>>>(Qb, SJ, SJb, 256);

  for (int i = 0; i < 3; ++i) {
    k_mgemm<1,0><<<dim3(18,4), b256, 0, stream>>>(SJb, WT + wt_h1 + (size_t)i*131072, nullptr, UVb, 2304,512,256);
    k_pgemm<<<dim3(162,2), b256, 0, stream>>>(UVb, WT + wt_h2 + (size_t)i*65536, h_b1 + i*256, h_b2 + i*256, Qb, 20736,256,256);
    k_mgemm<1,1><<<dim3(162,2), b256, 0, stream>>>(Qb, WT + wt_h3 + (size_t)i*65536, h_b3 + i*256, Pb, 20736,256,256);
    k_sumj<<<dim3(288), b256, 0, stream>>>(Pb, SJ, SJb, 256);
  }

  // head
  k_hsum<<<dim3(64), b256, 0, stream>>>(SJ, HS, HSb);
  k_mgemm<1,1><<<dim3(2,2), b256, 0, stream>>>(HSb, WT + wt_f1, f_b1, F1, 256,256,256);
  k_mgemm<1,1><<<dim3(2,2), b256, 0, stream>>>(F1,  WT + wt_f2, f_b2, F2, 256,256,256);
  k_tailfin<<<dim3(1), b256, 0, stream>>>(HS, F2, ff_w, ff_b, (float*)d_out);
}